// Round 1
// baseline (8213.638 us; speedup 1.0000x reference)
//
#include <hip/hip_runtime.h>
#include <cstdint>
#include <cstddef>

#define HID 128

// ---------------- device helpers ----------------
static __device__ __forceinline__ int lowerb(const int* __restrict__ a, int n, int v) {
  int lo = 0, hi = n;
  while (lo < hi) { int m = (lo + hi) >> 1; if (a[m] < v) lo = m + 1; else hi = m; }
  return lo;
}

// ---------------- kernels ----------------
__global__ void k_hist(const int* __restrict__ idx, float* __restrict__ cnt, int n) {
  const int stride = gridDim.x * blockDim.x;
  for (int i = blockIdx.x * blockDim.x + threadIdx.x; i < n; i += stride)
    atomicAdd(&cnt[idx[i]], 1.0f);
}

__global__ void k_deg2nrm(float* __restrict__ d, int n) {
  const int stride = gridDim.x * blockDim.x;
  for (int i = blockIdx.x * blockDim.x + threadIdx.x; i < n; i += stride)
    d[i] = rsqrtf(d[i] + 1.0f);
}

__global__ void k_vx_init(const float* __restrict__ emb, const float* __restrict__ feat,
                          float* __restrict__ vx, int total) {
  const int stride = gridDim.x * blockDim.x;
  for (int i = blockIdx.x * blockDim.x + threadIdx.x; i < total; i += stride)
    vx[i] = emb[i & (HID - 1)] + feat[i];
}

// out[i][c] = sum_k (X[i][k] (+ vx[batch[i]][k])) * W[k][c] (+ bias[c])
template<int K, bool ADD_VX, bool HAS_BIAS>
__global__ __launch_bounds__(128)
void k_node_linear(const float* __restrict__ X, const float* __restrict__ W,
                   const float* __restrict__ bias, float* __restrict__ out, int N,
                   const int* __restrict__ batch, const float* __restrict__ vx) {
  constexpr int NPB = 32;  // nodes per block; N is a multiple of 32 here
  __shared__ float Wl[K * HID];
  __shared__ float Xl[NPB][K];
  const int tid = threadIdx.x;
  const int base = blockIdx.x * NPB;
  const int nn = min(NPB, N - base);

  for (int i = tid; i < (K * HID) / 4; i += 128)
    ((float4*)Wl)[i] = ((const float4*)W)[i];

  if constexpr ((K % 4 == 0) && ADD_VX) {
    for (int i = tid; i < nn * (K / 4); i += 128) {
      const int n = i / (K / 4), k4 = i % (K / 4);
      float4 v = ((const float4*)(X + (size_t)(base + n) * K))[k4];
      const float4 u = ((const float4*)(vx + (size_t)batch[base + n] * HID))[k4];
      v.x += u.x; v.y += u.y; v.z += u.z; v.w += u.w;
      ((float4*)(&Xl[n][0]))[k4] = v;
    }
  } else {
    for (int i = tid; i < nn * K; i += 128) {
      const int n = i / K, k = i % K;
      float v = X[(size_t)(base + n) * K + k];
      if constexpr (ADD_VX) v += vx[(size_t)batch[base + n] * HID + k];
      Xl[n][k] = v;
    }
  }
  __syncthreads();

  const int c = tid;
  const float bb = HAS_BIAS ? bias[c] : 0.0f;
  for (int n0 = 0; n0 < nn; n0 += 4) {
    float a0 = bb, a1 = bb, a2 = bb, a3 = bb;
    #pragma unroll 4
    for (int k = 0; k < K; k += 2) {  // K is even (78, 70, 128)
      const float w0 = Wl[k * HID + c];
      const float w1 = Wl[(k + 1) * HID + c];
      const float2 x0 = *(const float2*)&Xl[n0 + 0][k];
      const float2 x1 = *(const float2*)&Xl[n0 + 1][k];
      const float2 x2 = *(const float2*)&Xl[n0 + 2][k];
      const float2 x3 = *(const float2*)&Xl[n0 + 3][k];
      a0 += x0.x * w0 + x0.y * w1;
      a1 += x1.x * w0 + x1.y * w1;
      a2 += x2.x * w0 + x2.y * w1;
      a3 += x3.x * w0 + x3.y * w1;
    }
    const size_t r = (size_t)(base + n0) * HID + c;
    out[r] = a0;
    if (n0 + 1 < nn) out[r + HID] = a1;
    if (n0 + 2 < nn) out[r + 2 * HID] = a2;
    if (n0 + 3 < nn) out[r + 3 * HID] = a3;
  }
}

// out[i][c] = hw[i][c]*nrm[i]^2 + b[c]   (vectorized float4; n4 = N*32)
__global__ void k_gcn_init(const float* __restrict__ hw, const float* __restrict__ nrm,
                           const float* __restrict__ bias, float* __restrict__ out, int n4) {
  const int stride = gridDim.x * blockDim.x;
  for (int i = blockIdx.x * blockDim.x + threadIdx.x; i < n4; i += stride) {
    const int row = i >> 5;
    const int c4 = i & 31;
    const float nv = nrm[row];
    const float s = nv * nv;
    float4 v = ((const float4*)hw)[i];
    const float4 b = ((const float4*)bias)[c4];
    v.x = v.x * s + b.x; v.y = v.y * s + b.y; v.z = v.z * s + b.z; v.w = v.w * s + b.w;
    ((float4*)out)[i] = v;
  }
}

// atomic: out[dst[e]][c] += hw[src[e]][c] * nrm[src]*nrm[dst]   (total = E*32)
__global__ void k_gcn_edges(const int* __restrict__ src, const int* __restrict__ dst,
                            const float* __restrict__ hw, const float* __restrict__ nrm,
                            float* __restrict__ out, int total) {
  const int stride = gridDim.x * blockDim.x;
  for (int i = blockIdx.x * blockDim.x + threadIdx.x; i < total; i += stride) {
    const int e = i >> 5, c4 = i & 31;
    const int s = src[e], d = dst[e];
    const float coef = nrm[s] * nrm[d];
    const float4 v = ((const float4*)(hw + (size_t)s * HID))[c4];
    float* o = out + (size_t)d * HID + c4 * 4;
    atomicAdd(o + 0, v.x * coef);
    atomicAdd(o + 1, v.y * coef);
    atomicAdd(o + 2, v.z * coef);
    atomicAdd(o + 3, v.w * coef);
  }
}

// atomic: S[si[j]][c] += H[sn[j]][c]   (total = NS*32)
__global__ void k_scatter(const int* __restrict__ sn, const int* __restrict__ si,
                          const float* __restrict__ H, float* __restrict__ S, int total) {
  const int stride = gridDim.x * blockDim.x;
  for (int i = blockIdx.x * blockDim.x + threadIdx.x; i < total; i += stride) {
    const int j = i >> 5, c4 = i & 31;
    const float4 v = ((const float4*)(H + (size_t)sn[j] * HID))[c4];
    float* o = S + (size_t)si[j] * HID + c4 * 4;
    atomicAdd(o + 0, v.x);
    atomicAdd(o + 1, v.y);
    atomicAdd(o + 2, v.z);
    atomicAdd(o + 3, v.w);
  }
}

__global__ __launch_bounds__(256)
void k_bn_stats(const float* __restrict__ X, float* __restrict__ stats, int N) {
  __shared__ float sh[2][256];
  const int tid = threadIdx.x;
  const int c = tid & (HID - 1);
  const int half = tid >> 7;  // 0 or 1
  float s = 0.f, ss = 0.f;
  for (int r = blockIdx.x * 2 + half; r < N; r += gridDim.x * 2) {
    const float v = X[(size_t)r * HID + c];
    s += v; ss += v * v;
  }
  sh[0][tid] = s; sh[1][tid] = ss;
  __syncthreads();
  if (tid < HID) {
    atomicAdd(&stats[c], sh[0][tid] + sh[0][tid + 128]);
    atomicAdd(&stats[HID + c], sh[1][tid] + sh[1][tid + 128]);
  }
}

template<bool RELU>
__global__ void k_bn_apply(const float* __restrict__ X, float* __restrict__ Y,
                           const float* __restrict__ stats, const float* __restrict__ g,
                           const float* __restrict__ b, int n4, float invN) {
  const int stride = gridDim.x * blockDim.x;
  for (int i = blockIdx.x * blockDim.x + threadIdx.x; i < n4; i += stride) {
    const int c4 = i & 31;
    const float4 m4 = ((const float4*)stats)[c4];
    const float4 q4 = ((const float4*)stats)[32 + c4];
    const float4 g4 = ((const float4*)g)[c4];
    const float4 b4 = ((const float4*)b)[c4];
    float4 v = ((const float4*)X)[i];
    float m, va;
    m = m4.x * invN; va = q4.x * invN - m * m; v.x = (v.x - m) * rsqrtf(va + 1e-5f) * g4.x + b4.x;
    m = m4.y * invN; va = q4.y * invN - m * m; v.y = (v.y - m) * rsqrtf(va + 1e-5f) * g4.y + b4.y;
    m = m4.z * invN; va = q4.z * invN - m * m; v.z = (v.z - m) * rsqrtf(va + 1e-5f) * g4.z + b4.z;
    m = m4.w * invN; va = q4.w * invN - m * m; v.w = (v.w - m) * rsqrtf(va + 1e-5f) * g4.w + b4.w;
    if (RELU) {
      v.x = fmaxf(v.x, 0.f); v.y = fmaxf(v.y, 0.f); v.z = fmaxf(v.z, 0.f); v.w = fmaxf(v.w, 0.f);
    }
    ((float4*)Y)[i] = v;
  }
}

// per-batch sum over sorted `batch` of S[i][c]/max(cnt[i],1); also node count per batch
__global__ __launch_bounds__(128)
void k_pool(const float* __restrict__ S, const float* __restrict__ cnt,
            const int* __restrict__ batch, int N, float* __restrict__ outSum,
            float* __restrict__ nb) {
  const int b = blockIdx.x, c = threadIdx.x;
  const int lo = lowerb(batch, N, b);
  const int hi = lowerb(batch, N, b + 1);
  float a0 = 0.f, a1 = 0.f, a2 = 0.f, a3 = 0.f;
  int i = lo;
  for (; i + 3 < hi; i += 4) {
    a0 += S[(size_t)(i + 0) * HID + c] / fmaxf(cnt[i + 0], 1.f);
    a1 += S[(size_t)(i + 1) * HID + c] / fmaxf(cnt[i + 1], 1.f);
    a2 += S[(size_t)(i + 2) * HID + c] / fmaxf(cnt[i + 2], 1.f);
    a3 += S[(size_t)(i + 3) * HID + c] / fmaxf(cnt[i + 3], 1.f);
  }
  for (; i < hi; ++i) a0 += S[(size_t)i * HID + c] / fmaxf(cnt[i], 1.f);
  outSum[(size_t)b * HID + c] = (a0 + a1) + (a2 + a3);
  if (c == 0) nb[b] = (float)(hi - lo);
}

__global__ __launch_bounds__(128)
void k_vn_update(const float* __restrict__ pooledSum, float* __restrict__ vx,
                 const float* __restrict__ W, const float* __restrict__ bias) {
  const int b = blockIdx.x, c = threadIdx.x;
  __shared__ float xin[HID];
  xin[c] = pooledSum[(size_t)b * HID + c] + vx[(size_t)b * HID + c];
  __syncthreads();
  float acc = bias[c];
  #pragma unroll 8
  for (int k = 0; k < HID; k += 4) {
    const float4 x = *(const float4*)&xin[k];
    acc += x.x * W[k * HID + c] + x.y * W[(k + 1) * HID + c]
         + x.z * W[(k + 2) * HID + c] + x.w * W[(k + 3) * HID + c];
  }
  vx[(size_t)b * HID + c] += fmaxf(acc, 0.0f);
}

// A_d = mean_d + [nd>0]*mean_p ; A_p = mean_p + [np>0]*mean_d
__global__ __launch_bounds__(128)
void k_final_A(const float* __restrict__ sum_Sd, const float* __restrict__ sum_Sp,
               const float* __restrict__ nb_d, const float* __restrict__ nb_p,
               float* __restrict__ A_d, float* __restrict__ A_p) {
  const int b = blockIdx.x, c = threadIdx.x;
  const float nd = nb_d[b], np_ = nb_p[b];
  const float md = sum_Sd[(size_t)b * HID + c] / fmaxf(nd, 1.f);
  const float mp = sum_Sp[(size_t)b * HID + c] / fmaxf(np_, 1.f);
  A_d[(size_t)b * HID + c] = md + (nd > 0.f ? mp : 0.f);
  A_p[(size_t)b * HID + c] = mp + (np_ > 0.f ? md : 0.f);
}

// out[b][c] = bias[c] + sum_k concat(A[b],feat[b])[k] * W[k][c]   (K = 256)
__global__ __launch_bounds__(128)
void k_final_mlp(const float* __restrict__ A, const float* __restrict__ feat,
                 const float* __restrict__ W, const float* __restrict__ bias,
                 float* __restrict__ out) {
  const int b = blockIdx.x, c = threadIdx.x;
  __shared__ float xin[2 * HID];
  xin[c] = A[(size_t)b * HID + c];
  xin[HID + c] = feat[(size_t)b * HID + c];
  __syncthreads();
  float acc = bias[c];
  #pragma unroll 8
  for (int k = 0; k < 2 * HID; k += 4) {
    const float4 x = *(const float4*)&xin[k];
    acc += x.x * W[k * HID + c] + x.y * W[(k + 1) * HID + c]
         + x.z * W[(k + 2) * HID + c] + x.w * W[(k + 3) * HID + c];
  }
  out[(size_t)b * HID + c] = acc;
}

// ---------------- host launch ----------------
extern "C" void kernel_launch(void* const* d_in, const int* in_sizes, int n_in,
                              void* d_out, int out_size, void* d_ws, size_t ws_size,
                              hipStream_t stream) {
  const float* drug_x   = (const float*)d_in[0];
  const float* prot_x   = (const float*)d_in[1];
  const float* d_feat   = (const float*)d_in[2];
  const float* p_feat   = (const float*)d_in[3];
  const int*   d_ei     = (const int*)d_in[4];
  const int*   d_batch  = (const int*)d_in[5];
  const int*   d_sn     = (const int*)d_in[6];
  const int*   d_si     = (const int*)d_in[7];
  const int*   p_ei     = (const int*)d_in[8];
  const int*   p_batch  = (const int*)d_in[9];
  const int*   p_sn     = (const int*)d_in[10];
  const int*   p_si     = (const int*)d_in[11];
  const float* enc_Wd   = (const float*)d_in[12];
  const float* enc_bd   = (const float*)d_in[13];
  const float* enc_Wp   = (const float*)d_in[14];
  const float* enc_bp   = (const float*)d_in[15];
  const float* convW_d  = (const float*)d_in[16];
  const float* convb_d  = (const float*)d_in[17];
  const float* convW_p  = (const float*)d_in[18];
  const float* convb_p  = (const float*)d_in[19];
  const float* bng_d    = (const float*)d_in[20];
  const float* bnb_d    = (const float*)d_in[21];
  const float* bng_p    = (const float*)d_in[22];
  const float* bnb_p    = (const float*)d_in[23];
  const float* vn_emb_d = (const float*)d_in[24];
  const float* vn_emb_p = (const float*)d_in[25];
  const float* vnW_d    = (const float*)d_in[26];
  const float* vnb_d    = (const float*)d_in[27];
  const float* vnW_p    = (const float*)d_in[28];
  const float* vnb_p    = (const float*)d_in[29];
  const float* mlpd1_W  = (const float*)d_in[30];
  const float* mlpd1_b  = (const float*)d_in[31];
  const float* mlpd1_g  = (const float*)d_in[32];
  const float* mlpd1_be = (const float*)d_in[33];
  const float* mlpp1_W  = (const float*)d_in[34];
  const float* mlpp1_b  = (const float*)d_in[35];
  const float* mlpp1_g  = (const float*)d_in[36];
  const float* mlpp1_be = (const float*)d_in[37];

  const int ND = in_sizes[5];
  const int ED = in_sizes[4] / 2;
  const int SD = in_sizes[6];
  const int NP = in_sizes[9];
  const int EP = in_sizes[8] / 2;
  const int SP = in_sizes[10];
  const int B  = in_sizes[2] / HID;
  (void)n_in; (void)out_size; (void)ws_size;

  char* wsb = (char*)d_ws;
  size_t off = 0;
  auto alloc = [&](size_t bytes) -> float* {
    float* p = (float*)(wsb + off);
    off = (off + bytes + 255) & ~(size_t)255;
    return p;
  };
  float* Ap   = alloc((size_t)NP * HID * 4);
  float* Bp   = alloc((size_t)NP * HID * 4);
  float* Cp   = alloc((size_t)NP * HID * 4);
  float* Adg  = alloc((size_t)ND * HID * 4);
  float* Bdg  = alloc((size_t)ND * HID * 4);
  float* Cdg  = alloc((size_t)ND * HID * 4);
  float* nrm_p = alloc((size_t)NP * 4);
  float* cnt_p = alloc((size_t)NP * 4);
  float* nrm_d = alloc((size_t)ND * 4);
  float* cnt_d = alloc((size_t)ND * 4);
  float* vx_d  = alloc((size_t)B * HID * 4);
  float* vx_p  = alloc((size_t)B * HID * 4);
  float* sum_Sd = alloc((size_t)B * HID * 4);
  float* sum_Sp = alloc((size_t)B * HID * 4);
  float* A_d   = alloc((size_t)B * HID * 4);
  float* A_p   = alloc((size_t)B * HID * 4);
  float* nb_d  = alloc((size_t)B * 4);
  float* nb_p  = alloc((size_t)B * 4);
  float* stats = alloc(2 * HID * 4);
  float* fpre  = alloc((size_t)B * HID * 4);

  const int* d_src = d_ei;  const int* d_dst = d_ei + ED;
  const int* p_src = p_ei;  const int* p_dst = p_ei + EP;

  // ---- invariants: degrees -> nrm, sub-index counts ----
  hipMemsetAsync(nrm_p, 0, (size_t)NP * 4, stream);
  hipMemsetAsync(nrm_d, 0, (size_t)ND * 4, stream);
  hipMemsetAsync(cnt_p, 0, (size_t)NP * 4, stream);
  hipMemsetAsync(cnt_d, 0, (size_t)ND * 4, stream);
  k_hist<<<1024, 256, 0, stream>>>(d_dst, nrm_d, ED);
  k_hist<<<2048, 256, 0, stream>>>(p_dst, nrm_p, EP);
  k_deg2nrm<<<64, 256, 0, stream>>>(nrm_d, ND);
  k_deg2nrm<<<512, 256, 0, stream>>>(nrm_p, NP);
  k_hist<<<2048, 256, 0, stream>>>(d_si, cnt_d, SD);
  k_hist<<<2048, 256, 0, stream>>>(p_si, cnt_p, SP);

  // ---- encoders + virtual node init ----
  k_node_linear<78, false, true><<<ND / 32, 128, 0, stream>>>(drug_x, enc_Wd, enc_bd, Adg, ND, nullptr, nullptr);
  k_node_linear<70, false, true><<<NP / 32, 128, 0, stream>>>(prot_x, enc_Wp, enc_bp, Ap, NP, nullptr, nullptr);
  k_vx_init<<<64, 256, 0, stream>>>(vn_emb_d, d_feat, vx_d, B * HID);
  k_vx_init<<<64, 256, 0, stream>>>(vn_emb_p, p_feat, vx_p, B * HID);

  float* cur_d = Adg; float* alt_d = Cdg;
  float* cur_p = Ap;  float* alt_p = Cp;

  for (int l = 0; l < 3; ++l) {
    // ---------- drug ----------
    k_node_linear<128, true, false><<<ND / 32, 128, 0, stream>>>(
        cur_d, convW_d + (size_t)l * HID * HID, nullptr, Bdg, ND, d_batch, vx_d);
    k_gcn_init<<<2048, 256, 0, stream>>>(Bdg, nrm_d, convb_d + l * HID, alt_d, ND * 32);
    k_gcn_edges<<<4096, 256, 0, stream>>>(d_src, d_dst, Bdg, nrm_d, alt_d, ED * 32);
    hipMemsetAsync(stats, 0, 2 * HID * 4, stream);
    k_bn_stats<<<512, 256, 0, stream>>>(alt_d, stats, ND);
    k_bn_apply<true><<<2048, 256, 0, stream>>>(alt_d, alt_d, stats, bng_d + l * HID, bnb_d + l * HID,
                                               ND * 32, 1.0f / (float)ND);
    hipMemsetAsync(cur_d, 0, (size_t)ND * HID * 4, stream);
    k_scatter<<<8192, 256, 0, stream>>>(d_sn, d_si, alt_d, cur_d, SD * 32);
    k_pool<<<B, 128, 0, stream>>>(cur_d, cnt_d, d_batch, ND, sum_Sd, nb_d);
    if (l < 2)
      k_vn_update<<<B, 128, 0, stream>>>(sum_Sd, vx_d, vnW_d + (size_t)l * HID * HID, vnb_d + l * HID);
    { float* t = cur_d; cur_d = alt_d; alt_d = t; }

    // ---------- protein ----------
    k_node_linear<128, true, false><<<NP / 32, 128, 0, stream>>>(
        cur_p, convW_p + (size_t)l * HID * HID, nullptr, Bp, NP, p_batch, vx_p);
    k_gcn_init<<<4096, 256, 0, stream>>>(Bp, nrm_p, convb_p + l * HID, alt_p, NP * 32);
    k_gcn_edges<<<8192, 256, 0, stream>>>(p_src, p_dst, Bp, nrm_p, alt_p, EP * 32);
    hipMemsetAsync(stats, 0, 2 * HID * 4, stream);
    k_bn_stats<<<1024, 256, 0, stream>>>(alt_p, stats, NP);
    k_bn_apply<true><<<4096, 256, 0, stream>>>(alt_p, alt_p, stats, bng_p + l * HID, bnb_p + l * HID,
                                               NP * 32, 1.0f / (float)NP);
    hipMemsetAsync(cur_p, 0, (size_t)NP * HID * 4, stream);
    k_scatter<<<8192, 256, 0, stream>>>(p_sn, p_si, alt_p, cur_p, SP * 32);
    k_pool<<<B, 128, 0, stream>>>(cur_p, cnt_p, p_batch, NP, sum_Sp, nb_p);
    if (l < 2)
      k_vn_update<<<B, 128, 0, stream>>>(sum_Sp, vx_p, vnW_p + (size_t)l * HID * HID, vnb_p + l * HID);
    { float* t = cur_p; cur_p = alt_p; alt_p = t; }
  }

  // ---- cross-modal sync collapses to pooled means; final MLP + BN ----
  k_final_A<<<B, 128, 0, stream>>>(sum_Sd, sum_Sp, nb_d, nb_p, A_d, A_p);

  float* outf = (float*)d_out;
  k_final_mlp<<<B, 128, 0, stream>>>(A_d, d_feat, mlpd1_W, mlpd1_b, fpre);
  hipMemsetAsync(stats, 0, 2 * HID * 4, stream);
  k_bn_stats<<<128, 256, 0, stream>>>(fpre, stats, B);
  k_bn_apply<false><<<64, 256, 0, stream>>>(fpre, outf, stats, mlpd1_g, mlpd1_be,
                                            B * 32, 1.0f / (float)B);

  k_final_mlp<<<B, 128, 0, stream>>>(A_p, p_feat, mlpp1_W, mlpp1_b, fpre);
  hipMemsetAsync(stats, 0, 2 * HID * 4, stream);
  k_bn_stats<<<128, 256, 0, stream>>>(fpre, stats, B);
  k_bn_apply<false><<<64, 256, 0, stream>>>(fpre, outf + (size_t)B * HID, stats, mlpp1_g, mlpp1_be,
                                            B * 32, 1.0f / (float)B);
}

// Round 2
// 2035.960 us; speedup vs baseline: 4.0343x; 4.0343x over previous
//
#include <hip/hip_runtime.h>
#include <cstdint>
#include <cstddef>

#define HID 128
#define NSLICE 32

// ---------------- device helpers ----------------
static __device__ __forceinline__ int lowerb(const int* __restrict__ a, int n, int v) {
  int lo = 0, hi = n;
  while (lo < hi) { int m = (lo + hi) >> 1; if (a[m] < v) lo = m + 1; else hi = m; }
  return lo;
}

// ---------------- CSR build ----------------
__global__ void k_hist_i(const int* __restrict__ idx, int* __restrict__ cnt, int n) {
  const int stride = gridDim.x * blockDim.x;
  for (int i = blockIdx.x * blockDim.x + threadIdx.x; i < n; i += stride)
    atomicAdd(&cnt[idx[i]], 1);
}

__global__ void k_nrm(const int* __restrict__ deg, float* __restrict__ nrm, int n) {
  const int stride = gridDim.x * blockDim.x;
  for (int i = blockIdx.x * blockDim.x + threadIdx.x; i < n; i += stride)
    nrm[i] = rsqrtf((float)deg[i] + 1.0f);
}

// pass 1: per-1024-chunk exclusive scan; chunk totals -> aux
__global__ __launch_bounds__(256)
void k_scan1(const int* __restrict__ cnt, int* __restrict__ row, int* __restrict__ aux, int n) {
  __shared__ int sh[256];
  const int tid = threadIdx.x;
  const int base = blockIdx.x * 1024 + tid * 4;
  int v0 = base + 0 < n ? cnt[base + 0] : 0;
  int v1 = base + 1 < n ? cnt[base + 1] : 0;
  int v2 = base + 2 < n ? cnt[base + 2] : 0;
  int v3 = base + 3 < n ? cnt[base + 3] : 0;
  const int s = v0 + v1 + v2 + v3;
  sh[tid] = s;
  __syncthreads();
  for (int o = 1; o < 256; o <<= 1) {
    const int t = (tid >= o) ? sh[tid - o] : 0;
    __syncthreads();
    sh[tid] += t;
    __syncthreads();
  }
  int excl = sh[tid] - s;
  if (tid == 255) aux[blockIdx.x] = sh[255];
  if (base + 0 < n) row[base + 0] = excl; excl += v0;
  if (base + 1 < n) row[base + 1] = excl; excl += v1;
  if (base + 2 < n) row[base + 2] = excl; excl += v2;
  if (base + 3 < n) row[base + 3] = excl;
}

// pass 2: single-block exclusive scan of aux (nb <= 256)
__global__ __launch_bounds__(256)
void k_scan2(int* __restrict__ aux, int nb) {
  __shared__ int sh[256];
  const int tid = threadIdx.x;
  const int v = tid < nb ? aux[tid] : 0;
  sh[tid] = v;
  __syncthreads();
  for (int o = 1; o < 256; o <<= 1) {
    const int t = (tid >= o) ? sh[tid - o] : 0;
    __syncthreads();
    sh[tid] += t;
    __syncthreads();
  }
  if (tid < nb) aux[tid] = sh[tid] - v;
}

// pass 3: add chunk offsets; write row[n] = total
__global__ void k_scan3(int* __restrict__ row, const int* __restrict__ aux, int n, int total) {
  const int stride = gridDim.x * blockDim.x;
  for (int i = blockIdx.x * blockDim.x + threadIdx.x; i < n; i += stride)
    row[i] += aux[i >> 10];
  if (blockIdx.x == 0 && threadIdx.x == 0) row[n] = total;
}

__global__ void k_fill_edges(const int* __restrict__ src, const int* __restrict__ dst,
                             const int* __restrict__ row, int* __restrict__ cur,
                             int* __restrict__ col, float* __restrict__ coef,
                             const float* __restrict__ nrm, int E) {
  const int stride = gridDim.x * blockDim.x;
  for (int e = blockIdx.x * blockDim.x + threadIdx.x; e < E; e += stride) {
    const int d = dst[e], s = src[e];
    const int pos = row[d] + atomicAdd(&cur[d], 1);
    col[pos] = s;
    coef[pos] = nrm[s] * nrm[d];
  }
}

__global__ void k_fill_sub(const int* __restrict__ sn, const int* __restrict__ si,
                           const int* __restrict__ row, int* __restrict__ cur,
                           int* __restrict__ col, int n) {
  const int stride = gridDim.x * blockDim.x;
  for (int j = blockIdx.x * blockDim.x + threadIdx.x; j < n; j += stride) {
    const int t = si[j];
    const int pos = row[t] + atomicAdd(&cur[t], 1);
    col[pos] = sn[j];
  }
}

// ---------------- misc ----------------
__global__ void k_vx_init(const float* __restrict__ emb, const float* __restrict__ feat,
                          float* __restrict__ vx, int total) {
  const int stride = gridDim.x * blockDim.x;
  for (int i = blockIdx.x * blockDim.x + threadIdx.x; i < total; i += stride)
    vx[i] = emb[i & (HID - 1)] + feat[i];
}

// out[i][c] = sum_k (X[i][k] (+ vx[batch[i]][k])) * W[k][c] (+ bias[c])
template<int K, bool ADD_VX, bool HAS_BIAS>
__global__ __launch_bounds__(128)
void k_node_linear(const float* __restrict__ X, const float* __restrict__ W,
                   const float* __restrict__ bias, float* __restrict__ out, int N,
                   const int* __restrict__ batch, const float* __restrict__ vx) {
  constexpr int NPB = 32;
  __shared__ float Wl[K * HID];
  __shared__ float Xl[NPB][K];
  const int tid = threadIdx.x;
  const int base = blockIdx.x * NPB;
  const int nn = min(NPB, N - base);

  for (int i = tid; i < (K * HID) / 4; i += 128)
    ((float4*)Wl)[i] = ((const float4*)W)[i];

  if constexpr ((K % 4 == 0) && ADD_VX) {
    for (int i = tid; i < nn * (K / 4); i += 128) {
      const int n = i / (K / 4), k4 = i % (K / 4);
      float4 v = ((const float4*)(X + (size_t)(base + n) * K))[k4];
      const float4 u = ((const float4*)(vx + (size_t)batch[base + n] * HID))[k4];
      v.x += u.x; v.y += u.y; v.z += u.z; v.w += u.w;
      ((float4*)(&Xl[n][0]))[k4] = v;
    }
  } else {
    for (int i = tid; i < nn * K; i += 128) {
      const int n = i / K, k = i % K;
      float v = X[(size_t)(base + n) * K + k];
      if constexpr (ADD_VX) v += vx[(size_t)batch[base + n] * HID + k];
      Xl[n][k] = v;
    }
  }
  __syncthreads();

  const int c = tid;
  const float bb = HAS_BIAS ? bias[c] : 0.0f;
  for (int n0 = 0; n0 < nn; n0 += 4) {
    float a0 = bb, a1 = bb, a2 = bb, a3 = bb;
    #pragma unroll 4
    for (int k = 0; k < K; k += 2) {
      const float w0 = Wl[k * HID + c];
      const float w1 = Wl[(k + 1) * HID + c];
      const float2 x0 = *(const float2*)&Xl[n0 + 0][k];
      const float2 x1 = *(const float2*)&Xl[n0 + 1][k];
      const float2 x2 = *(const float2*)&Xl[n0 + 2][k];
      const float2 x3 = *(const float2*)&Xl[n0 + 3][k];
      a0 += x0.x * w0 + x0.y * w1;
      a1 += x1.x * w0 + x1.y * w1;
      a2 += x2.x * w0 + x2.y * w1;
      a3 += x3.x * w0 + x3.y * w1;
    }
    const size_t r = (size_t)(base + n0) * HID + c;
    out[r] = a0;
    if (n0 + 1 < nn) out[r + HID] = a1;
    if (n0 + 2 < nn) out[r + 2 * HID] = a2;
    if (n0 + 3 < nn) out[r + 3 * HID] = a3;
  }
}

// GCN aggregation as CSR gather, fused with self-term + bias + sliced BN-stats.
// out[i][c] = hw[i][c]*nrm[i]^2 + bias[c] + sum_e coef[e]*hw[col[e]][c]
__global__ __launch_bounds__(256)
void k_gcn_gather(const int* __restrict__ row, const int* __restrict__ col,
                  const float* __restrict__ coef, const float* __restrict__ hw,
                  const float* __restrict__ nrm, const float* __restrict__ bias,
                  float* __restrict__ out, float* __restrict__ stats_sl, int N) {
  __shared__ float sh[8][HID];
  const int tid = threadIdx.x;
  const int grp = tid >> 5;
  const int c4 = tid & 31;
  const int node = blockIdx.x * 8 + grp;
  float4 acc = {0.f, 0.f, 0.f, 0.f};
  if (node < N) {
    const float nv = nrm[node];
    const float s2 = nv * nv;
    const float4 h = ((const float4*)(hw + (size_t)node * HID))[c4];
    const float4 b = ((const float4*)bias)[c4];
    acc.x = h.x * s2 + b.x; acc.y = h.y * s2 + b.y;
    acc.z = h.z * s2 + b.z; acc.w = h.w * s2 + b.w;
    const int lo = row[node], hi = row[node + 1];
    for (int e = lo; e < hi; ++e) {
      const int s = col[e];
      const float w = coef[e];
      const float4 v = ((const float4*)(hw + (size_t)s * HID))[c4];
      acc.x += v.x * w; acc.y += v.y * w; acc.z += v.z * w; acc.w += v.w * w;
    }
    ((float4*)(out + (size_t)node * HID))[c4] = acc;
  }
  // BN stats: reduce 8 nodes in LDS, then sliced global atomics
  ((float4*)&sh[grp][0])[c4] = acc;
  __syncthreads();
  if (tid < HID) {
    float s = 0.f, ss = 0.f;
    #pragma unroll
    for (int g = 0; g < 8; ++g) {
      const float v = sh[g][tid];
      s += v; ss += v * v;
    }
    float* base = stats_sl + (size_t)(blockIdx.x & (NSLICE - 1)) * (2 * HID);
    atomicAdd(&base[tid], s);
    atomicAdd(&base[HID + tid], ss);
  }
}

// fold 32 stat slices into statsF[0..127]=sum, [128..255]=sumsq
__global__ __launch_bounds__(256)
void k_fold(const float* __restrict__ stats_sl, float* __restrict__ statsF) {
  const int tid = threadIdx.x;
  float s = 0.f;
  for (int k = 0; k < NSLICE; ++k) s += stats_sl[(size_t)k * (2 * HID) + tid];
  statsF[tid] = s;
}

template<bool RELU>
__global__ void k_bn_apply(const float* __restrict__ X, float* __restrict__ Y,
                           const float* __restrict__ stats, const float* __restrict__ g,
                           const float* __restrict__ b, int n4, float invN) {
  const int stride = gridDim.x * blockDim.x;
  for (int i = blockIdx.x * blockDim.x + threadIdx.x; i < n4; i += stride) {
    const int c4 = i & 31;
    const float4 m4 = ((const float4*)stats)[c4];
    const float4 q4 = ((const float4*)stats)[32 + c4];
    const float4 g4 = ((const float4*)g)[c4];
    const float4 b4 = ((const float4*)b)[c4];
    float4 v = ((const float4*)X)[i];
    float m, va;
    m = m4.x * invN; va = q4.x * invN - m * m; v.x = (v.x - m) * rsqrtf(va + 1e-5f) * g4.x + b4.x;
    m = m4.y * invN; va = q4.y * invN - m * m; v.y = (v.y - m) * rsqrtf(va + 1e-5f) * g4.y + b4.y;
    m = m4.z * invN; va = q4.z * invN - m * m; v.z = (v.z - m) * rsqrtf(va + 1e-5f) * g4.z + b4.z;
    m = m4.w * invN; va = q4.w * invN - m * m; v.w = (v.w - m) * rsqrtf(va + 1e-5f) * g4.w + b4.w;
    if (RELU) {
      v.x = fmaxf(v.x, 0.f); v.y = fmaxf(v.y, 0.f); v.z = fmaxf(v.z, 0.f); v.w = fmaxf(v.w, 0.f);
    }
    ((float4*)Y)[i] = v;
  }
}

// per-node sub-graph mean via CSR gather: S[i][c] = mean_{j in row(i)} H[col[j]][c]
__global__ __launch_bounds__(256)
void k_sub_gather(const int* __restrict__ row, const int* __restrict__ col,
                  const float* __restrict__ H, float* __restrict__ S, int N) {
  const int tid = threadIdx.x;
  const int node = blockIdx.x * 8 + (tid >> 5);
  const int c4 = tid & 31;
  if (node >= N) return;
  const int lo = row[node], hi = row[node + 1];
  float4 acc = {0.f, 0.f, 0.f, 0.f};
  for (int e = lo; e < hi; ++e) {
    const int s = col[e];
    const float4 v = ((const float4*)(H + (size_t)s * HID))[c4];
    acc.x += v.x; acc.y += v.y; acc.z += v.z; acc.w += v.w;
  }
  const float inv = 1.0f / fmaxf((float)(hi - lo), 1.0f);
  acc.x *= inv; acc.y *= inv; acc.z *= inv; acc.w *= inv;
  ((float4*)(S + (size_t)node * HID))[c4] = acc;
}

// per-batch sum over sorted `batch` of S[i][c] (S already holds means); node count per batch
__global__ __launch_bounds__(128)
void k_pool(const float* __restrict__ S, const int* __restrict__ batch, int N,
            float* __restrict__ outSum, float* __restrict__ nb) {
  const int b = blockIdx.x, c = threadIdx.x;
  const int lo = lowerb(batch, N, b);
  const int hi = lowerb(batch, N, b + 1);
  float a0 = 0.f, a1 = 0.f, a2 = 0.f, a3 = 0.f;
  int i = lo;
  for (; i + 3 < hi; i += 4) {
    a0 += S[(size_t)(i + 0) * HID + c];
    a1 += S[(size_t)(i + 1) * HID + c];
    a2 += S[(size_t)(i + 2) * HID + c];
    a3 += S[(size_t)(i + 3) * HID + c];
  }
  for (; i < hi; ++i) a0 += S[(size_t)i * HID + c];
  outSum[(size_t)b * HID + c] = (a0 + a1) + (a2 + a3);
  if (c == 0) nb[b] = (float)(hi - lo);
}

__global__ __launch_bounds__(128)
void k_vn_update(const float* __restrict__ pooledSum, float* __restrict__ vx,
                 const float* __restrict__ W, const float* __restrict__ bias) {
  const int b = blockIdx.x, c = threadIdx.x;
  __shared__ float xin[HID];
  xin[c] = pooledSum[(size_t)b * HID + c] + vx[(size_t)b * HID + c];
  __syncthreads();
  float acc = bias[c];
  #pragma unroll 8
  for (int k = 0; k < HID; k += 4) {
    const float4 x = *(const float4*)&xin[k];
    acc += x.x * W[k * HID + c] + x.y * W[(k + 1) * HID + c]
         + x.z * W[(k + 2) * HID + c] + x.w * W[(k + 3) * HID + c];
  }
  vx[(size_t)b * HID + c] += fmaxf(acc, 0.0f);
}

__global__ __launch_bounds__(128)
void k_final_A(const float* __restrict__ sum_Sd, const float* __restrict__ sum_Sp,
               const float* __restrict__ nb_d, const float* __restrict__ nb_p,
               float* __restrict__ A_d, float* __restrict__ A_p) {
  const int b = blockIdx.x, c = threadIdx.x;
  const float nd = nb_d[b], np_ = nb_p[b];
  const float md = sum_Sd[(size_t)b * HID + c] / fmaxf(nd, 1.f);
  const float mp = sum_Sp[(size_t)b * HID + c] / fmaxf(np_, 1.f);
  A_d[(size_t)b * HID + c] = md + (nd > 0.f ? mp : 0.f);
  A_p[(size_t)b * HID + c] = mp + (np_ > 0.f ? md : 0.f);
}

__global__ __launch_bounds__(128)
void k_final_mlp(const float* __restrict__ A, const float* __restrict__ feat,
                 const float* __restrict__ W, const float* __restrict__ bias,
                 float* __restrict__ out) {
  const int b = blockIdx.x, c = threadIdx.x;
  __shared__ float xin[2 * HID];
  xin[c] = A[(size_t)b * HID + c];
  xin[HID + c] = feat[(size_t)b * HID + c];
  __syncthreads();
  float acc = bias[c];
  #pragma unroll 8
  for (int k = 0; k < 2 * HID; k += 4) {
    const float4 x = *(const float4*)&xin[k];
    acc += x.x * W[k * HID + c] + x.y * W[(k + 1) * HID + c]
         + x.z * W[(k + 2) * HID + c] + x.w * W[(k + 3) * HID + c];
  }
  out[(size_t)b * HID + c] = acc;
}

__global__ __launch_bounds__(256)
void k_bn_stats(const float* __restrict__ X, float* __restrict__ stats, int N) {
  __shared__ float sh[2][256];
  const int tid = threadIdx.x;
  const int c = tid & (HID - 1);
  const int half = tid >> 7;
  float s = 0.f, ss = 0.f;
  for (int r = blockIdx.x * 2 + half; r < N; r += gridDim.x * 2) {
    const float v = X[(size_t)r * HID + c];
    s += v; ss += v * v;
  }
  sh[0][tid] = s; sh[1][tid] = ss;
  __syncthreads();
  if (tid < HID) {
    atomicAdd(&stats[c], sh[0][tid] + sh[0][tid + 128]);
    atomicAdd(&stats[HID + c], sh[1][tid] + sh[1][tid + 128]);
  }
}

// ---------------- host launch ----------------
extern "C" void kernel_launch(void* const* d_in, const int* in_sizes, int n_in,
                              void* d_out, int out_size, void* d_ws, size_t ws_size,
                              hipStream_t stream) {
  const float* drug_x   = (const float*)d_in[0];
  const float* prot_x   = (const float*)d_in[1];
  const float* d_feat   = (const float*)d_in[2];
  const float* p_feat   = (const float*)d_in[3];
  const int*   d_ei     = (const int*)d_in[4];
  const int*   d_batch  = (const int*)d_in[5];
  const int*   d_sn     = (const int*)d_in[6];
  const int*   d_si     = (const int*)d_in[7];
  const int*   p_ei     = (const int*)d_in[8];
  const int*   p_batch  = (const int*)d_in[9];
  const int*   p_sn     = (const int*)d_in[10];
  const int*   p_si     = (const int*)d_in[11];
  const float* enc_Wd   = (const float*)d_in[12];
  const float* enc_bd   = (const float*)d_in[13];
  const float* enc_Wp   = (const float*)d_in[14];
  const float* enc_bp   = (const float*)d_in[15];
  const float* convW_d  = (const float*)d_in[16];
  const float* convb_d  = (const float*)d_in[17];
  const float* convW_p  = (const float*)d_in[18];
  const float* convb_p  = (const float*)d_in[19];
  const float* bng_d    = (const float*)d_in[20];
  const float* bnb_d    = (const float*)d_in[21];
  const float* bng_p    = (const float*)d_in[22];
  const float* bnb_p    = (const float*)d_in[23];
  const float* vn_emb_d = (const float*)d_in[24];
  const float* vn_emb_p = (const float*)d_in[25];
  const float* vnW_d    = (const float*)d_in[26];
  const float* vnb_d    = (const float*)d_in[27];
  const float* vnW_p    = (const float*)d_in[28];
  const float* vnb_p    = (const float*)d_in[29];
  const float* mlpd1_W  = (const float*)d_in[30];
  const float* mlpd1_b  = (const float*)d_in[31];
  const float* mlpd1_g  = (const float*)d_in[32];
  const float* mlpd1_be = (const float*)d_in[33];
  const float* mlpp1_W  = (const float*)d_in[34];
  const float* mlpp1_b  = (const float*)d_in[35];
  const float* mlpp1_g  = (const float*)d_in[36];
  const float* mlpp1_be = (const float*)d_in[37];

  const int ND = in_sizes[5];
  const int ED = in_sizes[4] / 2;
  const int SD = in_sizes[6];
  const int NP = in_sizes[9];
  const int EP = in_sizes[8] / 2;
  const int SP = in_sizes[10];
  const int B  = in_sizes[2] / HID;
  (void)n_in; (void)out_size; (void)ws_size;

  char* wsb = (char*)d_ws;
  size_t off = 0;
  auto alloc = [&](size_t bytes) -> void* {
    void* p = (void*)(wsb + off);
    off = (off + bytes + 255) & ~(size_t)255;
    return p;
  };
  float* Ap   = (float*)alloc((size_t)NP * HID * 4);
  float* Bp   = (float*)alloc((size_t)NP * HID * 4);
  float* Cp   = (float*)alloc((size_t)NP * HID * 4);
  float* Adg  = (float*)alloc((size_t)ND * HID * 4);
  float* Bdg  = (float*)alloc((size_t)ND * HID * 4);
  float* Cdg  = (float*)alloc((size_t)ND * HID * 4);
  float* nrm_p = (float*)alloc((size_t)NP * 4);
  float* nrm_d = (float*)alloc((size_t)ND * 4);
  int* deg_p  = (int*)alloc((size_t)NP * 4);
  int* deg_d  = (int*)alloc((size_t)ND * 4);
  int* scnt_p = (int*)alloc((size_t)NP * 4);
  int* scnt_d = (int*)alloc((size_t)ND * 4);
  int* rowE_p = (int*)alloc((size_t)(NP + 1) * 4);
  int* rowE_d = (int*)alloc((size_t)(ND + 1) * 4);
  int* rowS_p = (int*)alloc((size_t)(NP + 1) * 4);
  int* rowS_d = (int*)alloc((size_t)(ND + 1) * 4);
  int* colE_p = (int*)alloc((size_t)EP * 4);
  float* cofE_p = (float*)alloc((size_t)EP * 4);
  int* colE_d = (int*)alloc((size_t)ED * 4);
  float* cofE_d = (float*)alloc((size_t)ED * 4);
  int* colS_p = (int*)alloc((size_t)SP * 4);
  int* colS_d = (int*)alloc((size_t)SD * 4);
  int* cur_p  = (int*)alloc((size_t)NP * 4);
  int* cur_d  = (int*)alloc((size_t)ND * 4);
  int* aux    = (int*)alloc(1024 * 4);
  float* vx_d  = (float*)alloc((size_t)B * HID * 4);
  float* vx_p  = (float*)alloc((size_t)B * HID * 4);
  float* sum_Sd = (float*)alloc((size_t)B * HID * 4);
  float* sum_Sp = (float*)alloc((size_t)B * HID * 4);
  float* A_d   = (float*)alloc((size_t)B * HID * 4);
  float* A_p   = (float*)alloc((size_t)B * HID * 4);
  float* nb_d  = (float*)alloc((size_t)B * 4);
  float* nb_p  = (float*)alloc((size_t)B * 4);
  float* stats_sl = (float*)alloc((size_t)NSLICE * 2 * HID * 4);
  float* statsF   = (float*)alloc(2 * HID * 4);
  float* fpre  = (float*)alloc((size_t)B * HID * 4);

  const int* d_src = d_ei;  const int* d_dst = d_ei + ED;
  const int* p_src = p_ei;  const int* p_dst = p_ei + EP;

  // ---- CSR build (loop-invariant) ----
  hipMemsetAsync(deg_p, 0, (size_t)NP * 4, stream);
  hipMemsetAsync(deg_d, 0, (size_t)ND * 4, stream);
  hipMemsetAsync(scnt_p, 0, (size_t)NP * 4, stream);
  hipMemsetAsync(scnt_d, 0, (size_t)ND * 4, stream);
  k_hist_i<<<1024, 256, 0, stream>>>(d_dst, deg_d, ED);
  k_hist_i<<<2048, 256, 0, stream>>>(p_dst, deg_p, EP);
  k_hist_i<<<1024, 256, 0, stream>>>(d_si, scnt_d, SD);
  k_hist_i<<<2048, 256, 0, stream>>>(p_si, scnt_p, SP);
  k_nrm<<<64, 256, 0, stream>>>(deg_d, nrm_d, ND);
  k_nrm<<<512, 256, 0, stream>>>(deg_p, nrm_p, NP);

  const int nbP = (NP + 1023) / 1024, nbD = (ND + 1023) / 1024;
  // edges protein
  k_scan1<<<nbP, 256, 0, stream>>>(deg_p, rowE_p, aux, NP);
  k_scan2<<<1, 256, 0, stream>>>(aux, nbP);
  k_scan3<<<256, 256, 0, stream>>>(rowE_p, aux, NP, EP);
  // edges drug
  k_scan1<<<nbD, 256, 0, stream>>>(deg_d, rowE_d, aux, ND);
  k_scan2<<<1, 256, 0, stream>>>(aux, nbD);
  k_scan3<<<64, 256, 0, stream>>>(rowE_d, aux, ND, ED);
  // subs protein
  k_scan1<<<nbP, 256, 0, stream>>>(scnt_p, rowS_p, aux, NP);
  k_scan2<<<1, 256, 0, stream>>>(aux, nbP);
  k_scan3<<<256, 256, 0, stream>>>(rowS_p, aux, NP, SP);
  // subs drug
  k_scan1<<<nbD, 256, 0, stream>>>(scnt_d, rowS_d, aux, ND);
  k_scan2<<<1, 256, 0, stream>>>(aux, nbD);
  k_scan3<<<64, 256, 0, stream>>>(rowS_d, aux, ND, SD);

  hipMemsetAsync(cur_p, 0, (size_t)NP * 4, stream);
  hipMemsetAsync(cur_d, 0, (size_t)ND * 4, stream);
  k_fill_edges<<<2048, 256, 0, stream>>>(p_src, p_dst, rowE_p, cur_p, colE_p, cofE_p, nrm_p, EP);
  k_fill_edges<<<1024, 256, 0, stream>>>(d_src, d_dst, rowE_d, cur_d, colE_d, cofE_d, nrm_d, ED);
  hipMemsetAsync(cur_p, 0, (size_t)NP * 4, stream);
  hipMemsetAsync(cur_d, 0, (size_t)ND * 4, stream);
  k_fill_sub<<<2048, 256, 0, stream>>>(p_sn, p_si, rowS_p, cur_p, colS_p, SP);
  k_fill_sub<<<1024, 256, 0, stream>>>(d_sn, d_si, rowS_d, cur_d, colS_d, SD);

  // ---- encoders + virtual node init ----
  k_node_linear<78, false, true><<<ND / 32, 128, 0, stream>>>(drug_x, enc_Wd, enc_bd, Adg, ND, nullptr, nullptr);
  k_node_linear<70, false, true><<<NP / 32, 128, 0, stream>>>(prot_x, enc_Wp, enc_bp, Ap, NP, nullptr, nullptr);
  k_vx_init<<<64, 256, 0, stream>>>(vn_emb_d, d_feat, vx_d, B * HID);
  k_vx_init<<<64, 256, 0, stream>>>(vn_emb_p, p_feat, vx_p, B * HID);

  float* curD = Adg; float* altD = Cdg;
  float* curP = Ap;  float* altP = Cp;

  for (int l = 0; l < 3; ++l) {
    // ---------- drug ----------
    k_node_linear<128, true, false><<<ND / 32, 128, 0, stream>>>(
        curD, convW_d + (size_t)l * HID * HID, nullptr, Bdg, ND, d_batch, vx_d);
    hipMemsetAsync(stats_sl, 0, (size_t)NSLICE * 2 * HID * 4, stream);
    k_gcn_gather<<<(ND + 7) / 8, 256, 0, stream>>>(rowE_d, colE_d, cofE_d, Bdg, nrm_d,
                                                   convb_d + l * HID, altD, stats_sl, ND);
    k_fold<<<1, 256, 0, stream>>>(stats_sl, statsF);
    k_bn_apply<true><<<2048, 256, 0, stream>>>(altD, altD, statsF, bng_d + l * HID, bnb_d + l * HID,
                                               ND * 32, 1.0f / (float)ND);
    k_sub_gather<<<(ND + 7) / 8, 256, 0, stream>>>(rowS_d, colS_d, altD, curD, ND);
    k_pool<<<B, 128, 0, stream>>>(curD, d_batch, ND, sum_Sd, nb_d);
    if (l < 2)
      k_vn_update<<<B, 128, 0, stream>>>(sum_Sd, vx_d, vnW_d + (size_t)l * HID * HID, vnb_d + l * HID);
    { float* t = curD; curD = altD; altD = t; }

    // ---------- protein ----------
    k_node_linear<128, true, false><<<NP / 32, 128, 0, stream>>>(
        curP, convW_p + (size_t)l * HID * HID, nullptr, Bp, NP, p_batch, vx_p);
    hipMemsetAsync(stats_sl, 0, (size_t)NSLICE * 2 * HID * 4, stream);
    k_gcn_gather<<<(NP + 7) / 8, 256, 0, stream>>>(rowE_p, colE_p, cofE_p, Bp, nrm_p,
                                                   convb_p + l * HID, altP, stats_sl, NP);
    k_fold<<<1, 256, 0, stream>>>(stats_sl, statsF);
    k_bn_apply<true><<<4096, 256, 0, stream>>>(altP, altP, statsF, bng_p + l * HID, bnb_p + l * HID,
                                               NP * 32, 1.0f / (float)NP);
    k_sub_gather<<<(NP + 7) / 8, 256, 0, stream>>>(rowS_p, colS_p, altP, curP, NP);
    k_pool<<<B, 128, 0, stream>>>(curP, p_batch, NP, sum_Sp, nb_p);
    if (l < 2)
      k_vn_update<<<B, 128, 0, stream>>>(sum_Sp, vx_p, vnW_p + (size_t)l * HID * HID, vnb_p + l * HID);
    { float* t = curP; curP = altP; altP = t; }
  }

  // ---- cross-modal sync collapses to pooled means; final MLP + BN ----
  k_final_A<<<B, 128, 0, stream>>>(sum_Sd, sum_Sp, nb_d, nb_p, A_d, A_p);

  float* outf = (float*)d_out;
  k_final_mlp<<<B, 128, 0, stream>>>(A_d, d_feat, mlpd1_W, mlpd1_b, fpre);
  hipMemsetAsync(statsF, 0, 2 * HID * 4, stream);
  k_bn_stats<<<128, 256, 0, stream>>>(fpre, statsF, B);
  k_bn_apply<false><<<64, 256, 0, stream>>>(fpre, outf, statsF, mlpd1_g, mlpd1_be,
                                            B * 32, 1.0f / (float)B);

  k_final_mlp<<<B, 128, 0, stream>>>(A_p, p_feat, mlpp1_W, mlpp1_b, fpre);
  hipMemsetAsync(statsF, 0, 2 * HID * 4, stream);
  k_bn_stats<<<128, 256, 0, stream>>>(fpre, statsF, B);
  k_bn_apply<false><<<64, 256, 0, stream>>>(fpre, outf + (size_t)B * HID, statsF, mlpp1_g, mlpp1_be,
                                            B * 32, 1.0f / (float)B);
}

// Round 3
// 1213.559 us; speedup vs baseline: 6.7682x; 1.6777x over previous
//
#include <hip/hip_runtime.h>
#include <cstdint>
#include <cstddef>

#define HID 128
#define NSLICE 32

// ---------------- device helpers ----------------
static __device__ __forceinline__ int lowerb(const int* __restrict__ a, int n, int v) {
  int lo = 0, hi = n;
  while (lo < hi) { int m = (lo + hi) >> 1; if (a[m] < v) lo = m + 1; else hi = m; }
  return lo;
}

// ---------------- CSR build ----------------
__global__ void k_hist_i(const int* __restrict__ idx, int* __restrict__ cnt, int n) {
  const int stride = gridDim.x * blockDim.x;
  for (int i = blockIdx.x * blockDim.x + threadIdx.x; i < n; i += stride)
    atomicAdd(&cnt[idx[i]], 1);
}

__global__ void k_nrm(const int* __restrict__ deg, float* __restrict__ nrm, int n) {
  const int stride = gridDim.x * blockDim.x;
  for (int i = blockIdx.x * blockDim.x + threadIdx.x; i < n; i += stride)
    nrm[i] = rsqrtf((float)deg[i] + 1.0f);
}

__global__ __launch_bounds__(256)
void k_scan1(const int* __restrict__ cnt, int* __restrict__ row, int* __restrict__ aux, int n) {
  __shared__ int sh[256];
  const int tid = threadIdx.x;
  const int base = blockIdx.x * 1024 + tid * 4;
  int v0 = base + 0 < n ? cnt[base + 0] : 0;
  int v1 = base + 1 < n ? cnt[base + 1] : 0;
  int v2 = base + 2 < n ? cnt[base + 2] : 0;
  int v3 = base + 3 < n ? cnt[base + 3] : 0;
  const int s = v0 + v1 + v2 + v3;
  sh[tid] = s;
  __syncthreads();
  for (int o = 1; o < 256; o <<= 1) {
    const int t = (tid >= o) ? sh[tid - o] : 0;
    __syncthreads();
    sh[tid] += t;
    __syncthreads();
  }
  int excl = sh[tid] - s;
  if (tid == 255) aux[blockIdx.x] = sh[255];
  if (base + 0 < n) row[base + 0] = excl; excl += v0;
  if (base + 1 < n) row[base + 1] = excl; excl += v1;
  if (base + 2 < n) row[base + 2] = excl; excl += v2;
  if (base + 3 < n) row[base + 3] = excl;
}

__global__ __launch_bounds__(256)
void k_scan2(int* __restrict__ aux, int nb) {
  __shared__ int sh[256];
  const int tid = threadIdx.x;
  const int v = tid < nb ? aux[tid] : 0;
  sh[tid] = v;
  __syncthreads();
  for (int o = 1; o < 256; o <<= 1) {
    const int t = (tid >= o) ? sh[tid - o] : 0;
    __syncthreads();
    sh[tid] += t;
    __syncthreads();
  }
  if (tid < nb) aux[tid] = sh[tid] - v;
}

__global__ void k_scan3(int* __restrict__ row, const int* __restrict__ aux, int n, int total) {
  const int stride = gridDim.x * blockDim.x;
  for (int i = blockIdx.x * blockDim.x + threadIdx.x; i < n; i += stride)
    row[i] += aux[i >> 10];
  if (blockIdx.x == 0 && threadIdx.x == 0) row[n] = total;
}

__global__ void k_fill_edges(const int* __restrict__ src, const int* __restrict__ dst,
                             const int* __restrict__ row, int* __restrict__ cur,
                             int* __restrict__ col, float* __restrict__ coef,
                             const float* __restrict__ nrm, int E) {
  const int stride = gridDim.x * blockDim.x;
  for (int e = blockIdx.x * blockDim.x + threadIdx.x; e < E; e += stride) {
    const int d = dst[e], s = src[e];
    const int pos = row[d] + atomicAdd(&cur[d], 1);
    col[pos] = s;
    coef[pos] = nrm[s] * nrm[d];
  }
}

__global__ void k_fill_sub(const int* __restrict__ sn, const int* __restrict__ si,
                           const int* __restrict__ row, int* __restrict__ cur,
                           int* __restrict__ col, int n) {
  const int stride = gridDim.x * blockDim.x;
  for (int j = blockIdx.x * blockDim.x + threadIdx.x; j < n; j += stride) {
    const int t = si[j];
    const int pos = row[t] + atomicAdd(&cur[t], 1);
    col[pos] = sn[j];
  }
}

// ---------------- misc ----------------
__global__ void k_vx_init(const float* __restrict__ emb, const float* __restrict__ feat,
                          float* __restrict__ vx, int total) {
  const int stride = gridDim.x * blockDim.x;
  for (int i = blockIdx.x * blockDim.x + threadIdx.x; i < total; i += stride)
    vx[i] = emb[i & (HID - 1)] + feat[i];
}

// ---------------- tiled fp32 GEMM: out[i][c] = sum_k f(X[i][k]) * W[k][c] ----------------
// f(x) = [BN_IN: relu(x*scale[k]+shift[k])] (+ vx[batch[i]][k]); optional bias on out.
// BM=128 nodes, BN=128 cols, BK k-slice; 256 threads, 8x8 micro-tile.
// N must be a multiple of 128 (holds: 16384, 131072).
template<int K, int BK, bool ADD_VX, bool HAS_BIAS, bool BN_IN>
__global__ __launch_bounds__(256, 4)
void k_gemm(const float* __restrict__ X, const float* __restrict__ W,
            const float* __restrict__ bias, float* __restrict__ out, int N,
            const int* __restrict__ batch, const float* __restrict__ vx,
            const float* __restrict__ scsh) {
  static_assert(K % BK == 0, "BK must divide K");
  constexpr int NSTEP = K / BK;
  __shared__ float Xl[BK][132];  // stride 132 words = 528B (16B aligned)
  __shared__ float Wl[BK][132];
  const int tid = threadIdx.x;
  const int base = blockIdx.x * 128;
  const int ng = tid & 15;   // node group: nodes ng*4..+3 and 64+ng*4..+3
  const int cg = tid >> 4;   // col group: cols cg*8..+7

  float acc[8][8];
  #pragma unroll
  for (int i = 0; i < 8; ++i)
    #pragma unroll
    for (int j = 0; j < 8; ++j) acc[i][j] = 0.f;

  for (int ks = 0; ks < NSTEP; ++ks) {
    __syncthreads();  // protect LDS reuse across steps
    // --- stage W chunk: rows ks*BK..+BK-1, contiguous in W ---
    {
      const float4* wsrc = (const float4*)(W + (size_t)ks * BK * HID);
      for (int i = tid; i < BK * 32; i += 256) {
        const int r = i >> 5, c4 = i & 31;
        *(float4*)&Wl[r][c4 * 4] = wsrc[i];
      }
    }
    // --- stage X chunk (transposed to k-major), fused BN+ReLU / +vx ---
    if constexpr (K == HID && BK == 32) {
      #pragma unroll
      for (int r = 0; r < 4; ++r) {
        const int i = r * 256 + tid;
        const int node = i >> 3, kq = i & 7;
        float4 v = ((const float4*)(X + (size_t)(base + node) * K + ks * 32))[kq];
        if constexpr (BN_IN) {
          const float4 sc = ((const float4*)scsh)[ks * 8 + kq];
          const float4 sf = ((const float4*)(scsh + HID))[ks * 8 + kq];
          v.x = fmaxf(v.x * sc.x + sf.x, 0.f);
          v.y = fmaxf(v.y * sc.y + sf.y, 0.f);
          v.z = fmaxf(v.z * sc.z + sf.z, 0.f);
          v.w = fmaxf(v.w * sc.w + sf.w, 0.f);
        }
        if constexpr (ADD_VX) {
          const float4 u = ((const float4*)(vx + (size_t)batch[base + node] * HID + ks * 32))[kq];
          v.x += u.x; v.y += u.y; v.z += u.z; v.w += u.w;
        }
        Xl[kq * 4 + 0][node] = v.x;
        Xl[kq * 4 + 1][node] = v.y;
        Xl[kq * 4 + 2][node] = v.z;
        Xl[kq * 4 + 3][node] = v.w;
      }
    } else {
      for (int i = tid; i < 128 * BK; i += 256) {
        const int node = i / BK, kk = i % BK;
        float v = X[(size_t)(base + node) * K + ks * BK + kk];
        if constexpr (BN_IN) v = fmaxf(v * scsh[ks * BK + kk] + scsh[HID + ks * BK + kk], 0.f);
        if constexpr (ADD_VX) v += vx[(size_t)batch[base + node] * HID + ks * BK + kk];
        Xl[kk][node] = v;
      }
    }
    __syncthreads();

    // --- compute ---
    #pragma unroll 4
    for (int kk = 0; kk < BK; ++kk) {
      const float4 x0 = *(const float4*)&Xl[kk][ng * 4];
      const float4 x1 = *(const float4*)&Xl[kk][64 + ng * 4];
      const float4 w0 = *(const float4*)&Wl[kk][cg * 8];
      const float4 w1 = *(const float4*)&Wl[kk][cg * 8 + 4];
      const float xs[8] = {x0.x, x0.y, x0.z, x0.w, x1.x, x1.y, x1.z, x1.w};
      const float ws[8] = {w0.x, w0.y, w0.z, w0.w, w1.x, w1.y, w1.z, w1.w};
      #pragma unroll
      for (int n = 0; n < 8; ++n)
        #pragma unroll
        for (int c = 0; c < 8; ++c)
          acc[n][c] += xs[n] * ws[c];
    }
  }

  // --- epilogue ---
  float4 b0 = {0, 0, 0, 0}, b1 = {0, 0, 0, 0};
  if constexpr (HAS_BIAS) {
    b0 = ((const float4*)bias)[cg * 2];
    b1 = ((const float4*)bias)[cg * 2 + 1];
  }
  #pragma unroll
  for (int n = 0; n < 8; ++n) {
    const int node = base + (n < 4 ? ng * 4 + n : 64 + ng * 4 + (n - 4));
    float* o = out + (size_t)node * HID + cg * 8;
    float4 v0 = {acc[n][0] + b0.x, acc[n][1] + b0.y, acc[n][2] + b0.z, acc[n][3] + b0.w};
    float4 v1 = {acc[n][4] + b1.x, acc[n][5] + b1.y, acc[n][6] + b1.z, acc[n][7] + b1.w};
    ((float4*)o)[0] = v0;
    ((float4*)o)[1] = v1;
  }
}

// GCN aggregation as CSR gather, fused self-term + bias + sliced BN-stats (on RAW output).
__global__ __launch_bounds__(256)
void k_gcn_gather(const int* __restrict__ row, const int* __restrict__ col,
                  const float* __restrict__ coef, const float* __restrict__ hw,
                  const float* __restrict__ nrm, const float* __restrict__ bias,
                  float* __restrict__ out, float* __restrict__ stats_sl, int N) {
  __shared__ float sh[8][HID];
  const int tid = threadIdx.x;
  const int grp = tid >> 5;
  const int c4 = tid & 31;
  const int node = blockIdx.x * 8 + grp;
  float4 acc = {0.f, 0.f, 0.f, 0.f};
  if (node < N) {
    const float nv = nrm[node];
    const float s2 = nv * nv;
    const float4 h = ((const float4*)(hw + (size_t)node * HID))[c4];
    const float4 b = ((const float4*)bias)[c4];
    acc.x = h.x * s2 + b.x; acc.y = h.y * s2 + b.y;
    acc.z = h.z * s2 + b.z; acc.w = h.w * s2 + b.w;
    const int lo = row[node], hi = row[node + 1];
    for (int e = lo; e < hi; ++e) {
      const int s = col[e];
      const float w = coef[e];
      const float4 v = ((const float4*)(hw + (size_t)s * HID))[c4];
      acc.x += v.x * w; acc.y += v.y * w; acc.z += v.z * w; acc.w += v.w * w;
    }
    ((float4*)(out + (size_t)node * HID))[c4] = acc;
  }
  ((float4*)&sh[grp][0])[c4] = acc;
  __syncthreads();
  if (tid < HID) {
    float s = 0.f, ss = 0.f;
    #pragma unroll
    for (int g = 0; g < 8; ++g) {
      const float v = sh[g][tid];
      s += v; ss += v * v;
    }
    float* base = stats_sl + (size_t)(blockIdx.x & (NSLICE - 1)) * (2 * HID);
    atomicAdd(&base[tid], s);
    atomicAdd(&base[HID + tid], ss);
  }
}

// fold stat slices -> per-channel scale/shift:  y = x*scale + shift == BN(x)
__global__ __launch_bounds__(128)
void k_bn_scale(const float* __restrict__ stats_sl, const float* __restrict__ g,
                const float* __restrict__ b, float invN, float* __restrict__ scsh) {
  const int c = threadIdx.x;
  float s = 0.f, ss = 0.f;
  for (int k = 0; k < NSLICE; ++k) {
    s += stats_sl[(size_t)k * (2 * HID) + c];
    ss += stats_sl[(size_t)k * (2 * HID) + HID + c];
  }
  const float m = s * invN;
  const float var = ss * invN - m * m;
  const float sc = g[c] * rsqrtf(var + 1e-5f);
  scsh[c] = sc;
  scsh[HID + c] = b[c] - m * sc;
}

// sub-graph mean gather with fused BN+ReLU on the gathered (raw) rows.
__global__ __launch_bounds__(256)
void k_sub_gather(const int* __restrict__ row, const int* __restrict__ col,
                  const float* __restrict__ H, const float* __restrict__ scsh,
                  float* __restrict__ S, int N) {
  const int tid = threadIdx.x;
  const int node = blockIdx.x * 8 + (tid >> 5);
  const int c4 = tid & 31;
  if (node >= N) return;
  const float4 sc = ((const float4*)scsh)[c4];
  const float4 sf = ((const float4*)(scsh + HID))[c4];
  const int lo = row[node], hi = row[node + 1];
  float4 acc = {0.f, 0.f, 0.f, 0.f};
  for (int e = lo; e < hi; ++e) {
    const int s = col[e];
    const float4 v = ((const float4*)(H + (size_t)s * HID))[c4];
    acc.x += fmaxf(v.x * sc.x + sf.x, 0.f);
    acc.y += fmaxf(v.y * sc.y + sf.y, 0.f);
    acc.z += fmaxf(v.z * sc.z + sf.z, 0.f);
    acc.w += fmaxf(v.w * sc.w + sf.w, 0.f);
  }
  const float inv = 1.0f / fmaxf((float)(hi - lo), 1.0f);
  acc.x *= inv; acc.y *= inv; acc.z *= inv; acc.w *= inv;
  ((float4*)(S + (size_t)node * HID))[c4] = acc;
}

// parallel per-batch pooling: 8 chunks per batch, then fold
__global__ __launch_bounds__(128)
void k_pool_part(const float* __restrict__ S, const int* __restrict__ batch, int N,
                 float* __restrict__ part, float* __restrict__ nb) {
  const int b = blockIdx.x >> 3, pc = blockIdx.x & 7, c = threadIdx.x;
  const int lo = lowerb(batch, N, b);
  const int hi = lowerb(batch, N, b + 1);
  const int len = hi - lo;
  const int s = lo + (len * pc) / 8;
  const int e = lo + (len * (pc + 1)) / 8;
  float a = 0.f;
  for (int i = s; i < e; ++i) a += S[(size_t)i * HID + c];
  part[(size_t)blockIdx.x * HID + c] = a;
  if (pc == 0 && c == 0) nb[b] = (float)len;
}

__global__ __launch_bounds__(128)
void k_pool_fold(const float* __restrict__ part, float* __restrict__ outSum) {
  const int b = blockIdx.x, c = threadIdx.x;
  float a = 0.f;
  #pragma unroll
  for (int pc = 0; pc < 8; ++pc) a += part[(size_t)(b * 8 + pc) * HID + c];
  outSum[(size_t)b * HID + c] = a;
}

__global__ __launch_bounds__(128)
void k_vn_update(const float* __restrict__ pooledSum, float* __restrict__ vx,
                 const float* __restrict__ W, const float* __restrict__ bias) {
  const int b = blockIdx.x, c = threadIdx.x;
  __shared__ float xin[HID];
  xin[c] = pooledSum[(size_t)b * HID + c] + vx[(size_t)b * HID + c];
  __syncthreads();
  float acc = bias[c];
  #pragma unroll 8
  for (int k = 0; k < HID; k += 4) {
    const float4 x = *(const float4*)&xin[k];
    acc += x.x * W[k * HID + c] + x.y * W[(k + 1) * HID + c]
         + x.z * W[(k + 2) * HID + c] + x.w * W[(k + 3) * HID + c];
  }
  vx[(size_t)b * HID + c] += fmaxf(acc, 0.0f);
}

__global__ __launch_bounds__(128)
void k_final_A(const float* __restrict__ sum_Sd, const float* __restrict__ sum_Sp,
               const float* __restrict__ nb_d, const float* __restrict__ nb_p,
               float* __restrict__ A_d, float* __restrict__ A_p) {
  const int b = blockIdx.x, c = threadIdx.x;
  const float nd = nb_d[b], np_ = nb_p[b];
  const float md = sum_Sd[(size_t)b * HID + c] / fmaxf(nd, 1.f);
  const float mp = sum_Sp[(size_t)b * HID + c] / fmaxf(np_, 1.f);
  A_d[(size_t)b * HID + c] = md + (nd > 0.f ? mp : 0.f);
  A_p[(size_t)b * HID + c] = mp + (np_ > 0.f ? md : 0.f);
}

__global__ __launch_bounds__(128)
void k_final_mlp(const float* __restrict__ A, const float* __restrict__ feat,
                 const float* __restrict__ W, const float* __restrict__ bias,
                 float* __restrict__ out) {
  const int b = blockIdx.x, c = threadIdx.x;
  __shared__ float xin[2 * HID];
  xin[c] = A[(size_t)b * HID + c];
  xin[HID + c] = feat[(size_t)b * HID + c];
  __syncthreads();
  float acc = bias[c];
  #pragma unroll 8
  for (int k = 0; k < 2 * HID; k += 4) {
    const float4 x = *(const float4*)&xin[k];
    acc += x.x * W[k * HID + c] + x.y * W[(k + 1) * HID + c]
         + x.z * W[(k + 2) * HID + c] + x.w * W[(k + 3) * HID + c];
  }
  out[(size_t)b * HID + c] = acc;
}

__global__ __launch_bounds__(256)
void k_bn_stats(const float* __restrict__ X, float* __restrict__ stats, int N) {
  __shared__ float sh[2][256];
  const int tid = threadIdx.x;
  const int c = tid & (HID - 1);
  const int half = tid >> 7;
  float s = 0.f, ss = 0.f;
  for (int r = blockIdx.x * 2 + half; r < N; r += gridDim.x * 2) {
    const float v = X[(size_t)r * HID + c];
    s += v; ss += v * v;
  }
  sh[0][tid] = s; sh[1][tid] = ss;
  __syncthreads();
  if (tid < HID) {
    atomicAdd(&stats[c], sh[0][tid] + sh[0][tid + 128]);
    atomicAdd(&stats[HID + c], sh[1][tid] + sh[1][tid + 128]);
  }
}

template<bool RELU>
__global__ void k_bn_apply(const float* __restrict__ X, float* __restrict__ Y,
                           const float* __restrict__ stats, const float* __restrict__ g,
                           const float* __restrict__ b, int n4, float invN) {
  const int stride = gridDim.x * blockDim.x;
  for (int i = blockIdx.x * blockDim.x + threadIdx.x; i < n4; i += stride) {
    const int c4 = i & 31;
    const float4 m4 = ((const float4*)stats)[c4];
    const float4 q4 = ((const float4*)stats)[32 + c4];
    const float4 g4 = ((const float4*)g)[c4];
    const float4 b4 = ((const float4*)b)[c4];
    float4 v = ((const float4*)X)[i];
    float m, va;
    m = m4.x * invN; va = q4.x * invN - m * m; v.x = (v.x - m) * rsqrtf(va + 1e-5f) * g4.x + b4.x;
    m = m4.y * invN; va = q4.y * invN - m * m; v.y = (v.y - m) * rsqrtf(va + 1e-5f) * g4.y + b4.y;
    m = m4.z * invN; va = q4.z * invN - m * m; v.z = (v.z - m) * rsqrtf(va + 1e-5f) * g4.z + b4.z;
    m = m4.w * invN; va = q4.w * invN - m * m; v.w = (v.w - m) * rsqrtf(va + 1e-5f) * g4.w + b4.w;
    if (RELU) {
      v.x = fmaxf(v.x, 0.f); v.y = fmaxf(v.y, 0.f); v.z = fmaxf(v.z, 0.f); v.w = fmaxf(v.w, 0.f);
    }
    ((float4*)Y)[i] = v;
  }
}

// ---------------- host launch ----------------
extern "C" void kernel_launch(void* const* d_in, const int* in_sizes, int n_in,
                              void* d_out, int out_size, void* d_ws, size_t ws_size,
                              hipStream_t stream) {
  const float* drug_x   = (const float*)d_in[0];
  const float* prot_x   = (const float*)d_in[1];
  const float* d_feat   = (const float*)d_in[2];
  const float* p_feat   = (const float*)d_in[3];
  const int*   d_ei     = (const int*)d_in[4];
  const int*   d_batch  = (const int*)d_in[5];
  const int*   d_sn     = (const int*)d_in[6];
  const int*   d_si     = (const int*)d_in[7];
  const int*   p_ei     = (const int*)d_in[8];
  const int*   p_batch  = (const int*)d_in[9];
  const int*   p_sn     = (const int*)d_in[10];
  const int*   p_si     = (const int*)d_in[11];
  const float* enc_Wd   = (const float*)d_in[12];
  const float* enc_bd   = (const float*)d_in[13];
  const float* enc_Wp   = (const float*)d_in[14];
  const float* enc_bp   = (const float*)d_in[15];
  const float* convW_d  = (const float*)d_in[16];
  const float* convb_d  = (const float*)d_in[17];
  const float* convW_p  = (const float*)d_in[18];
  const float* convb_p  = (const float*)d_in[19];
  const float* bng_d    = (const float*)d_in[20];
  const float* bnb_d    = (const float*)d_in[21];
  const float* bng_p    = (const float*)d_in[22];
  const float* bnb_p    = (const float*)d_in[23];
  const float* vn_emb_d = (const float*)d_in[24];
  const float* vn_emb_p = (const float*)d_in[25];
  const float* vnW_d    = (const float*)d_in[26];
  const float* vnb_d    = (const float*)d_in[27];
  const float* vnW_p    = (const float*)d_in[28];
  const float* vnb_p    = (const float*)d_in[29];
  const float* mlpd1_W  = (const float*)d_in[30];
  const float* mlpd1_b  = (const float*)d_in[31];
  const float* mlpd1_g  = (const float*)d_in[32];
  const float* mlpd1_be = (const float*)d_in[33];
  const float* mlpp1_W  = (const float*)d_in[34];
  const float* mlpp1_b  = (const float*)d_in[35];
  const float* mlpp1_g  = (const float*)d_in[36];
  const float* mlpp1_be = (const float*)d_in[37];

  const int ND = in_sizes[5];
  const int ED = in_sizes[4] / 2;
  const int SD = in_sizes[6];
  const int NP = in_sizes[9];
  const int EP = in_sizes[8] / 2;
  const int SP = in_sizes[10];
  const int B  = in_sizes[2] / HID;
  (void)n_in; (void)out_size; (void)ws_size;

  char* wsb = (char*)d_ws;
  size_t off = 0;
  auto alloc = [&](size_t bytes) -> void* {
    void* p = (void*)(wsb + off);
    off = (off + bytes + 255) & ~(size_t)255;
    return p;
  };
  float* Ap   = (float*)alloc((size_t)NP * HID * 4);
  float* Bp   = (float*)alloc((size_t)NP * HID * 4);
  float* Cp   = (float*)alloc((size_t)NP * HID * 4);
  float* Adg  = (float*)alloc((size_t)ND * HID * 4);
  float* Bdg  = (float*)alloc((size_t)ND * HID * 4);
  float* Cdg  = (float*)alloc((size_t)ND * HID * 4);
  float* nrm_p = (float*)alloc((size_t)NP * 4);
  float* nrm_d = (float*)alloc((size_t)ND * 4);
  int* deg_p  = (int*)alloc((size_t)NP * 4);
  int* deg_d  = (int*)alloc((size_t)ND * 4);
  int* scnt_p = (int*)alloc((size_t)NP * 4);
  int* scnt_d = (int*)alloc((size_t)ND * 4);
  int* rowE_p = (int*)alloc((size_t)(NP + 1) * 4);
  int* rowE_d = (int*)alloc((size_t)(ND + 1) * 4);
  int* rowS_p = (int*)alloc((size_t)(NP + 1) * 4);
  int* rowS_d = (int*)alloc((size_t)(ND + 1) * 4);
  int* colE_p = (int*)alloc((size_t)EP * 4);
  float* cofE_p = (float*)alloc((size_t)EP * 4);
  int* colE_d = (int*)alloc((size_t)ED * 4);
  float* cofE_d = (float*)alloc((size_t)ED * 4);
  int* colS_p = (int*)alloc((size_t)SP * 4);
  int* colS_d = (int*)alloc((size_t)SD * 4);
  int* cur_p  = (int*)alloc((size_t)NP * 4);
  int* cur_d  = (int*)alloc((size_t)ND * 4);
  int* aux    = (int*)alloc(1024 * 4);
  float* vx_d  = (float*)alloc((size_t)B * HID * 4);
  float* vx_p  = (float*)alloc((size_t)B * HID * 4);
  float* sum_Sd = (float*)alloc((size_t)B * HID * 4);
  float* sum_Sp = (float*)alloc((size_t)B * HID * 4);
  float* A_d   = (float*)alloc((size_t)B * HID * 4);
  float* A_p   = (float*)alloc((size_t)B * HID * 4);
  float* nb_d  = (float*)alloc((size_t)B * 4);
  float* nb_p  = (float*)alloc((size_t)B * 4);
  float* stats_sl = (float*)alloc((size_t)NSLICE * 2 * HID * 4);
  float* statsF   = (float*)alloc(2 * HID * 4);
  float* scsh_d = (float*)alloc(2 * HID * 4);
  float* scsh_p = (float*)alloc(2 * HID * 4);
  float* part  = (float*)alloc((size_t)B * 8 * HID * 4);
  float* fpre  = (float*)alloc((size_t)B * HID * 4);

  const int* d_src = d_ei;  const int* d_dst = d_ei + ED;
  const int* p_src = p_ei;  const int* p_dst = p_ei + EP;

  // ---- CSR build (loop-invariant) ----
  hipMemsetAsync(deg_p, 0, (size_t)NP * 4, stream);
  hipMemsetAsync(deg_d, 0, (size_t)ND * 4, stream);
  hipMemsetAsync(scnt_p, 0, (size_t)NP * 4, stream);
  hipMemsetAsync(scnt_d, 0, (size_t)ND * 4, stream);
  k_hist_i<<<1024, 256, 0, stream>>>(d_dst, deg_d, ED);
  k_hist_i<<<2048, 256, 0, stream>>>(p_dst, deg_p, EP);
  k_hist_i<<<1024, 256, 0, stream>>>(d_si, scnt_d, SD);
  k_hist_i<<<2048, 256, 0, stream>>>(p_si, scnt_p, SP);
  k_nrm<<<64, 256, 0, stream>>>(deg_d, nrm_d, ND);
  k_nrm<<<512, 256, 0, stream>>>(deg_p, nrm_p, NP);

  const int nbP = (NP + 1023) / 1024, nbD = (ND + 1023) / 1024;
  k_scan1<<<nbP, 256, 0, stream>>>(deg_p, rowE_p, aux, NP);
  k_scan2<<<1, 256, 0, stream>>>(aux, nbP);
  k_scan3<<<256, 256, 0, stream>>>(rowE_p, aux, NP, EP);
  k_scan1<<<nbD, 256, 0, stream>>>(deg_d, rowE_d, aux, ND);
  k_scan2<<<1, 256, 0, stream>>>(aux, nbD);
  k_scan3<<<64, 256, 0, stream>>>(rowE_d, aux, ND, ED);
  k_scan1<<<nbP, 256, 0, stream>>>(scnt_p, rowS_p, aux, NP);
  k_scan2<<<1, 256, 0, stream>>>(aux, nbP);
  k_scan3<<<256, 256, 0, stream>>>(rowS_p, aux, NP, SP);
  k_scan1<<<nbD, 256, 0, stream>>>(scnt_d, rowS_d, aux, ND);
  k_scan2<<<1, 256, 0, stream>>>(aux, nbD);
  k_scan3<<<64, 256, 0, stream>>>(rowS_d, aux, ND, SD);

  hipMemsetAsync(cur_p, 0, (size_t)NP * 4, stream);
  hipMemsetAsync(cur_d, 0, (size_t)ND * 4, stream);
  k_fill_edges<<<2048, 256, 0, stream>>>(p_src, p_dst, rowE_p, cur_p, colE_p, cofE_p, nrm_p, EP);
  k_fill_edges<<<1024, 256, 0, stream>>>(d_src, d_dst, rowE_d, cur_d, colE_d, cofE_d, nrm_d, ED);
  hipMemsetAsync(cur_p, 0, (size_t)NP * 4, stream);
  hipMemsetAsync(cur_d, 0, (size_t)ND * 4, stream);
  k_fill_sub<<<2048, 256, 0, stream>>>(p_sn, p_si, rowS_p, cur_p, colS_p, SP);
  k_fill_sub<<<1024, 256, 0, stream>>>(d_sn, d_si, rowS_d, cur_d, colS_d, SD);

  // ---- encoders + virtual node init ----
  k_gemm<78, 39, false, true, false><<<ND / 128, 256, 0, stream>>>(
      drug_x, enc_Wd, enc_bd, Adg, ND, nullptr, nullptr, nullptr);
  k_gemm<70, 35, false, true, false><<<NP / 128, 256, 0, stream>>>(
      prot_x, enc_Wp, enc_bp, Ap, NP, nullptr, nullptr, nullptr);
  k_vx_init<<<64, 256, 0, stream>>>(vn_emb_d, d_feat, vx_d, B * HID);
  k_vx_init<<<64, 256, 0, stream>>>(vn_emb_p, p_feat, vx_p, B * HID);

  float* curD = Adg; float* altD = Cdg;
  float* curP = Ap;  float* altP = Cp;

  for (int l = 0; l < 3; ++l) {
    // ---------- drug ----------
    if (l == 0)
      k_gemm<128, 32, true, false, false><<<ND / 128, 256, 0, stream>>>(
          curD, convW_d + (size_t)l * HID * HID, nullptr, Bdg, ND, d_batch, vx_d, nullptr);
    else
      k_gemm<128, 32, true, false, true><<<ND / 128, 256, 0, stream>>>(
          curD, convW_d + (size_t)l * HID * HID, nullptr, Bdg, ND, d_batch, vx_d, scsh_d);
    hipMemsetAsync(stats_sl, 0, (size_t)NSLICE * 2 * HID * 4, stream);
    k_gcn_gather<<<(ND + 7) / 8, 256, 0, stream>>>(rowE_d, colE_d, cofE_d, Bdg, nrm_d,
                                                   convb_d + l * HID, altD, stats_sl, ND);
    k_bn_scale<<<1, 128, 0, stream>>>(stats_sl, bng_d + l * HID, bnb_d + l * HID,
                                      1.0f / (float)ND, scsh_d);
    k_sub_gather<<<(ND + 7) / 8, 256, 0, stream>>>(rowS_d, colS_d, altD, scsh_d, curD, ND);
    k_pool_part<<<B * 8, 128, 0, stream>>>(curD, d_batch, ND, part, nb_d);
    k_pool_fold<<<B, 128, 0, stream>>>(part, sum_Sd);
    if (l < 2)
      k_vn_update<<<B, 128, 0, stream>>>(sum_Sd, vx_d, vnW_d + (size_t)l * HID * HID, vnb_d + l * HID);
    { float* t = curD; curD = altD; altD = t; }

    // ---------- protein ----------
    if (l == 0)
      k_gemm<128, 32, true, false, false><<<NP / 128, 256, 0, stream>>>(
          curP, convW_p + (size_t)l * HID * HID, nullptr, Bp, NP, p_batch, vx_p, nullptr);
    else
      k_gemm<128, 32, true, false, true><<<NP / 128, 256, 0, stream>>>(
          curP, convW_p + (size_t)l * HID * HID, nullptr, Bp, NP, p_batch, vx_p, scsh_p);
    hipMemsetAsync(stats_sl, 0, (size_t)NSLICE * 2 * HID * 4, stream);
    k_gcn_gather<<<(NP + 7) / 8, 256, 0, stream>>>(rowE_p, colE_p, cofE_p, Bp, nrm_p,
                                                   convb_p + l * HID, altP, stats_sl, NP);
    k_bn_scale<<<1, 128, 0, stream>>>(stats_sl, bng_p + l * HID, bnb_p + l * HID,
                                      1.0f / (float)NP, scsh_p);
    k_sub_gather<<<(NP + 7) / 8, 256, 0, stream>>>(rowS_p, colS_p, altP, scsh_p, curP, NP);
    k_pool_part<<<B * 8, 128, 0, stream>>>(curP, p_batch, NP, part, nb_p);
    k_pool_fold<<<B, 128, 0, stream>>>(part, sum_Sp);
    if (l < 2)
      k_vn_update<<<B, 128, 0, stream>>>(sum_Sp, vx_p, vnW_p + (size_t)l * HID * HID, vnb_p + l * HID);
    { float* t = curP; curP = altP; altP = t; }
  }

  // ---- cross-modal sync collapses to pooled means; final MLP + BN ----
  k_final_A<<<B, 128, 0, stream>>>(sum_Sd, sum_Sp, nb_d, nb_p, A_d, A_p);

  float* outf = (float*)d_out;
  k_final_mlp<<<B, 128, 0, stream>>>(A_d, d_feat, mlpd1_W, mlpd1_b, fpre);
  hipMemsetAsync(statsF, 0, 2 * HID * 4, stream);
  k_bn_stats<<<128, 256, 0, stream>>>(fpre, statsF, B);
  k_bn_apply<false><<<64, 256, 0, stream>>>(fpre, outf, statsF, mlpd1_g, mlpd1_be,
                                            B * 32, 1.0f / (float)B);

  k_final_mlp<<<B, 128, 0, stream>>>(A_p, p_feat, mlpp1_W, mlpp1_b, fpre);
  hipMemsetAsync(statsF, 0, 2 * HID * 4, stream);
  k_bn_stats<<<128, 256, 0, stream>>>(fpre, statsF, B);
  k_bn_apply<false><<<64, 256, 0, stream>>>(fpre, outf + (size_t)B * HID, statsF, mlpp1_g, mlpp1_be,
                                            B * 32, 1.0f / (float)B);
}

// Round 6
// 1099.508 us; speedup vs baseline: 7.4703x; 1.1037x over previous
//
#include <hip/hip_runtime.h>
#include <cstdint>
#include <cstddef>

#define HID 128
#define NSLICE 32

using bf16x8 = __attribute__((ext_vector_type(8))) short;
using f32x4v = __attribute__((ext_vector_type(4))) float;

// ---------------- bf16 helpers (RNE) ----------------
static __device__ __forceinline__ unsigned short f2b(float x) {
  unsigned int u = __float_as_uint(x);
  unsigned int r = u + 0x7FFFu + ((u >> 16) & 1u);
  return (unsigned short)(r >> 16);
}
static __device__ __forceinline__ float b2f(unsigned short h) {
  return __uint_as_float(((unsigned int)h) << 16);
}

static __device__ __forceinline__ int lowerb(const int* __restrict__ a, int n, int v) {
  int lo = 0, hi = n;
  while (lo < hi) { int m = (lo + hi) >> 1; if (a[m] < v) lo = m + 1; else hi = m; }
  return lo;
}

// ---------------- CSR build ----------------
__global__ void k_hist_i(const int* __restrict__ idx, int* __restrict__ cnt, int n) {
  const int stride = gridDim.x * blockDim.x;
  for (int i = blockIdx.x * blockDim.x + threadIdx.x; i < n; i += stride)
    atomicAdd(&cnt[idx[i]], 1);
}

__global__ void k_nrm(const int* __restrict__ deg, float* __restrict__ nrm, int n) {
  const int stride = gridDim.x * blockDim.x;
  for (int i = blockIdx.x * blockDim.x + threadIdx.x; i < n; i += stride)
    nrm[i] = rsqrtf((float)deg[i] + 1.0f);
}

__global__ __launch_bounds__(256)
void k_scan1(const int* __restrict__ cnt, int* __restrict__ row, int* __restrict__ aux, int n) {
  __shared__ int sh[256];
  const int tid = threadIdx.x;
  const int base = blockIdx.x * 1024 + tid * 4;
  int v0 = base + 0 < n ? cnt[base + 0] : 0;
  int v1 = base + 1 < n ? cnt[base + 1] : 0;
  int v2 = base + 2 < n ? cnt[base + 2] : 0;
  int v3 = base + 3 < n ? cnt[base + 3] : 0;
  const int s = v0 + v1 + v2 + v3;
  sh[tid] = s;
  __syncthreads();
  for (int o = 1; o < 256; o <<= 1) {
    const int t = (tid >= o) ? sh[tid - o] : 0;
    __syncthreads();
    sh[tid] += t;
    __syncthreads();
  }
  int excl = sh[tid] - s;
  if (tid == 255) aux[blockIdx.x] = sh[255];
  if (base + 0 < n) row[base + 0] = excl; excl += v0;
  if (base + 1 < n) row[base + 1] = excl; excl += v1;
  if (base + 2 < n) row[base + 2] = excl; excl += v2;
  if (base + 3 < n) row[base + 3] = excl;
}

__global__ __launch_bounds__(256)
void k_scan2(int* __restrict__ aux, int nb) {
  __shared__ int sh[256];
  const int tid = threadIdx.x;
  const int v = tid < nb ? aux[tid] : 0;
  sh[tid] = v;
  __syncthreads();
  for (int o = 1; o < 256; o <<= 1) {
    const int t = (tid >= o) ? sh[tid - o] : 0;
    __syncthreads();
    sh[tid] += t;
    __syncthreads();
  }
  if (tid < nb) aux[tid] = sh[tid] - v;
}

__global__ void k_scan3(int* __restrict__ row, const int* __restrict__ aux, int n, int total) {
  const int stride = gridDim.x * blockDim.x;
  for (int i = blockIdx.x * blockDim.x + threadIdx.x; i < n; i += stride)
    row[i] += aux[i >> 10];
  if (blockIdx.x == 0 && threadIdx.x == 0) row[n] = total;
}

__global__ void k_fill_edges(const int* __restrict__ src, const int* __restrict__ dst,
                             const int* __restrict__ row, int* __restrict__ cur,
                             int* __restrict__ col, float* __restrict__ coef,
                             const float* __restrict__ nrm, int E) {
  const int stride = gridDim.x * blockDim.x;
  for (int e = blockIdx.x * blockDim.x + threadIdx.x; e < E; e += stride) {
    const int d = dst[e], s = src[e];
    const int pos = row[d] + atomicAdd(&cur[d], 1);
    col[pos] = s;
    coef[pos] = nrm[s] * nrm[d];
  }
}

__global__ void k_fill_sub(const int* __restrict__ sn, const int* __restrict__ si,
                           const int* __restrict__ row, int* __restrict__ cur,
                           int* __restrict__ col, int n) {
  const int stride = gridDim.x * blockDim.x;
  for (int j = blockIdx.x * blockDim.x + threadIdx.x; j < n; j += stride) {
    const int t = si[j];
    const int pos = row[t] + atomicAdd(&cur[t], 1);
    col[pos] = sn[j];
  }
}

// ---------------- misc ----------------
__global__ void k_vx_init(const float* __restrict__ emb, const float* __restrict__ feat,
                          float* __restrict__ vx, int total) {
  const int stride = gridDim.x * blockDim.x;
  for (int i = blockIdx.x * blockDim.x + threadIdx.x; i < total; i += stride)
    vx[i] = emb[i & (HID - 1)] + feat[i];
}

// transpose+convert conv weights (split): Whi/Wlo [c][k] bf16 from W[k][c] fp32
__global__ __launch_bounds__(256)
void k_wcvt(const float* __restrict__ Wd, const float* __restrict__ Wp,
            unsigned short* __restrict__ WhiAll, unsigned short* __restrict__ WloAll) {
  const float* W = blockIdx.x < 3 ? Wd + (size_t)blockIdx.x * HID * HID
                                  : Wp + (size_t)(blockIdx.x - 3) * HID * HID;
  unsigned short* Whi = WhiAll + (size_t)blockIdx.x * HID * HID;
  unsigned short* Wlo = WloAll + (size_t)blockIdx.x * HID * HID;
  for (int i = threadIdx.x; i < HID * HID; i += 256) {
    const int c = i >> 7, k = i & 127;
    const float v = W[k * HID + c];
    const unsigned short hi = f2b(v);
    Whi[i] = hi;
    Wlo[i] = f2b(v - b2f(hi));
  }
}

// ---------------- fp32 encoder GEMM (K=78/70), fp32 output ----------------
template<int K, int BK>
__global__ __launch_bounds__(256, 4)
void k_gemm_enc(const float* __restrict__ X, const float* __restrict__ W,
                const float* __restrict__ bias, float* __restrict__ out, int N) {
  static_assert(K % BK == 0, "BK must divide K");
  constexpr int NSTEP = K / BK;
  __shared__ float Xl[BK][132];
  __shared__ float Wl[BK][132];
  const int tid = threadIdx.x;
  const int base = blockIdx.x * 128;
  const int ng = tid & 15;
  const int cg = tid >> 4;

  float acc[8][8];
  #pragma unroll
  for (int i = 0; i < 8; ++i)
    #pragma unroll
    for (int j = 0; j < 8; ++j) acc[i][j] = 0.f;

  for (int ks = 0; ks < NSTEP; ++ks) {
    __syncthreads();
    {
      const float4* wsrc = (const float4*)(W + (size_t)ks * BK * HID);
      for (int i = tid; i < BK * 32; i += 256) {
        const int r = i >> 5, c4 = i & 31;
        *(float4*)&Wl[r][c4 * 4] = wsrc[i];
      }
    }
    for (int i = tid; i < 128 * BK; i += 256) {
      const int node = i / BK, kk = i % BK;
      Xl[kk][node] = X[(size_t)(base + node) * K + ks * BK + kk];
    }
    __syncthreads();

    #pragma unroll 4
    for (int kk = 0; kk < BK; ++kk) {
      const float4 x0 = *(const float4*)&Xl[kk][ng * 4];
      const float4 x1 = *(const float4*)&Xl[kk][64 + ng * 4];
      const float4 w0 = *(const float4*)&Wl[kk][cg * 8];
      const float4 w1 = *(const float4*)&Wl[kk][cg * 8 + 4];
      const float xs[8] = {x0.x, x0.y, x0.z, x0.w, x1.x, x1.y, x1.z, x1.w};
      const float ws[8] = {w0.x, w0.y, w0.z, w0.w, w1.x, w1.y, w1.z, w1.w};
      #pragma unroll
      for (int n = 0; n < 8; ++n)
        #pragma unroll
        for (int c = 0; c < 8; ++c)
          acc[n][c] += xs[n] * ws[c];
    }
  }

  const float4 b0 = ((const float4*)bias)[cg * 2];
  const float4 b1 = ((const float4*)bias)[cg * 2 + 1];
  #pragma unroll
  for (int n = 0; n < 8; ++n) {
    const int node = base + (n < 4 ? ng * 4 + n : 64 + ng * 4 + (n - 4));
    float* o = out + (size_t)node * HID + cg * 8;
    float4 v0 = {acc[n][0] + b0.x, acc[n][1] + b0.y, acc[n][2] + b0.z, acc[n][3] + b0.w};
    float4 v1 = {acc[n][4] + b1.x, acc[n][5] + b1.y, acc[n][6] + b1.z, acc[n][7] + b1.w};
    ((float4*)o)[0] = v0;
    ((float4*)o)[1] = v1;
  }
}

// ---------------- split-bf16 MFMA GEMM: G = Z @ W, K=N=128, near-fp32 ----------------
// G ≈ Zhi·Whi + Zhi·Wlo + Zlo·Whi (Zlo·Wlo ~2^-16 rel, omitted).
// 128 rows/block, 4 waves; A from global; W staged in ONE LDS buffer, two phases (hi then lo).
// fp32 output + fused per-column BN stats into stats_sl slices.
__global__ __launch_bounds__(256, 2)
void k_gemm_mfma(const unsigned short* __restrict__ Zhi, const unsigned short* __restrict__ Zlo,
                 const unsigned short* __restrict__ Wthi, const unsigned short* __restrict__ Wtlo,
                 float* __restrict__ G, float* __restrict__ stats_sl, int N) {
  __shared__ unsigned short Bt[128 * 132];  // stride 132 shorts: 16 rows -> banks 2*l, conflict-free
  __shared__ float lstats[256];
  const int tid = threadIdx.x;
  const int w = tid >> 6;
  const int l = tid & 63;
  const int l15 = l & 15;
  const int kb = l >> 4;  // 0..3

  // phase 1: stage Whi
  for (int i = tid; i < 128 * 16; i += 256) {
    const int c = i >> 4, k8 = i & 15;
    *(bf16x8*)(&Bt[c * 132 + k8 * 8]) = *(const bf16x8*)(Wthi + (size_t)c * 128 + k8 * 8);
  }
  lstats[tid] = 0.f;

  // A fragments from global: row = rbase + rt*16, k = ks*32 + kb*8 + j
  const int rbase = blockIdx.x * 128 + w * 32 + l15;
  bf16x8 ahi[2][4], alo[2][4];
  #pragma unroll
  for (int rt = 0; rt < 2; ++rt)
    #pragma unroll
    for (int ks = 0; ks < 4; ++ks) {
      ahi[rt][ks] = *(const bf16x8*)(Zhi + (size_t)(rbase + rt * 16) * 128 + ks * 32 + kb * 8);
      alo[rt][ks] = *(const bf16x8*)(Zlo + (size_t)(rbase + rt * 16) * 128 + ks * 32 + kb * 8);
    }

  f32x4v acc[2][8];
  #pragma unroll
  for (int rt = 0; rt < 2; ++rt)
    #pragma unroll
    for (int ct = 0; ct < 8; ++ct)
      acc[rt][ct] = (f32x4v){0.f, 0.f, 0.f, 0.f};

  __syncthreads();
  #pragma unroll
  for (int ks = 0; ks < 4; ++ks) {
    #pragma unroll
    for (int ct = 0; ct < 8; ++ct) {
      const bf16x8 b = *(const bf16x8*)(&Bt[(ct * 16 + l15) * 132 + ks * 32 + kb * 8]);
      acc[0][ct] = __builtin_amdgcn_mfma_f32_16x16x32_bf16(ahi[0][ks], b, acc[0][ct], 0, 0, 0);
      acc[1][ct] = __builtin_amdgcn_mfma_f32_16x16x32_bf16(ahi[1][ks], b, acc[1][ct], 0, 0, 0);
      acc[0][ct] = __builtin_amdgcn_mfma_f32_16x16x32_bf16(alo[0][ks], b, acc[0][ct], 0, 0, 0);
      acc[1][ct] = __builtin_amdgcn_mfma_f32_16x16x32_bf16(alo[1][ks], b, acc[1][ct], 0, 0, 0);
    }
  }
  __syncthreads();

  // phase 2: stage Wlo, add Zhi·Wlo
  for (int i = tid; i < 128 * 16; i += 256) {
    const int c = i >> 4, k8 = i & 15;
    *(bf16x8*)(&Bt[c * 132 + k8 * 8]) = *(const bf16x8*)(Wtlo + (size_t)c * 128 + k8 * 8);
  }
  __syncthreads();
  #pragma unroll
  for (int ks = 0; ks < 4; ++ks) {
    #pragma unroll
    for (int ct = 0; ct < 8; ++ct) {
      const bf16x8 b = *(const bf16x8*)(&Bt[(ct * 16 + l15) * 132 + ks * 32 + kb * 8]);
      acc[0][ct] = __builtin_amdgcn_mfma_f32_16x16x32_bf16(ahi[0][ks], b, acc[0][ct], 0, 0, 0);
      acc[1][ct] = __builtin_amdgcn_mfma_f32_16x16x32_bf16(ahi[1][ks], b, acc[1][ct], 0, 0, 0);
    }
  }

  // store + per-column stats. C/D layout: col = l&15, row = (l>>4)*4 + j.
  float csum[8], csq[8];
  #pragma unroll
  for (int ct = 0; ct < 8; ++ct) { csum[ct] = 0.f; csq[ct] = 0.f; }
  #pragma unroll
  for (int rt = 0; rt < 2; ++rt) {
    const size_t grow = (size_t)blockIdx.x * 128 + w * 32 + rt * 16 + (l >> 4) * 4;
    #pragma unroll
    for (int j = 0; j < 4; ++j) {
      float* gr = G + (grow + j) * 128 + l15;
      #pragma unroll
      for (int ct = 0; ct < 8; ++ct) {
        const float v = acc[rt][ct][j];
        gr[ct * 16] = v;
        csum[ct] += v;
        csq[ct] += v * v;
      }
    }
  }
  #pragma unroll
  for (int ct = 0; ct < 8; ++ct) {
    csum[ct] += __shfl_xor(csum[ct], 16);
    csum[ct] += __shfl_xor(csum[ct], 32);
    csq[ct] += __shfl_xor(csq[ct], 16);
    csq[ct] += __shfl_xor(csq[ct], 32);
  }
  if (l < 16) {
    #pragma unroll
    for (int ct = 0; ct < 8; ++ct) {
      atomicAdd(&lstats[ct * 16 + l], csum[ct]);
      atomicAdd(&lstats[128 + ct * 16 + l], csq[ct]);
    }
  }
  __syncthreads();
  atomicAdd(&stats_sl[(size_t)(blockIdx.x & (NSLICE - 1)) * 256 + tid], lstats[tid]);
}

// fold stat slices -> per-channel scale/shift:  y = x*scale + shift == BN(x)
__global__ __launch_bounds__(128)
void k_bn_scale(const float* __restrict__ stats_sl, const float* __restrict__ g,
                const float* __restrict__ b, float invN, float* __restrict__ scsh) {
  const int c = threadIdx.x;
  float s = 0.f, ss = 0.f;
  for (int k = 0; k < NSLICE; ++k) {
    s += stats_sl[(size_t)k * (2 * HID) + c];
    ss += stats_sl[(size_t)k * (2 * HID) + HID + c];
  }
  const float m = s * invN;
  const float var = ss * invN - m * m;
  const float sc = g[c] * rsqrtf(var + 1e-5f);
  scsh[c] = sc;
  scsh[HID + c] = b[c] - m * sc;
}

// U[i][c] = f(G[i][c]) + vx[batch[i]][c], f = relu(bn) or identity; fp32 in/out
template<bool HASF>
__global__ __launch_bounds__(256)
void k_upass(const float* __restrict__ G, const float* __restrict__ scsh,
             const int* __restrict__ batch, const float* __restrict__ vx,
             float* __restrict__ U, int total4) {
  const int i = blockIdx.x * 256 + threadIdx.x;
  if (i >= total4) return;
  const int node = i >> 5, c4 = i & 31;
  float4 v = ((const float4*)G)[i];
  if constexpr (HASF) {
    const float4 sc = ((const float4*)scsh)[c4];
    const float4 sh = ((const float4*)(scsh + HID))[c4];
    v.x = fmaxf(v.x * sc.x + sh.x, 0.f);
    v.y = fmaxf(v.y * sc.y + sh.y, 0.f);
    v.z = fmaxf(v.z * sc.z + sh.z, 0.f);
    v.w = fmaxf(v.w * sc.w + sh.w, 0.f);
  }
  const float4 u = ((const float4*)(vx + (size_t)batch[node] * HID))[c4];
  v.x += u.x; v.y += u.y; v.z += u.z; v.w += u.w;
  ((float4*)U)[i] = v;
}

// Z_i = sum_e coef*U[col] + nrm_i^2 * U[i]  (fp32 in, split bf16 out: Zhi + Zlo)
__global__ __launch_bounds__(256)
void k_agg(const int* __restrict__ rowp, const int* __restrict__ colp,
           const float* __restrict__ coefp, const float* __restrict__ U,
           const float* __restrict__ nrm, unsigned short* __restrict__ Zhi,
           unsigned short* __restrict__ Zlo, int N) {
  const int tid = threadIdx.x;
  const int node = blockIdx.x * 8 + (tid >> 5);
  const int c4 = tid & 31;
  const int lo = rowp[node], hi = rowp[node + 1];
  const float nv = nrm[node];
  float4 acc = *(const float4*)(U + (size_t)node * HID + c4 * 4);
  const float s2 = nv * nv;
  acc.x *= s2; acc.y *= s2; acc.z *= s2; acc.w *= s2;
  int e = lo;
  for (; e + 4 <= hi; e += 4) {
    const int i0 = colp[e], i1 = colp[e + 1], i2 = colp[e + 2], i3 = colp[e + 3];
    const float w0 = coefp[e], w1 = coefp[e + 1], w2 = coefp[e + 2], w3 = coefp[e + 3];
    const float4 v0 = *(const float4*)(U + (size_t)i0 * HID + c4 * 4);
    const float4 v1 = *(const float4*)(U + (size_t)i1 * HID + c4 * 4);
    const float4 v2 = *(const float4*)(U + (size_t)i2 * HID + c4 * 4);
    const float4 v3 = *(const float4*)(U + (size_t)i3 * HID + c4 * 4);
    acc.x += v0.x * w0 + v1.x * w1 + v2.x * w2 + v3.x * w3;
    acc.y += v0.y * w0 + v1.y * w1 + v2.y * w2 + v3.y * w3;
    acc.z += v0.z * w0 + v1.z * w1 + v2.z * w2 + v3.z * w3;
    acc.w += v0.w * w0 + v1.w * w1 + v2.w * w2 + v3.w * w3;
  }
  for (; e < hi; ++e) {
    const float w = coefp[e];
    const float4 v = *(const float4*)(U + (size_t)colp[e] * HID + c4 * 4);
    acc.x += v.x * w; acc.y += v.y * w; acc.z += v.z * w; acc.w += v.w * w;
  }
  ushort4 h, lo4;
  h.x = f2b(acc.x); lo4.x = f2b(acc.x - b2f(h.x));
  h.y = f2b(acc.y); lo4.y = f2b(acc.y - b2f(h.y));
  h.z = f2b(acc.z); lo4.z = f2b(acc.z - b2f(h.z));
  h.w = f2b(acc.w); lo4.w = f2b(acc.w - b2f(h.w));
  *(ushort4*)(Zhi + (size_t)node * HID + c4 * 4) = h;
  *(ushort4*)(Zlo + (size_t)node * HID + c4 * 4) = lo4;
}

// S_i = mean_e relu(G[col]*sc+sh)  (fp32 in/out)
__global__ __launch_bounds__(256)
void k_sub(const int* __restrict__ rowp, const int* __restrict__ colp,
           const float* __restrict__ G, const float* __restrict__ scsh,
           float* __restrict__ S, int N) {
  const int tid = threadIdx.x;
  const int node = blockIdx.x * 8 + (tid >> 5);
  const int c4 = tid & 31;
  const float4 sc = ((const float4*)scsh)[c4];
  const float4 sh = ((const float4*)(scsh + HID))[c4];
  const int lo = rowp[node], hi = rowp[node + 1];
  float4 acc = {0.f, 0.f, 0.f, 0.f};
  int e = lo;
  for (; e + 4 <= hi; e += 4) {
    const int i0 = colp[e], i1 = colp[e + 1], i2 = colp[e + 2], i3 = colp[e + 3];
    const float4 v0 = *(const float4*)(G + (size_t)i0 * HID + c4 * 4);
    const float4 v1 = *(const float4*)(G + (size_t)i1 * HID + c4 * 4);
    const float4 v2 = *(const float4*)(G + (size_t)i2 * HID + c4 * 4);
    const float4 v3 = *(const float4*)(G + (size_t)i3 * HID + c4 * 4);
    acc.x += fmaxf(v0.x * sc.x + sh.x, 0.f) + fmaxf(v1.x * sc.x + sh.x, 0.f)
           + fmaxf(v2.x * sc.x + sh.x, 0.f) + fmaxf(v3.x * sc.x + sh.x, 0.f);
    acc.y += fmaxf(v0.y * sc.y + sh.y, 0.f) + fmaxf(v1.y * sc.y + sh.y, 0.f)
           + fmaxf(v2.y * sc.y + sh.y, 0.f) + fmaxf(v3.y * sc.y + sh.y, 0.f);
    acc.z += fmaxf(v0.z * sc.z + sh.z, 0.f) + fmaxf(v1.z * sc.z + sh.z, 0.f)
           + fmaxf(v2.z * sc.z + sh.z, 0.f) + fmaxf(v3.z * sc.z + sh.z, 0.f);
    acc.w += fmaxf(v0.w * sc.w + sh.w, 0.f) + fmaxf(v1.w * sc.w + sh.w, 0.f)
           + fmaxf(v2.w * sc.w + sh.w, 0.f) + fmaxf(v3.w * sc.w + sh.w, 0.f);
  }
  for (; e < hi; ++e) {
    const float4 v = *(const float4*)(G + (size_t)colp[e] * HID + c4 * 4);
    acc.x += fmaxf(v.x * sc.x + sh.x, 0.f);
    acc.y += fmaxf(v.y * sc.y + sh.y, 0.f);
    acc.z += fmaxf(v.z * sc.z + sh.z, 0.f);
    acc.w += fmaxf(v.w * sc.w + sh.w, 0.f);
  }
  const float inv = 1.0f / fmaxf((float)(hi - lo), 1.0f);
  acc.x *= inv; acc.y *= inv; acc.z *= inv; acc.w *= inv;
  *(float4*)(S + (size_t)node * HID + c4 * 4) = acc;
}

// parallel per-batch pooling on fp32 S: 8 chunks per batch, then fold
__global__ __launch_bounds__(128)
void k_pool_part(const float* __restrict__ S, const int* __restrict__ batch, int N,
                 float* __restrict__ part, float* __restrict__ nb) {
  const int b = blockIdx.x >> 3, pc = blockIdx.x & 7, c = threadIdx.x;
  const int lo = lowerb(batch, N, b);
  const int hi = lowerb(batch, N, b + 1);
  const int len = hi - lo;
  const int s = lo + (len * pc) / 8;
  const int e = lo + (len * (pc + 1)) / 8;
  float a = 0.f;
  for (int i = s; i < e; ++i) a += S[(size_t)i * HID + c];
  part[(size_t)blockIdx.x * HID + c] = a;
  if (pc == 0 && c == 0) nb[b] = (float)len;
}

__global__ __launch_bounds__(128)
void k_pool_fold(const float* __restrict__ part, float* __restrict__ outSum) {
  const int b = blockIdx.x, c = threadIdx.x;
  float a = 0.f;
  #pragma unroll
  for (int pc = 0; pc < 8; ++pc) a += part[(size_t)(b * 8 + pc) * HID + c];
  outSum[(size_t)b * HID + c] = a;
}

__global__ __launch_bounds__(128)
void k_vn_update(const float* __restrict__ pooledSum, float* __restrict__ vx,
                 const float* __restrict__ W, const float* __restrict__ bias) {
  const int b = blockIdx.x, c = threadIdx.x;
  __shared__ float xin[HID];
  xin[c] = pooledSum[(size_t)b * HID + c] + vx[(size_t)b * HID + c];
  __syncthreads();
  float acc = bias[c];
  #pragma unroll 8
  for (int k = 0; k < HID; k += 4) {
    const float4 x = *(const float4*)&xin[k];
    acc += x.x * W[k * HID + c] + x.y * W[(k + 1) * HID + c]
         + x.z * W[(k + 2) * HID + c] + x.w * W[(k + 3) * HID + c];
  }
  vx[(size_t)b * HID + c] += fmaxf(acc, 0.0f);
}

__global__ __launch_bounds__(128)
void k_final_A(const float* __restrict__ sum_Sd, const float* __restrict__ sum_Sp,
               const float* __restrict__ nb_d, const float* __restrict__ nb_p,
               float* __restrict__ A_d, float* __restrict__ A_p) {
  const int b = blockIdx.x, c = threadIdx.x;
  const float nd = nb_d[b], np_ = nb_p[b];
  const float md = sum_Sd[(size_t)b * HID + c] / fmaxf(nd, 1.f);
  const float mp = sum_Sp[(size_t)b * HID + c] / fmaxf(np_, 1.f);
  A_d[(size_t)b * HID + c] = md + (nd > 0.f ? mp : 0.f);
  A_p[(size_t)b * HID + c] = mp + (np_ > 0.f ? md : 0.f);
}

__global__ __launch_bounds__(128)
void k_final_mlp(const float* __restrict__ A, const float* __restrict__ feat,
                 const float* __restrict__ W, const float* __restrict__ bias,
                 float* __restrict__ out) {
  const int b = blockIdx.x, c = threadIdx.x;
  __shared__ float xin[2 * HID];
  xin[c] = A[(size_t)b * HID + c];
  xin[HID + c] = feat[(size_t)b * HID + c];
  __syncthreads();
  float acc = bias[c];
  #pragma unroll 8
  for (int k = 0; k < 2 * HID; k += 4) {
    const float4 x = *(const float4*)&xin[k];
    acc += x.x * W[k * HID + c] + x.y * W[(k + 1) * HID + c]
         + x.z * W[(k + 2) * HID + c] + x.w * W[(k + 3) * HID + c];
  }
  out[(size_t)b * HID + c] = acc;
}

__global__ __launch_bounds__(256)
void k_bn_stats(const float* __restrict__ X, float* __restrict__ stats, int N) {
  __shared__ float sh[2][256];
  const int tid = threadIdx.x;
  const int c = tid & (HID - 1);
  const int half = tid >> 7;
  float s = 0.f, ss = 0.f;
  for (int r = blockIdx.x * 2 + half; r < N; r += gridDim.x * 2) {
    const float v = X[(size_t)r * HID + c];
    s += v; ss += v * v;
  }
  sh[0][tid] = s; sh[1][tid] = ss;
  __syncthreads();
  if (tid < HID) {
    atomicAdd(&stats[c], sh[0][tid] + sh[0][tid + 128]);
    atomicAdd(&stats[HID + c], sh[1][tid] + sh[1][tid + 128]);
  }
}

template<bool RELU>
__global__ void k_bn_apply(const float* __restrict__ X, float* __restrict__ Y,
                           const float* __restrict__ stats, const float* __restrict__ g,
                           const float* __restrict__ b, int n4, float invN) {
  const int stride = gridDim.x * blockDim.x;
  for (int i = blockIdx.x * blockDim.x + threadIdx.x; i < n4; i += stride) {
    const int c4 = i & 31;
    const float4 m4 = ((const float4*)stats)[c4];
    const float4 q4 = ((const float4*)stats)[32 + c4];
    const float4 g4 = ((const float4*)g)[c4];
    const float4 b4 = ((const float4*)b)[c4];
    float4 v = ((const float4*)X)[i];
    float m, va;
    m = m4.x * invN; va = q4.x * invN - m * m; v.x = (v.x - m) * rsqrtf(va + 1e-5f) * g4.x + b4.x;
    m = m4.y * invN; va = q4.y * invN - m * m; v.y = (v.y - m) * rsqrtf(va + 1e-5f) * g4.y + b4.y;
    m = m4.z * invN; va = q4.z * invN - m * m; v.z = (v.z - m) * rsqrtf(va + 1e-5f) * g4.z + b4.z;
    m = m4.w * invN; va = q4.w * invN - m * m; v.w = (v.w - m) * rsqrtf(va + 1e-5f) * g4.w + b4.w;
    if (RELU) {
      v.x = fmaxf(v.x, 0.f); v.y = fmaxf(v.y, 0.f); v.z = fmaxf(v.z, 0.f); v.w = fmaxf(v.w, 0.f);
    }
    ((float4*)Y)[i] = v;
  }
}

// ---------------- host launch ----------------
extern "C" void kernel_launch(void* const* d_in, const int* in_sizes, int n_in,
                              void* d_out, int out_size, void* d_ws, size_t ws_size,
                              hipStream_t stream) {
  const float* drug_x   = (const float*)d_in[0];
  const float* prot_x   = (const float*)d_in[1];
  const float* d_feat   = (const float*)d_in[2];
  const float* p_feat   = (const float*)d_in[3];
  const int*   d_ei     = (const int*)d_in[4];
  const int*   d_batch  = (const int*)d_in[5];
  const int*   d_sn     = (const int*)d_in[6];
  const int*   d_si     = (const int*)d_in[7];
  const int*   p_ei     = (const int*)d_in[8];
  const int*   p_batch  = (const int*)d_in[9];
  const int*   p_sn     = (const int*)d_in[10];
  const int*   p_si     = (const int*)d_in[11];
  const float* enc_Wd   = (const float*)d_in[12];
  const float* enc_bd   = (const float*)d_in[13];
  const float* enc_Wp   = (const float*)d_in[14];
  const float* enc_bp   = (const float*)d_in[15];
  const float* convW_d  = (const float*)d_in[16];
  const float* convW_p  = (const float*)d_in[18];
  const float* bng_d    = (const float*)d_in[20];
  const float* bnb_d    = (const float*)d_in[21];
  const float* bng_p    = (const float*)d_in[22];
  const float* bnb_p    = (const float*)d_in[23];
  const float* vn_emb_d = (const float*)d_in[24];
  const float* vn_emb_p = (const float*)d_in[25];
  const float* vnW_d    = (const float*)d_in[26];
  const float* vnb_d    = (const float*)d_in[27];
  const float* vnW_p    = (const float*)d_in[28];
  const float* vnb_p    = (const float*)d_in[29];
  const float* mlpd1_W  = (const float*)d_in[30];
  const float* mlpd1_b  = (const float*)d_in[31];
  const float* mlpd1_g  = (const float*)d_in[32];
  const float* mlpd1_be = (const float*)d_in[33];
  const float* mlpp1_W  = (const float*)d_in[34];
  const float* mlpp1_b  = (const float*)d_in[35];
  const float* mlpp1_g  = (const float*)d_in[36];
  const float* mlpp1_be = (const float*)d_in[37];

  const int ND = in_sizes[5];
  const int ED = in_sizes[4] / 2;
  const int SD = in_sizes[6];
  const int NP = in_sizes[9];
  const int EP = in_sizes[8] / 2;
  const int SP = in_sizes[10];
  const int B  = in_sizes[2] / HID;
  (void)n_in; (void)out_size; (void)ws_size;

  char* wsb = (char*)d_ws;
  size_t off = 0;
  auto alloc = [&](size_t bytes) -> void* {
    void* p = (void*)(wsb + off);
    off = (off + bytes + 255) & ~(size_t)255;
    return p;
  };
  // node buffers: fp32 G, fp32 U (doubles as S), split-bf16 Z
  float* Gp = (float*)alloc((size_t)NP * HID * 4);
  float* Up = (float*)alloc((size_t)NP * HID * 4);
  unsigned short* Zhi_p = (unsigned short*)alloc((size_t)NP * HID * 2);
  unsigned short* Zlo_p = (unsigned short*)alloc((size_t)NP * HID * 2);
  float* Gd = (float*)alloc((size_t)ND * HID * 4);
  float* Ud = (float*)alloc((size_t)ND * HID * 4);
  unsigned short* Zhi_d = (unsigned short*)alloc((size_t)ND * HID * 2);
  unsigned short* Zlo_d = (unsigned short*)alloc((size_t)ND * HID * 2);
  unsigned short* WhiAll = (unsigned short*)alloc((size_t)6 * HID * HID * 2);
  unsigned short* WloAll = (unsigned short*)alloc((size_t)6 * HID * HID * 2);
  // CSR + misc
  float* nrm_p = (float*)alloc((size_t)NP * 4);
  float* nrm_d = (float*)alloc((size_t)ND * 4);
  int* deg_p  = (int*)alloc((size_t)NP * 4);
  int* deg_d  = (int*)alloc((size_t)ND * 4);
  int* scnt_p = (int*)alloc((size_t)NP * 4);
  int* scnt_d = (int*)alloc((size_t)ND * 4);
  int* rowE_p = (int*)alloc((size_t)(NP + 1) * 4);
  int* rowE_d = (int*)alloc((size_t)(ND + 1) * 4);
  int* rowS_p = (int*)alloc((size_t)(NP + 1) * 4);
  int* rowS_d = (int*)alloc((size_t)(ND + 1) * 4);
  int* colE_p = (int*)alloc((size_t)EP * 4);
  float* cofE_p = (float*)alloc((size_t)EP * 4);
  int* colE_d = (int*)alloc((size_t)ED * 4);
  float* cofE_d = (float*)alloc((size_t)ED * 4);
  int* colS_p = (int*)alloc((size_t)SP * 4);
  int* colS_d = (int*)alloc((size_t)SD * 4);
  int* cur_p  = (int*)alloc((size_t)NP * 4);
  int* cur_d  = (int*)alloc((size_t)ND * 4);
  int* aux    = (int*)alloc(1024 * 4);
  float* vx_d  = (float*)alloc((size_t)B * HID * 4);
  float* vx_p  = (float*)alloc((size_t)B * HID * 4);
  float* sum_Sd = (float*)alloc((size_t)B * HID * 4);
  float* sum_Sp = (float*)alloc((size_t)B * HID * 4);
  float* A_d   = (float*)alloc((size_t)B * HID * 4);
  float* A_p   = (float*)alloc((size_t)B * HID * 4);
  float* nb_d  = (float*)alloc((size_t)B * 4);
  float* nb_p  = (float*)alloc((size_t)B * 4);
  float* stats_sl = (float*)alloc((size_t)NSLICE * 2 * HID * 4);
  float* statsF   = (float*)alloc(2 * HID * 4);
  float* scsh_d = (float*)alloc(2 * HID * 4);
  float* scsh_p = (float*)alloc(2 * HID * 4);
  float* part  = (float*)alloc((size_t)B * 8 * HID * 4);
  float* fpre  = (float*)alloc((size_t)B * HID * 4);

  const int* d_src = d_ei;  const int* d_dst = d_ei + ED;
  const int* p_src = p_ei;  const int* p_dst = p_ei + EP;

  // ---- CSR build (loop-invariant) ----
  hipMemsetAsync(deg_p, 0, (size_t)NP * 4, stream);
  hipMemsetAsync(deg_d, 0, (size_t)ND * 4, stream);
  hipMemsetAsync(scnt_p, 0, (size_t)NP * 4, stream);
  hipMemsetAsync(scnt_d, 0, (size_t)ND * 4, stream);
  k_hist_i<<<1024, 256, 0, stream>>>(d_dst, deg_d, ED);
  k_hist_i<<<2048, 256, 0, stream>>>(p_dst, deg_p, EP);
  k_hist_i<<<1024, 256, 0, stream>>>(d_si, scnt_d, SD);
  k_hist_i<<<2048, 256, 0, stream>>>(p_si, scnt_p, SP);
  k_nrm<<<64, 256, 0, stream>>>(deg_d, nrm_d, ND);
  k_nrm<<<512, 256, 0, stream>>>(deg_p, nrm_p, NP);

  const int nbP = (NP + 1023) / 1024, nbD = (ND + 1023) / 1024;
  k_scan1<<<nbP, 256, 0, stream>>>(deg_p, rowE_p, aux, NP);
  k_scan2<<<1, 256, 0, stream>>>(aux, nbP);
  k_scan3<<<256, 256, 0, stream>>>(rowE_p, aux, NP, EP);
  k_scan1<<<nbD, 256, 0, stream>>>(deg_d, rowE_d, aux, ND);
  k_scan2<<<1, 256, 0, stream>>>(aux, nbD);
  k_scan3<<<64, 256, 0, stream>>>(rowE_d, aux, ND, ED);
  k_scan1<<<nbP, 256, 0, stream>>>(scnt_p, rowS_p, aux, NP);
  k_scan2<<<1, 256, 0, stream>>>(aux, nbP);
  k_scan3<<<256, 256, 0, stream>>>(rowS_p, aux, NP, SP);
  k_scan1<<<nbD, 256, 0, stream>>>(scnt_d, rowS_d, aux, ND);
  k_scan2<<<1, 256, 0, stream>>>(aux, nbD);
  k_scan3<<<64, 256, 0, stream>>>(rowS_d, aux, ND, SD);

  hipMemsetAsync(cur_p, 0, (size_t)NP * 4, stream);
  hipMemsetAsync(cur_d, 0, (size_t)ND * 4, stream);
  k_fill_edges<<<2048, 256, 0, stream>>>(p_src, p_dst, rowE_p, cur_p, colE_p, cofE_p, nrm_p, EP);
  k_fill_edges<<<1024, 256, 0, stream>>>(d_src, d_dst, rowE_d, cur_d, colE_d, cofE_d, nrm_d, ED);
  hipMemsetAsync(cur_p, 0, (size_t)NP * 4, stream);
  hipMemsetAsync(cur_d, 0, (size_t)ND * 4, stream);
  k_fill_sub<<<2048, 256, 0, stream>>>(p_sn, p_si, rowS_p, cur_p, colS_p, SP);
  k_fill_sub<<<1024, 256, 0, stream>>>(d_sn, d_si, rowS_d, cur_d, colS_d, SD);

  // ---- weight transpose/convert + encoders + vx init ----
  k_wcvt<<<6, 256, 0, stream>>>(convW_d, convW_p, WhiAll, WloAll);
  k_gemm_enc<78, 39><<<ND / 128, 256, 0, stream>>>(drug_x, enc_Wd, enc_bd, Gd, ND);
  k_gemm_enc<70, 35><<<NP / 128, 256, 0, stream>>>(prot_x, enc_Wp, enc_bp, Gp, NP);
  k_vx_init<<<64, 256, 0, stream>>>(vn_emb_d, d_feat, vx_d, B * HID);
  k_vx_init<<<64, 256, 0, stream>>>(vn_emb_p, p_feat, vx_p, B * HID);

  for (int l = 0; l < 3; ++l) {
    // ---------- drug ----------
    if (l == 0)
      k_upass<false><<<ND / 8, 256, 0, stream>>>(Gd, nullptr, d_batch, vx_d, Ud, ND * 32);
    else
      k_upass<true><<<ND / 8, 256, 0, stream>>>(Gd, scsh_d, d_batch, vx_d, Ud, ND * 32);
    k_agg<<<ND / 8, 256, 0, stream>>>(rowE_d, colE_d, cofE_d, Ud, nrm_d, Zhi_d, Zlo_d, ND);
    hipMemsetAsync(stats_sl, 0, (size_t)NSLICE * 2 * HID * 4, stream);
    k_gemm_mfma<<<ND / 128, 256, 0, stream>>>(Zhi_d, Zlo_d, WhiAll + (size_t)l * HID * HID,
                                              WloAll + (size_t)l * HID * HID, Gd, stats_sl, ND);
    k_bn_scale<<<1, 128, 0, stream>>>(stats_sl, bng_d + l * HID, bnb_d + l * HID,
                                      1.0f / (float)ND, scsh_d);
    k_sub<<<ND / 8, 256, 0, stream>>>(rowS_d, colS_d, Gd, scsh_d, Ud, ND);
    k_pool_part<<<B * 8, 128, 0, stream>>>(Ud, d_batch, ND, part, nb_d);
    k_pool_fold<<<B, 128, 0, stream>>>(part, sum_Sd);
    if (l < 2)
      k_vn_update<<<B, 128, 0, stream>>>(sum_Sd, vx_d, vnW_d + (size_t)l * HID * HID, vnb_d + l * HID);

    // ---------- protein ----------
    if (l == 0)
      k_upass<false><<<NP / 8, 256, 0, stream>>>(Gp, nullptr, p_batch, vx_p, Up, NP * 32);
    else
      k_upass<true><<<NP / 8, 256, 0, stream>>>(Gp, scsh_p, p_batch, vx_p, Up, NP * 32);
    k_agg<<<NP / 8, 256, 0, stream>>>(rowE_p, colE_p, cofE_p, Up, nrm_p, Zhi_p, Zlo_p, NP);
    hipMemsetAsync(stats_sl, 0, (size_t)NSLICE * 2 * HID * 4, stream);
    k_gemm_mfma<<<NP / 128, 256, 0, stream>>>(Zhi_p, Zlo_p, WhiAll + (size_t)(3 + l) * HID * HID,
                                              WloAll + (size_t)(3 + l) * HID * HID, Gp, stats_sl, NP);
    k_bn_scale<<<1, 128, 0, stream>>>(stats_sl, bng_p + l * HID, bnb_p + l * HID,
                                      1.0f / (float)NP, scsh_p);
    k_sub<<<NP / 8, 256, 0, stream>>>(rowS_p, colS_p, Gp, scsh_p, Up, NP);
    k_pool_part<<<B * 8, 128, 0, stream>>>(Up, p_batch, NP, part, nb_p);
    k_pool_fold<<<B, 128, 0, stream>>>(part, sum_Sp);
    if (l < 2)
      k_vn_update<<<B, 128, 0, stream>>>(sum_Sp, vx_p, vnW_p + (size_t)l * HID * HID, vnb_p + l * HID);
  }

  // ---- cross-modal sync collapses to pooled means; final MLP + BN ----
  k_final_A<<<B, 128, 0, stream>>>(sum_Sd, sum_Sp, nb_d, nb_p, A_d, A_p);

  float* outf = (float*)d_out;
  k_final_mlp<<<B, 128, 0, stream>>>(A_d, d_feat, mlpd1_W, mlpd1_b, fpre);
  hipMemsetAsync(statsF, 0, 2 * HID * 4, stream);
  k_bn_stats<<<128, 256, 0, stream>>>(fpre, statsF, B);
  k_bn_apply<false><<<64, 256, 0, stream>>>(fpre, outf, statsF, mlpd1_g, mlpd1_be,
                                            B * 32, 1.0f / (float)B);

  k_final_mlp<<<B, 128, 0, stream>>>(A_p, p_feat, mlpp1_W, mlpp1_b, fpre);
  hipMemsetAsync(statsF, 0, 2 * HID * 4, stream);
  k_bn_stats<<<128, 256, 0, stream>>>(fpre, statsF, B);
  k_bn_apply<false><<<64, 256, 0, stream>>>(fpre, outf + (size_t)B * HID, statsF, mlpp1_g, mlpp1_be,
                                            B * 32, 1.0f / (float)B);
}

// Round 7
// 882.410 us; speedup vs baseline: 9.3082x; 1.2460x over previous
//
#include <hip/hip_runtime.h>
#include <cstdint>
#include <cstddef>

#define HID 128
#define NSLICE 32

using bf16x8 = __attribute__((ext_vector_type(8))) short;
using f32x4v = __attribute__((ext_vector_type(4))) float;

// ---------------- bf16 helpers (RNE) ----------------
static __device__ __forceinline__ unsigned short f2b(float x) {
  unsigned int u = __float_as_uint(x);
  unsigned int r = u + 0x7FFFu + ((u >> 16) & 1u);
  return (unsigned short)(r >> 16);
}
static __device__ __forceinline__ float b2f(unsigned short h) {
  return __uint_as_float(((unsigned int)h) << 16);
}

static __device__ __forceinline__ int lowerb(const int* __restrict__ a, int n, int v) {
  int lo = 0, hi = n;
  while (lo < hi) { int m = (lo + hi) >> 1; if (a[m] < v) lo = m + 1; else hi = m; }
  return lo;
}

// ---------------- CSR build ----------------
__global__ void k_hist_i(const int* __restrict__ idx, int* __restrict__ cnt, int n) {
  const int stride = gridDim.x * blockDim.x;
  for (int i = blockIdx.x * blockDim.x + threadIdx.x; i < n; i += stride)
    atomicAdd(&cnt[idx[i]], 1);
}

__global__ void k_nrm(const int* __restrict__ deg, float* __restrict__ nrm, int n) {
  const int stride = gridDim.x * blockDim.x;
  for (int i = blockIdx.x * blockDim.x + threadIdx.x; i < n; i += stride)
    nrm[i] = rsqrtf((float)deg[i] + 1.0f);
}

__global__ __launch_bounds__(256)
void k_scan1(const int* __restrict__ cnt, int* __restrict__ row, int* __restrict__ aux, int n) {
  __shared__ int sh[256];
  const int tid = threadIdx.x;
  const int base = blockIdx.x * 1024 + tid * 4;
  int v0 = base + 0 < n ? cnt[base + 0] : 0;
  int v1 = base + 1 < n ? cnt[base + 1] : 0;
  int v2 = base + 2 < n ? cnt[base + 2] : 0;
  int v3 = base + 3 < n ? cnt[base + 3] : 0;
  const int s = v0 + v1 + v2 + v3;
  sh[tid] = s;
  __syncthreads();
  for (int o = 1; o < 256; o <<= 1) {
    const int t = (tid >= o) ? sh[tid - o] : 0;
    __syncthreads();
    sh[tid] += t;
    __syncthreads();
  }
  int excl = sh[tid] - s;
  if (tid == 255) aux[blockIdx.x] = sh[255];
  if (base + 0 < n) row[base + 0] = excl; excl += v0;
  if (base + 1 < n) row[base + 1] = excl; excl += v1;
  if (base + 2 < n) row[base + 2] = excl; excl += v2;
  if (base + 3 < n) row[base + 3] = excl;
}

__global__ __launch_bounds__(256)
void k_scan2(int* __restrict__ aux, int nb) {
  __shared__ int sh[256];
  const int tid = threadIdx.x;
  const int v = tid < nb ? aux[tid] : 0;
  sh[tid] = v;
  __syncthreads();
  for (int o = 1; o < 256; o <<= 1) {
    const int t = (tid >= o) ? sh[tid - o] : 0;
    __syncthreads();
    sh[tid] += t;
    __syncthreads();
  }
  if (tid < nb) aux[tid] = sh[tid] - v;
}

__global__ void k_scan3(int* __restrict__ row, const int* __restrict__ aux, int n, int total) {
  const int stride = gridDim.x * blockDim.x;
  for (int i = blockIdx.x * blockDim.x + threadIdx.x; i < n; i += stride)
    row[i] += aux[i >> 10];
  if (blockIdx.x == 0 && threadIdx.x == 0) row[n] = total;
}

__global__ void k_fill_edges(const int* __restrict__ src, const int* __restrict__ dst,
                             const int* __restrict__ row, int* __restrict__ cur,
                             int* __restrict__ col, float* __restrict__ coef,
                             const float* __restrict__ nrm, int E) {
  const int stride = gridDim.x * blockDim.x;
  for (int e = blockIdx.x * blockDim.x + threadIdx.x; e < E; e += stride) {
    const int d = dst[e], s = src[e];
    const int pos = row[d] + atomicAdd(&cur[d], 1);
    col[pos] = s;
    coef[pos] = nrm[s] * nrm[d];
  }
}

__global__ void k_fill_sub(const int* __restrict__ sn, const int* __restrict__ si,
                           const int* __restrict__ row, int* __restrict__ cur,
                           int* __restrict__ col, int n) {
  const int stride = gridDim.x * blockDim.x;
  for (int j = blockIdx.x * blockDim.x + threadIdx.x; j < n; j += stride) {
    const int t = si[j];
    const int pos = row[t] + atomicAdd(&cur[t], 1);
    col[pos] = sn[j];
  }
}

// ---------------- misc ----------------
__global__ void k_vx_init(const float* __restrict__ emb, const float* __restrict__ feat,
                          float* __restrict__ vx, int total) {
  const int stride = gridDim.x * blockDim.x;
  for (int i = blockIdx.x * blockDim.x + threadIdx.x; i < total; i += stride)
    vx[i] = emb[i & (HID - 1)] + feat[i];
}

// nb[b] = #nodes in batch b (loop-invariant)
__global__ void k_nb(const int* __restrict__ batch, int N, float* __restrict__ nb, int B) {
  const int b = blockIdx.x * blockDim.x + threadIdx.x;
  if (b < B) nb[b] = (float)(lowerb(batch, N, b + 1) - lowerb(batch, N, b));
}

// X [N][K] fp32 -> padded split-bf16 [N][128] (k>=K -> 0)
__global__ void k_xcvt(const float* __restrict__ X, int K,
                       unsigned short* __restrict__ Xhi, unsigned short* __restrict__ Xlo,
                       int total) {
  const int stride = gridDim.x * blockDim.x;
  for (int i = blockIdx.x * blockDim.x + threadIdx.x; i < total; i += stride) {
    const int node = i >> 7, k = i & 127;
    const float v = (k < K) ? X[(size_t)node * K + k] : 0.f;
    const unsigned short hi = f2b(v);
    Xhi[i] = hi;
    Xlo[i] = f2b(v - b2f(hi));
  }
}

// W [K][128] fp32 -> transposed padded split-bf16 Wt [c][128] (k>=K -> 0)
__global__ __launch_bounds__(256)
void k_wcvt(const float* __restrict__ W, int K,
            unsigned short* __restrict__ Whi, unsigned short* __restrict__ Wlo) {
  for (int i = threadIdx.x + blockIdx.x * 256; i < HID * HID; i += gridDim.x * 256) {
    const int c = i >> 7, k = i & 127;
    const float v = (k < K) ? W[k * HID + c] : 0.f;
    const unsigned short hi = f2b(v);
    Whi[i] = hi;
    Wlo[i] = f2b(v - b2f(hi));
  }
}

// ---------------- split-bf16 MFMA GEMM: G = Z @ W, K=N=128, near-fp32 ----------------
// G ≈ Zhi·Whi + Zhi·Wlo + Zlo·Whi. ENC: +bias epilogue, no stats. else: BN-stats epilogue.
template<bool ENC>
__global__ __launch_bounds__(256, 2)
void k_gemm_mfma(const unsigned short* __restrict__ Zhi, const unsigned short* __restrict__ Zlo,
                 const unsigned short* __restrict__ Wthi, const unsigned short* __restrict__ Wtlo,
                 const float* __restrict__ bias, float* __restrict__ G,
                 float* __restrict__ stats_sl, int N) {
  __shared__ unsigned short Bt[128 * 132];
  __shared__ float lstats[256];
  const int tid = threadIdx.x;
  const int w = tid >> 6;
  const int l = tid & 63;
  const int l15 = l & 15;
  const int kb = l >> 4;

  for (int i = tid; i < 128 * 16; i += 256) {
    const int c = i >> 4, k8 = i & 15;
    *(bf16x8*)(&Bt[c * 132 + k8 * 8]) = *(const bf16x8*)(Wthi + (size_t)c * 128 + k8 * 8);
  }
  if constexpr (!ENC) lstats[tid] = 0.f;

  const int rbase = blockIdx.x * 128 + w * 32 + l15;
  bf16x8 ahi[2][4], alo[2][4];
  #pragma unroll
  for (int rt = 0; rt < 2; ++rt)
    #pragma unroll
    for (int ks = 0; ks < 4; ++ks) {
      ahi[rt][ks] = *(const bf16x8*)(Zhi + (size_t)(rbase + rt * 16) * 128 + ks * 32 + kb * 8);
      alo[rt][ks] = *(const bf16x8*)(Zlo + (size_t)(rbase + rt * 16) * 128 + ks * 32 + kb * 8);
    }

  f32x4v acc[2][8];
  #pragma unroll
  for (int rt = 0; rt < 2; ++rt)
    #pragma unroll
    for (int ct = 0; ct < 8; ++ct)
      acc[rt][ct] = (f32x4v){0.f, 0.f, 0.f, 0.f};

  __syncthreads();
  #pragma unroll
  for (int ks = 0; ks < 4; ++ks) {
    #pragma unroll
    for (int ct = 0; ct < 8; ++ct) {
      const bf16x8 b = *(const bf16x8*)(&Bt[(ct * 16 + l15) * 132 + ks * 32 + kb * 8]);
      acc[0][ct] = __builtin_amdgcn_mfma_f32_16x16x32_bf16(ahi[0][ks], b, acc[0][ct], 0, 0, 0);
      acc[1][ct] = __builtin_amdgcn_mfma_f32_16x16x32_bf16(ahi[1][ks], b, acc[1][ct], 0, 0, 0);
      acc[0][ct] = __builtin_amdgcn_mfma_f32_16x16x32_bf16(alo[0][ks], b, acc[0][ct], 0, 0, 0);
      acc[1][ct] = __builtin_amdgcn_mfma_f32_16x16x32_bf16(alo[1][ks], b, acc[1][ct], 0, 0, 0);
    }
  }
  __syncthreads();

  for (int i = tid; i < 128 * 16; i += 256) {
    const int c = i >> 4, k8 = i & 15;
    *(bf16x8*)(&Bt[c * 132 + k8 * 8]) = *(const bf16x8*)(Wtlo + (size_t)c * 128 + k8 * 8);
  }
  __syncthreads();
  #pragma unroll
  for (int ks = 0; ks < 4; ++ks) {
    #pragma unroll
    for (int ct = 0; ct < 8; ++ct) {
      const bf16x8 b = *(const bf16x8*)(&Bt[(ct * 16 + l15) * 132 + ks * 32 + kb * 8]);
      acc[0][ct] = __builtin_amdgcn_mfma_f32_16x16x32_bf16(ahi[0][ks], b, acc[0][ct], 0, 0, 0);
      acc[1][ct] = __builtin_amdgcn_mfma_f32_16x16x32_bf16(ahi[1][ks], b, acc[1][ct], 0, 0, 0);
    }
  }

  // epilogue. C/D layout: col = l&15 (+ct*16), row = (l>>4)*4 + j.
  float bb[8];
  if constexpr (ENC) {
    #pragma unroll
    for (int ct = 0; ct < 8; ++ct) bb[ct] = bias[ct * 16 + l15];
  }
  float csum[8], csq[8];
  #pragma unroll
  for (int ct = 0; ct < 8; ++ct) { csum[ct] = 0.f; csq[ct] = 0.f; }
  #pragma unroll
  for (int rt = 0; rt < 2; ++rt) {
    const size_t grow = (size_t)blockIdx.x * 128 + w * 32 + rt * 16 + (l >> 4) * 4;
    #pragma unroll
    for (int j = 0; j < 4; ++j) {
      float* gr = G + (grow + j) * 128 + l15;
      #pragma unroll
      for (int ct = 0; ct < 8; ++ct) {
        float v = acc[rt][ct][j];
        if constexpr (ENC) v += bb[ct];
        gr[ct * 16] = v;
        if constexpr (!ENC) { csum[ct] += v; csq[ct] += v * v; }
      }
    }
  }
  if constexpr (!ENC) {
    #pragma unroll
    for (int ct = 0; ct < 8; ++ct) {
      csum[ct] += __shfl_xor(csum[ct], 16);
      csum[ct] += __shfl_xor(csum[ct], 32);
      csq[ct] += __shfl_xor(csq[ct], 16);
      csq[ct] += __shfl_xor(csq[ct], 32);
    }
    if (l < 16) {
      #pragma unroll
      for (int ct = 0; ct < 8; ++ct) {
        atomicAdd(&lstats[ct * 16 + l], csum[ct]);
        atomicAdd(&lstats[128 + ct * 16 + l], csq[ct]);
      }
    }
    __syncthreads();
    atomicAdd(&stats_sl[(size_t)(blockIdx.x & (NSLICE - 1)) * 256 + tid], lstats[tid]);
  }
}

// fold stat slices -> scale/shift; re-zeros stats_sl for the next GEMM
__global__ __launch_bounds__(128)
void k_bn_scale(float* __restrict__ stats_sl, const float* __restrict__ g,
                const float* __restrict__ b, float invN, float* __restrict__ scsh) {
  const int c = threadIdx.x;
  float s = 0.f, ss = 0.f;
  for (int k = 0; k < NSLICE; ++k) {
    s += stats_sl[(size_t)k * (2 * HID) + c];
    ss += stats_sl[(size_t)k * (2 * HID) + HID + c];
    stats_sl[(size_t)k * (2 * HID) + c] = 0.f;
    stats_sl[(size_t)k * (2 * HID) + HID + c] = 0.f;
  }
  const float m = s * invN;
  const float var = ss * invN - m * m;
  const float sc = g[c] * rsqrtf(var + 1e-5f);
  scsh[c] = sc;
  scsh[HID + c] = b[c] - m * sc;
}

// fused upass+agg: u(i) = f(G[i]) + vx[batch[i]];  Z_i = nrm_i^2*u(i) + sum_e coef*u(col)
// split-bf16 out. f = relu(x*sc+sh) if HASF else identity.
template<bool HASF>
__global__ __launch_bounds__(256)
void k_agg(const int* __restrict__ rowp, const int* __restrict__ colp,
           const float* __restrict__ coefp, const float* __restrict__ G,
           const float* __restrict__ scsh, const int* __restrict__ batch,
           const float* __restrict__ vx, const float* __restrict__ nrm,
           unsigned short* __restrict__ Zhi, unsigned short* __restrict__ Zlo, int N) {
  const int tid = threadIdx.x;
  const int node = blockIdx.x * 8 + (tid >> 5);
  const int c4 = tid & 31;
  float4 sc, shv;
  if constexpr (HASF) {
    sc = ((const float4*)scsh)[c4];
    shv = ((const float4*)(scsh + HID))[c4];
  }
  auto loadU = [&](int i) -> float4 {
    float4 v = *(const float4*)(G + (size_t)i * HID + c4 * 4);
    if constexpr (HASF) {
      v.x = fmaxf(v.x * sc.x + shv.x, 0.f);
      v.y = fmaxf(v.y * sc.y + shv.y, 0.f);
      v.z = fmaxf(v.z * sc.z + shv.z, 0.f);
      v.w = fmaxf(v.w * sc.w + shv.w, 0.f);
    }
    const float4 u = *(const float4*)(vx + (size_t)batch[i] * HID + c4 * 4);
    v.x += u.x; v.y += u.y; v.z += u.z; v.w += u.w;
    return v;
  };
  const int lo = rowp[node], hi = rowp[node + 1];
  const float nv = nrm[node];
  const float s2 = nv * nv;
  float4 acc = loadU(node);
  acc.x *= s2; acc.y *= s2; acc.z *= s2; acc.w *= s2;
  int e = lo;
  for (; e + 4 <= hi; e += 4) {
    const float w0 = coefp[e], w1 = coefp[e + 1], w2 = coefp[e + 2], w3 = coefp[e + 3];
    const float4 v0 = loadU(colp[e]);
    const float4 v1 = loadU(colp[e + 1]);
    const float4 v2 = loadU(colp[e + 2]);
    const float4 v3 = loadU(colp[e + 3]);
    acc.x += v0.x * w0 + v1.x * w1 + v2.x * w2 + v3.x * w3;
    acc.y += v0.y * w0 + v1.y * w1 + v2.y * w2 + v3.y * w3;
    acc.z += v0.z * w0 + v1.z * w1 + v2.z * w2 + v3.z * w3;
    acc.w += v0.w * w0 + v1.w * w1 + v2.w * w2 + v3.w * w3;
  }
  for (; e < hi; ++e) {
    const float w = coefp[e];
    const float4 v = loadU(colp[e]);
    acc.x += v.x * w; acc.y += v.y * w; acc.z += v.z * w; acc.w += v.w * w;
  }
  ushort4 h, lo4;
  h.x = f2b(acc.x); lo4.x = f2b(acc.x - b2f(h.x));
  h.y = f2b(acc.y); lo4.y = f2b(acc.y - b2f(h.y));
  h.z = f2b(acc.z); lo4.z = f2b(acc.z - b2f(h.z));
  h.w = f2b(acc.w); lo4.w = f2b(acc.w - b2f(h.w));
  *(ushort4*)(Zhi + (size_t)node * HID + c4 * 4) = h;
  *(ushort4*)(Zlo + (size_t)node * HID + c4 * 4) = lo4;
}

// fused sub-gather + batch pooling: S_i = mean_e relu(G[col]*sc+sh); sumS[batch[i]] += S_i
// batch is sorted; flush-on-change per block (8 nodes). N divisible by 8.
__global__ __launch_bounds__(256)
void k_sub_pool(const int* __restrict__ rowp, const int* __restrict__ colp,
                const float* __restrict__ G, const float* __restrict__ scsh,
                const int* __restrict__ batch, float* __restrict__ sumS, int N) {
  __shared__ float sh[8][HID];
  __shared__ int bat[8];
  const int tid = threadIdx.x;
  const int grp = tid >> 5;
  const int node = blockIdx.x * 8 + grp;
  const int c4 = tid & 31;
  const float4 sc = ((const float4*)scsh)[c4];
  const float4 shv = ((const float4*)(scsh + HID))[c4];
  const int lo = rowp[node], hi = rowp[node + 1];
  float4 acc = {0.f, 0.f, 0.f, 0.f};
  int e = lo;
  for (; e + 4 <= hi; e += 4) {
    const int i0 = colp[e], i1 = colp[e + 1], i2 = colp[e + 2], i3 = colp[e + 3];
    const float4 v0 = *(const float4*)(G + (size_t)i0 * HID + c4 * 4);
    const float4 v1 = *(const float4*)(G + (size_t)i1 * HID + c4 * 4);
    const float4 v2 = *(const float4*)(G + (size_t)i2 * HID + c4 * 4);
    const float4 v3 = *(const float4*)(G + (size_t)i3 * HID + c4 * 4);
    acc.x += fmaxf(v0.x * sc.x + shv.x, 0.f) + fmaxf(v1.x * sc.x + shv.x, 0.f)
           + fmaxf(v2.x * sc.x + shv.x, 0.f) + fmaxf(v3.x * sc.x + shv.x, 0.f);
    acc.y += fmaxf(v0.y * sc.y + shv.y, 0.f) + fmaxf(v1.y * sc.y + shv.y, 0.f)
           + fmaxf(v2.y * sc.y + shv.y, 0.f) + fmaxf(v3.y * sc.y + shv.y, 0.f);
    acc.z += fmaxf(v0.z * sc.z + shv.z, 0.f) + fmaxf(v1.z * sc.z + shv.z, 0.f)
           + fmaxf(v2.z * sc.z + shv.z, 0.f) + fmaxf(v3.z * sc.z + shv.z, 0.f);
    acc.w += fmaxf(v0.w * sc.w + shv.w, 0.f) + fmaxf(v1.w * sc.w + shv.w, 0.f)
           + fmaxf(v2.w * sc.w + shv.w, 0.f) + fmaxf(v3.w * sc.w + shv.w, 0.f);
  }
  for (; e < hi; ++e) {
    const float4 v = *(const float4*)(G + (size_t)colp[e] * HID + c4 * 4);
    acc.x += fmaxf(v.x * sc.x + shv.x, 0.f);
    acc.y += fmaxf(v.y * sc.y + shv.y, 0.f);
    acc.z += fmaxf(v.z * sc.z + shv.z, 0.f);
    acc.w += fmaxf(v.w * sc.w + shv.w, 0.f);
  }
  const float inv = 1.0f / fmaxf((float)(hi - lo), 1.0f);
  acc.x *= inv; acc.y *= inv; acc.z *= inv; acc.w *= inv;
  ((float4*)&sh[grp][0])[c4] = acc;
  if (tid < 8) bat[tid] = batch[blockIdx.x * 8 + tid];
  __syncthreads();
  if (tid < HID) {
    int cur = bat[0];
    float a = 0.f;
    #pragma unroll
    for (int g = 0; g < 8; ++g) {
      if (bat[g] != cur) {
        atomicAdd(&sumS[(size_t)cur * HID + tid], a);
        a = 0.f;
        cur = bat[g];
      }
      a += sh[g][tid];
    }
    atomicAdd(&sumS[(size_t)cur * HID + tid], a);
  }
}

__global__ __launch_bounds__(128)
void k_vn_update(const float* __restrict__ pooledSum, float* __restrict__ vx,
                 const float* __restrict__ W, const float* __restrict__ bias) {
  const int b = blockIdx.x, c = threadIdx.x;
  __shared__ float xin[HID];
  xin[c] = pooledSum[(size_t)b * HID + c] + vx[(size_t)b * HID + c];
  __syncthreads();
  float acc = bias[c];
  #pragma unroll 8
  for (int k = 0; k < HID; k += 4) {
    const float4 x = *(const float4*)&xin[k];
    acc += x.x * W[k * HID + c] + x.y * W[(k + 1) * HID + c]
         + x.z * W[(k + 2) * HID + c] + x.w * W[(k + 3) * HID + c];
  }
  vx[(size_t)b * HID + c] += fmaxf(acc, 0.0f);
}

__global__ __launch_bounds__(128)
void k_final_A(const float* __restrict__ sum_Sd, const float* __restrict__ sum_Sp,
               const float* __restrict__ nb_d, const float* __restrict__ nb_p,
               float* __restrict__ A_d, float* __restrict__ A_p) {
  const int b = blockIdx.x, c = threadIdx.x;
  const float nd = nb_d[b], np_ = nb_p[b];
  const float md = sum_Sd[(size_t)b * HID + c] / fmaxf(nd, 1.f);
  const float mp = sum_Sp[(size_t)b * HID + c] / fmaxf(np_, 1.f);
  A_d[(size_t)b * HID + c] = md + (nd > 0.f ? mp : 0.f);
  A_p[(size_t)b * HID + c] = mp + (np_ > 0.f ? md : 0.f);
}

__global__ __launch_bounds__(128)
void k_final_mlp(const float* __restrict__ A, const float* __restrict__ feat,
                 const float* __restrict__ W, const float* __restrict__ bias,
                 float* __restrict__ out) {
  const int b = blockIdx.x, c = threadIdx.x;
  __shared__ float xin[2 * HID];
  xin[c] = A[(size_t)b * HID + c];
  xin[HID + c] = feat[(size_t)b * HID + c];
  __syncthreads();
  float acc = bias[c];
  #pragma unroll 8
  for (int k = 0; k < 2 * HID; k += 4) {
    const float4 x = *(const float4*)&xin[k];
    acc += x.x * W[k * HID + c] + x.y * W[(k + 1) * HID + c]
         + x.z * W[(k + 2) * HID + c] + x.w * W[(k + 3) * HID + c];
  }
  out[(size_t)b * HID + c] = acc;
}

__global__ __launch_bounds__(256)
void k_bn_stats(const float* __restrict__ X, float* __restrict__ stats, int N) {
  __shared__ float sh[2][256];
  const int tid = threadIdx.x;
  const int c = tid & (HID - 1);
  const int half = tid >> 7;
  float s = 0.f, ss = 0.f;
  for (int r = blockIdx.x * 2 + half; r < N; r += gridDim.x * 2) {
    const float v = X[(size_t)r * HID + c];
    s += v; ss += v * v;
  }
  sh[0][tid] = s; sh[1][tid] = ss;
  __syncthreads();
  if (tid < HID) {
    atomicAdd(&stats[c], sh[0][tid] + sh[0][tid + 128]);
    atomicAdd(&stats[HID + c], sh[1][tid] + sh[1][tid + 128]);
  }
}

template<bool RELU>
__global__ void k_bn_apply(const float* __restrict__ X, float* __restrict__ Y,
                           const float* __restrict__ stats, const float* __restrict__ g,
                           const float* __restrict__ b, int n4, float invN) {
  const int stride = gridDim.x * blockDim.x;
  for (int i = blockIdx.x * blockDim.x + threadIdx.x; i < n4; i += stride) {
    const int c4 = i & 31;
    const float4 m4 = ((const float4*)stats)[c4];
    const float4 q4 = ((const float4*)stats)[32 + c4];
    const float4 g4 = ((const float4*)g)[c4];
    const float4 b4 = ((const float4*)b)[c4];
    float4 v = ((const float4*)X)[i];
    float m, va;
    m = m4.x * invN; va = q4.x * invN - m * m; v.x = (v.x - m) * rsqrtf(va + 1e-5f) * g4.x + b4.x;
    m = m4.y * invN; va = q4.y * invN - m * m; v.y = (v.y - m) * rsqrtf(va + 1e-5f) * g4.y + b4.y;
    m = m4.z * invN; va = q4.z * invN - m * m; v.z = (v.z - m) * rsqrtf(va + 1e-5f) * g4.z + b4.z;
    m = m4.w * invN; va = q4.w * invN - m * m; v.w = (v.w - m) * rsqrtf(va + 1e-5f) * g4.w + b4.w;
    if (RELU) {
      v.x = fmaxf(v.x, 0.f); v.y = fmaxf(v.y, 0.f); v.z = fmaxf(v.z, 0.f); v.w = fmaxf(v.w, 0.f);
    }
    ((float4*)Y)[i] = v;
  }
}

// ---------------- host launch ----------------
extern "C" void kernel_launch(void* const* d_in, const int* in_sizes, int n_in,
                              void* d_out, int out_size, void* d_ws, size_t ws_size,
                              hipStream_t stream) {
  const float* drug_x   = (const float*)d_in[0];
  const float* prot_x   = (const float*)d_in[1];
  const float* d_feat   = (const float*)d_in[2];
  const float* p_feat   = (const float*)d_in[3];
  const int*   d_ei     = (const int*)d_in[4];
  const int*   d_batch  = (const int*)d_in[5];
  const int*   d_sn     = (const int*)d_in[6];
  const int*   d_si     = (const int*)d_in[7];
  const int*   p_ei     = (const int*)d_in[8];
  const int*   p_batch  = (const int*)d_in[9];
  const int*   p_sn     = (const int*)d_in[10];
  const int*   p_si     = (const int*)d_in[11];
  const float* enc_Wd   = (const float*)d_in[12];
  const float* enc_bd   = (const float*)d_in[13];
  const float* enc_Wp   = (const float*)d_in[14];
  const float* enc_bp   = (const float*)d_in[15];
  const float* convW_d  = (const float*)d_in[16];
  const float* convW_p  = (const float*)d_in[18];
  const float* bng_d    = (const float*)d_in[20];
  const float* bnb_d    = (const float*)d_in[21];
  const float* bng_p    = (const float*)d_in[22];
  const float* bnb_p    = (const float*)d_in[23];
  const float* vn_emb_d = (const float*)d_in[24];
  const float* vn_emb_p = (const float*)d_in[25];
  const float* vnW_d    = (const float*)d_in[26];
  const float* vnb_d    = (const float*)d_in[27];
  const float* vnW_p    = (const float*)d_in[28];
  const float* vnb_p    = (const float*)d_in[29];
  const float* mlpd1_W  = (const float*)d_in[30];
  const float* mlpd1_b  = (const float*)d_in[31];
  const float* mlpd1_g  = (const float*)d_in[32];
  const float* mlpd1_be = (const float*)d_in[33];
  const float* mlpp1_W  = (const float*)d_in[34];
  const float* mlpp1_b  = (const float*)d_in[35];
  const float* mlpp1_g  = (const float*)d_in[36];
  const float* mlpp1_be = (const float*)d_in[37];

  const int ND = in_sizes[5];
  const int ED = in_sizes[4] / 2;
  const int SD = in_sizes[6];
  const int NP = in_sizes[9];
  const int EP = in_sizes[8] / 2;
  const int SP = in_sizes[10];
  const int B  = in_sizes[2] / HID;
  (void)n_in; (void)out_size; (void)ws_size;

  char* wsb = (char*)d_ws;
  size_t off = 0;
  auto alloc = [&](size_t bytes) -> void* {
    void* p = (void*)(wsb + off);
    off = (off + bytes + 255) & ~(size_t)255;
    return p;
  };
  // node buffers: fp32 G, split-bf16 Z (doubles as encoder X)
  float* Gp = (float*)alloc((size_t)NP * HID * 4);
  unsigned short* Zhi_p = (unsigned short*)alloc((size_t)NP * HID * 2);
  unsigned short* Zlo_p = (unsigned short*)alloc((size_t)NP * HID * 2);
  float* Gd = (float*)alloc((size_t)ND * HID * 4);
  unsigned short* Zhi_d = (unsigned short*)alloc((size_t)ND * HID * 2);
  unsigned short* Zlo_d = (unsigned short*)alloc((size_t)ND * HID * 2);
  // weights: 0..2 conv_d, 3..5 conv_p, 6 enc_d, 7 enc_p
  unsigned short* WhiAll = (unsigned short*)alloc((size_t)8 * HID * HID * 2);
  unsigned short* WloAll = (unsigned short*)alloc((size_t)8 * HID * HID * 2);
  // CSR + misc
  float* nrm_p = (float*)alloc((size_t)NP * 4);
  float* nrm_d = (float*)alloc((size_t)ND * 4);
  int* deg_p  = (int*)alloc((size_t)NP * 4);
  int* deg_d  = (int*)alloc((size_t)ND * 4);
  int* scnt_p = (int*)alloc((size_t)NP * 4);
  int* scnt_d = (int*)alloc((size_t)ND * 4);
  int* rowE_p = (int*)alloc((size_t)(NP + 1) * 4);
  int* rowE_d = (int*)alloc((size_t)(ND + 1) * 4);
  int* rowS_p = (int*)alloc((size_t)(NP + 1) * 4);
  int* rowS_d = (int*)alloc((size_t)(ND + 1) * 4);
  int* colE_p = (int*)alloc((size_t)EP * 4);
  float* cofE_p = (float*)alloc((size_t)EP * 4);
  int* colE_d = (int*)alloc((size_t)ED * 4);
  float* cofE_d = (float*)alloc((size_t)ED * 4);
  int* colS_p = (int*)alloc((size_t)SP * 4);
  int* colS_d = (int*)alloc((size_t)SD * 4);
  int* cur_p  = (int*)alloc((size_t)NP * 4);
  int* cur_d  = (int*)alloc((size_t)ND * 4);
  int* aux    = (int*)alloc(1024 * 4);
  float* vx_d  = (float*)alloc((size_t)B * HID * 4);
  float* vx_p  = (float*)alloc((size_t)B * HID * 4);
  float* sum_Sd = (float*)alloc((size_t)B * HID * 4);
  float* sum_Sp = (float*)alloc((size_t)B * HID * 4);
  float* A_d   = (float*)alloc((size_t)B * HID * 4);
  float* A_p   = (float*)alloc((size_t)B * HID * 4);
  float* nb_d  = (float*)alloc((size_t)B * 4);
  float* nb_p  = (float*)alloc((size_t)B * 4);
  float* stats_sl = (float*)alloc((size_t)NSLICE * 2 * HID * 4);
  float* statsF   = (float*)alloc(2 * HID * 4);
  float* scsh_d = (float*)alloc(2 * HID * 4);
  float* scsh_p = (float*)alloc(2 * HID * 4);
  float* fpre  = (float*)alloc((size_t)B * HID * 4);

  const int* d_src = d_ei;  const int* d_dst = d_ei + ED;
  const int* p_src = p_ei;  const int* p_dst = p_ei + EP;

  // ---- CSR build (loop-invariant) ----
  hipMemsetAsync(deg_p, 0, (size_t)NP * 4, stream);
  hipMemsetAsync(deg_d, 0, (size_t)ND * 4, stream);
  hipMemsetAsync(scnt_p, 0, (size_t)NP * 4, stream);
  hipMemsetAsync(scnt_d, 0, (size_t)ND * 4, stream);
  hipMemsetAsync(stats_sl, 0, (size_t)NSLICE * 2 * HID * 4, stream);
  k_hist_i<<<1024, 256, 0, stream>>>(d_dst, deg_d, ED);
  k_hist_i<<<2048, 256, 0, stream>>>(p_dst, deg_p, EP);
  k_hist_i<<<1024, 256, 0, stream>>>(d_si, scnt_d, SD);
  k_hist_i<<<2048, 256, 0, stream>>>(p_si, scnt_p, SP);
  k_nrm<<<64, 256, 0, stream>>>(deg_d, nrm_d, ND);
  k_nrm<<<512, 256, 0, stream>>>(deg_p, nrm_p, NP);
  k_nb<<<(B + 127) / 128, 128, 0, stream>>>(d_batch, ND, nb_d, B);
  k_nb<<<(B + 127) / 128, 128, 0, stream>>>(p_batch, NP, nb_p, B);

  const int nbP = (NP + 1023) / 1024, nbD = (ND + 1023) / 1024;
  k_scan1<<<nbP, 256, 0, stream>>>(deg_p, rowE_p, aux, NP);
  k_scan2<<<1, 256, 0, stream>>>(aux, nbP);
  k_scan3<<<256, 256, 0, stream>>>(rowE_p, aux, NP, EP);
  k_scan1<<<nbD, 256, 0, stream>>>(deg_d, rowE_d, aux, ND);
  k_scan2<<<1, 256, 0, stream>>>(aux, nbD);
  k_scan3<<<64, 256, 0, stream>>>(rowE_d, aux, ND, ED);
  k_scan1<<<nbP, 256, 0, stream>>>(scnt_p, rowS_p, aux, NP);
  k_scan2<<<1, 256, 0, stream>>>(aux, nbP);
  k_scan3<<<256, 256, 0, stream>>>(rowS_p, aux, NP, SP);
  k_scan1<<<nbD, 256, 0, stream>>>(scnt_d, rowS_d, aux, ND);
  k_scan2<<<1, 256, 0, stream>>>(aux, nbD);
  k_scan3<<<64, 256, 0, stream>>>(rowS_d, aux, ND, SD);

  hipMemsetAsync(cur_p, 0, (size_t)NP * 4, stream);
  hipMemsetAsync(cur_d, 0, (size_t)ND * 4, stream);
  k_fill_edges<<<2048, 256, 0, stream>>>(p_src, p_dst, rowE_p, cur_p, colE_p, cofE_p, nrm_p, EP);
  k_fill_edges<<<1024, 256, 0, stream>>>(d_src, d_dst, rowE_d, cur_d, colE_d, cofE_d, nrm_d, ED);
  hipMemsetAsync(cur_p, 0, (size_t)NP * 4, stream);
  hipMemsetAsync(cur_d, 0, (size_t)ND * 4, stream);
  k_fill_sub<<<2048, 256, 0, stream>>>(p_sn, p_si, rowS_p, cur_p, colS_p, SP);
  k_fill_sub<<<1024, 256, 0, stream>>>(d_sn, d_si, rowS_d, cur_d, colS_d, SD);

  // ---- weight conversion + encoders (MFMA) + vx init ----
  for (int l = 0; l < 3; ++l) {
    k_wcvt<<<32, 256, 0, stream>>>(convW_d + (size_t)l * HID * HID, 128,
                                   WhiAll + (size_t)l * HID * HID, WloAll + (size_t)l * HID * HID);
    k_wcvt<<<32, 256, 0, stream>>>(convW_p + (size_t)l * HID * HID, 128,
                                   WhiAll + (size_t)(3 + l) * HID * HID, WloAll + (size_t)(3 + l) * HID * HID);
  }
  k_wcvt<<<32, 256, 0, stream>>>(enc_Wd, 78, WhiAll + (size_t)6 * HID * HID, WloAll + (size_t)6 * HID * HID);
  k_wcvt<<<32, 256, 0, stream>>>(enc_Wp, 70, WhiAll + (size_t)7 * HID * HID, WloAll + (size_t)7 * HID * HID);

  k_xcvt<<<1024, 256, 0, stream>>>(drug_x, 78, Zhi_d, Zlo_d, ND * HID);
  k_xcvt<<<4096, 256, 0, stream>>>(prot_x, 70, Zhi_p, Zlo_p, NP * HID);
  k_gemm_mfma<true><<<ND / 128, 256, 0, stream>>>(Zhi_d, Zlo_d, WhiAll + (size_t)6 * HID * HID,
                                                  WloAll + (size_t)6 * HID * HID, enc_bd, Gd, nullptr, ND);
  k_gemm_mfma<true><<<NP / 128, 256, 0, stream>>>(Zhi_p, Zlo_p, WhiAll + (size_t)7 * HID * HID,
                                                  WloAll + (size_t)7 * HID * HID, enc_bp, Gp, nullptr, NP);
  k_vx_init<<<64, 256, 0, stream>>>(vn_emb_d, d_feat, vx_d, B * HID);
  k_vx_init<<<64, 256, 0, stream>>>(vn_emb_p, p_feat, vx_p, B * HID);

  for (int l = 0; l < 3; ++l) {
    // ---------- drug ----------
    if (l == 0)
      k_agg<false><<<ND / 8, 256, 0, stream>>>(rowE_d, colE_d, cofE_d, Gd, nullptr,
                                               d_batch, vx_d, nrm_d, Zhi_d, Zlo_d, ND);
    else
      k_agg<true><<<ND / 8, 256, 0, stream>>>(rowE_d, colE_d, cofE_d, Gd, scsh_d,
                                              d_batch, vx_d, nrm_d, Zhi_d, Zlo_d, ND);
    k_gemm_mfma<false><<<ND / 128, 256, 0, stream>>>(Zhi_d, Zlo_d, WhiAll + (size_t)l * HID * HID,
                                                     WloAll + (size_t)l * HID * HID, nullptr, Gd, stats_sl, ND);
    k_bn_scale<<<1, 128, 0, stream>>>(stats_sl, bng_d + l * HID, bnb_d + l * HID,
                                      1.0f / (float)ND, scsh_d);
    hipMemsetAsync(sum_Sd, 0, (size_t)B * HID * 4, stream);
    k_sub_pool<<<ND / 8, 256, 0, stream>>>(rowS_d, colS_d, Gd, scsh_d, d_batch, sum_Sd, ND);
    if (l < 2)
      k_vn_update<<<B, 128, 0, stream>>>(sum_Sd, vx_d, vnW_d + (size_t)l * HID * HID, vnb_d + l * HID);

    // ---------- protein ----------
    if (l == 0)
      k_agg<false><<<NP / 8, 256, 0, stream>>>(rowE_p, colE_p, cofE_p, Gp, nullptr,
                                               p_batch, vx_p, nrm_p, Zhi_p, Zlo_p, NP);
    else
      k_agg<true><<<NP / 8, 256, 0, stream>>>(rowE_p, colE_p, cofE_p, Gp, scsh_p,
                                              p_batch, vx_p, nrm_p, Zhi_p, Zlo_p, NP);
    k_gemm_mfma<false><<<NP / 128, 256, 0, stream>>>(Zhi_p, Zlo_p, WhiAll + (size_t)(3 + l) * HID * HID,
                                                     WloAll + (size_t)(3 + l) * HID * HID, nullptr, Gp, stats_sl, NP);
    k_bn_scale<<<1, 128, 0, stream>>>(stats_sl, bng_p + l * HID, bnb_p + l * HID,
                                      1.0f / (float)NP, scsh_p);
    hipMemsetAsync(sum_Sp, 0, (size_t)B * HID * 4, stream);
    k_sub_pool<<<NP / 8, 256, 0, stream>>>(rowS_p, colS_p, Gp, scsh_p, p_batch, sum_Sp, NP);
    if (l < 2)
      k_vn_update<<<B, 128, 0, stream>>>(sum_Sp, vx_p, vnW_p + (size_t)l * HID * HID, vnb_p + l * HID);
  }

  // ---- cross-modal sync collapses to pooled means; final MLP + BN ----
  k_final_A<<<B, 128, 0, stream>>>(sum_Sd, sum_Sp, nb_d, nb_p, A_d, A_p);

  float* outf = (float*)d_out;
  k_final_mlp<<<B, 128, 0, stream>>>(A_d, d_feat, mlpd1_W, mlpd1_b, fpre);
  hipMemsetAsync(statsF, 0, 2 * HID * 4, stream);
  k_bn_stats<<<128, 256, 0, stream>>>(fpre, statsF, B);
  k_bn_apply<false><<<64, 256, 0, stream>>>(fpre, outf, statsF, mlpd1_g, mlpd1_be,
                                            B * 32, 1.0f / (float)B);

  k_final_mlp<<<B, 128, 0, stream>>>(A_p, p_feat, mlpp1_W, mlpp1_b, fpre);
  hipMemsetAsync(statsF, 0, 2 * HID * 4, stream);
  k_bn_stats<<<128, 256, 0, stream>>>(fpre, statsF, B);
  k_bn_apply<false><<<64, 256, 0, stream>>>(fpre, outf + (size_t)B * HID, statsF, mlpp1_g, mlpp1_be,
                                            B * 32, 1.0f / (float)B);
}

// Round 8
// 719.731 us; speedup vs baseline: 11.4121x; 1.2260x over previous
//
#include <hip/hip_runtime.h>
#include <cstdint>
#include <cstddef>

#define HID 128

using bf16x8 = __attribute__((ext_vector_type(8))) short;
using f32x4v = __attribute__((ext_vector_type(4))) float;

// ---------------- bf16 helpers (RNE) ----------------
static __device__ __forceinline__ unsigned short f2b(float x) {
  unsigned int u = __float_as_uint(x);
  unsigned int r = u + 0x7FFFu + ((u >> 16) & 1u);
  return (unsigned short)(r >> 16);
}
static __device__ __forceinline__ float b2f(unsigned short h) {
  return __uint_as_float(((unsigned int)h) << 16);
}

static __device__ __forceinline__ int lowerb(const int* __restrict__ a, int n, int v) {
  int lo = 0, hi = n;
  while (lo < hi) { int m = (lo + hi) >> 1; if (a[m] < v) lo = m + 1; else hi = m; }
  return lo;
}

// ---------------- CSR build (merged) ----------------
// 4 segments: (idx,n,cnt) quadruples
__global__ void k_hist_all(const int* i0, int n0, int* c0, const int* i1, int n1, int* c1,
                           const int* i2, int n2, int* c2, const int* i3, int n3, int* c3) {
  const int seg = blockIdx.x & 3;
  const int lb = blockIdx.x >> 2;
  const int stride = (gridDim.x >> 2) * blockDim.x;
  const int start = lb * blockDim.x + threadIdx.x;
  const int* idx = seg == 0 ? i0 : seg == 1 ? i1 : seg == 2 ? i2 : i3;
  int* cnt = seg == 0 ? c0 : seg == 1 ? c1 : seg == 2 ? c2 : c3;
  const int n = seg == 0 ? n0 : seg == 1 ? n1 : seg == 2 ? n2 : n3;
  for (int i = start; i < n; i += stride) atomicAdd(&cnt[idx[i]], 1);
}

// nrm_d, nrm_p from deg; nb_d, nb_p from sorted batch
__global__ void k_nrm_nb(const int* __restrict__ deg_d, float* __restrict__ nrm_d, int ND,
                         const int* __restrict__ deg_p, float* __restrict__ nrm_p, int NP,
                         const int* __restrict__ d_batch, float* __restrict__ nb_d,
                         const int* __restrict__ p_batch, float* __restrict__ nb_p, int B) {
  const int stride = gridDim.x * blockDim.x;
  const int total = ND + NP + 2 * B;
  for (int i = blockIdx.x * blockDim.x + threadIdx.x; i < total; i += stride) {
    if (i < ND) nrm_d[i] = rsqrtf((float)deg_d[i] + 1.0f);
    else if (i < ND + NP) { const int j = i - ND; nrm_p[j] = rsqrtf((float)deg_p[j] + 1.0f); }
    else if (i < ND + NP + B) {
      const int b = i - ND - NP;
      nb_d[b] = (float)(lowerb(d_batch, ND, b + 1) - lowerb(d_batch, ND, b));
    } else {
      const int b = i - ND - NP - B;
      nb_p[b] = (float)(lowerb(p_batch, NP, b + 1) - lowerb(p_batch, NP, b));
    }
  }
}

// segmented scan pass 1: per-1024-chunk exclusive scan; 4 segments
__global__ __launch_bounds__(256)
void k_scan1_all(const int* c0, int* r0, int n0, int nb0,
                 const int* c1, int* r1, int n1, int nb1,
                 const int* c2, int* r2, int n2, int nb2,
                 const int* c3, int* r3, int n3, int nb3, int* aux) {
  __shared__ int sh[256];
  int b = blockIdx.x, seg = 0;
  if (b >= nb0) { b -= nb0; seg = 1; }
  if (seg == 1 && b >= nb1) { b -= nb1; seg = 2; }
  if (seg == 2 && b >= nb2) { b -= nb2; seg = 3; }
  const int* cnt = seg == 0 ? c0 : seg == 1 ? c1 : seg == 2 ? c2 : c3;
  int* row = seg == 0 ? r0 : seg == 1 ? r1 : seg == 2 ? r2 : r3;
  const int n = seg == 0 ? n0 : seg == 1 ? n1 : seg == 2 ? n2 : n3;
  const int tid = threadIdx.x;
  const int base = b * 1024 + tid * 4;
  int v0 = base + 0 < n ? cnt[base + 0] : 0;
  int v1 = base + 1 < n ? cnt[base + 1] : 0;
  int v2 = base + 2 < n ? cnt[base + 2] : 0;
  int v3 = base + 3 < n ? cnt[base + 3] : 0;
  const int s = v0 + v1 + v2 + v3;
  sh[tid] = s;
  __syncthreads();
  for (int o = 1; o < 256; o <<= 1) {
    const int t = (tid >= o) ? sh[tid - o] : 0;
    __syncthreads();
    sh[tid] += t;
    __syncthreads();
  }
  int excl = sh[tid] - s;
  if (tid == 255) aux[seg * 256 + b] = sh[255];
  if (base + 0 < n) row[base + 0] = excl; excl += v0;
  if (base + 1 < n) row[base + 1] = excl; excl += v1;
  if (base + 2 < n) row[base + 2] = excl; excl += v2;
  if (base + 3 < n) row[base + 3] = excl;
}

// pass 2: 4 blocks, each scans its aux segment
__global__ __launch_bounds__(256)
void k_scan2_all(int* aux, int nb0, int nb1, int nb2, int nb3) {
  __shared__ int sh[256];
  const int seg = blockIdx.x;
  const int nb = seg == 0 ? nb0 : seg == 1 ? nb1 : seg == 2 ? nb2 : nb3;
  int* a = aux + seg * 256;
  const int tid = threadIdx.x;
  const int v = tid < nb ? a[tid] : 0;
  sh[tid] = v;
  __syncthreads();
  for (int o = 1; o < 256; o <<= 1) {
    const int t = (tid >= o) ? sh[tid - o] : 0;
    __syncthreads();
    sh[tid] += t;
    __syncthreads();
  }
  if (tid < nb) a[tid] = sh[tid] - v;
}

// pass 3: add chunk offsets; segment block 0 writes row[n]=total
__global__ __launch_bounds__(256)
void k_scan3_all(int* r0, int n0, int nb0, int t0, int* r1, int n1, int nb1, int t1,
                 int* r2, int n2, int nb2, int t2, int* r3, int n3, int nb3, int t3,
                 const int* aux) {
  int b = blockIdx.x, seg = 0;
  if (b >= nb0) { b -= nb0; seg = 1; }
  if (seg == 1 && b >= nb1) { b -= nb1; seg = 2; }
  if (seg == 2 && b >= nb2) { b -= nb2; seg = 3; }
  int* row = seg == 0 ? r0 : seg == 1 ? r1 : seg == 2 ? r2 : r3;
  const int n = seg == 0 ? n0 : seg == 1 ? n1 : seg == 2 ? n2 : n3;
  const int total = seg == 0 ? t0 : seg == 1 ? t1 : seg == 2 ? t2 : t3;
  const int add = aux[seg * 256 + b];
  const int base = b * 1024 + threadIdx.x * 4;
  #pragma unroll
  for (int k = 0; k < 4; ++k)
    if (base + k < n) row[base + k] += add;
  if (b == 0 && threadIdx.x == 0) row[n] = total;
}

// fill all 4 CSRs: seg 0 edges_p, 1 edges_d, 2 subs_p, 3 subs_d
__global__ void k_fill_all(const int* p_src, const int* p_dst, const int* rowE_p, int* curE_p,
                           int* colE_p, float* cofE_p, const float* nrm_p, int EP,
                           const int* d_src, const int* d_dst, const int* rowE_d, int* curE_d,
                           int* colE_d, float* cofE_d, const float* nrm_d, int ED,
                           const int* p_sn, const int* p_si, const int* rowS_p, int* curS_p,
                           int* colS_p, int SP,
                           const int* d_sn, const int* d_si, const int* rowS_d, int* curS_d,
                           int* colS_d, int SD) {
  const int seg = blockIdx.x & 3;
  const int lb = blockIdx.x >> 2;
  const int stride = (gridDim.x >> 2) * blockDim.x;
  const int start = lb * blockDim.x + threadIdx.x;
  if (seg == 0) {
    for (int e = start; e < EP; e += stride) {
      const int d = p_dst[e], s = p_src[e];
      const int pos = rowE_p[d] + atomicAdd(&curE_p[d], 1);
      colE_p[pos] = s;
      cofE_p[pos] = nrm_p[s] * nrm_p[d];
    }
  } else if (seg == 1) {
    for (int e = start; e < ED; e += stride) {
      const int d = d_dst[e], s = d_src[e];
      const int pos = rowE_d[d] + atomicAdd(&curE_d[d], 1);
      colE_d[pos] = s;
      cofE_d[pos] = nrm_d[s] * nrm_d[d];
    }
  } else if (seg == 2) {
    for (int j = start; j < SP; j += stride) {
      const int t = p_si[j];
      const int pos = rowS_p[t] + atomicAdd(&curS_p[t], 1);
      colS_p[pos] = p_sn[j];
    }
  } else {
    for (int j = start; j < SD; j += stride) {
      const int t = d_si[j];
      const int pos = rowS_d[t] + atomicAdd(&curS_d[t], 1);
      colS_d[pos] = d_sn[j];
    }
  }
}

// ---------------- conversions ----------------
// vx init for both sides
__global__ void k_vx_init_both(const float* __restrict__ emb_d, const float* __restrict__ d_feat,
                               float* __restrict__ vx_d, const float* __restrict__ emb_p,
                               const float* __restrict__ p_feat, float* __restrict__ vx_p,
                               int half) {
  const int stride = gridDim.x * blockDim.x;
  for (int i = blockIdx.x * blockDim.x + threadIdx.x; i < 2 * half; i += stride) {
    if (i < half) vx_d[i] = emb_d[i & (HID - 1)] + d_feat[i];
    else { const int j = i - half; vx_p[j] = emb_p[j & (HID - 1)] + p_feat[j]; }
  }
}

// 8 weight matrices -> transposed padded split-bf16. seg: 0-2 conv_d, 3-5 conv_p, 6 enc_d, 7 enc_p
__global__ __launch_bounds__(256)
void k_wcvt_all(const float* __restrict__ convW_d, const float* __restrict__ convW_p,
                const float* __restrict__ enc_Wd, const float* __restrict__ enc_Wp,
                unsigned short* __restrict__ WhiAll, unsigned short* __restrict__ WloAll) {
  const int seg = blockIdx.x >> 5;
  const int lb = blockIdx.x & 31;
  const float* W;
  int K;
  if (seg < 3) { W = convW_d + (size_t)seg * HID * HID; K = 128; }
  else if (seg < 6) { W = convW_p + (size_t)(seg - 3) * HID * HID; K = 128; }
  else if (seg == 6) { W = enc_Wd; K = 78; }
  else { W = enc_Wp; K = 70; }
  unsigned short* Whi = WhiAll + (size_t)seg * HID * HID;
  unsigned short* Wlo = WloAll + (size_t)seg * HID * HID;
  for (int i = lb * 256 + threadIdx.x; i < HID * HID; i += 32 * 256) {
    const int c = i >> 7, k = i & 127;
    const float v = (k < K) ? W[k * HID + c] : 0.f;
    const unsigned short hi = f2b(v);
    Whi[i] = hi;
    Wlo[i] = f2b(v - b2f(hi));
  }
}

// X [N][K] fp32 -> padded split-bf16 [N][128]; both graphs in one launch
__global__ void k_xcvt_both(const float* __restrict__ Xd, int Kd, unsigned short* __restrict__ Dhi,
                            unsigned short* __restrict__ Dlo, int totD,
                            const float* __restrict__ Xp, int Kp, unsigned short* __restrict__ Phi,
                            unsigned short* __restrict__ Plo, int totP) {
  const int stride = gridDim.x * blockDim.x;
  for (int i = blockIdx.x * blockDim.x + threadIdx.x; i < totD + totP; i += stride) {
    if (i < totD) {
      const int node = i >> 7, k = i & 127;
      const float v = (k < Kd) ? Xd[(size_t)node * Kd + k] : 0.f;
      const unsigned short hi = f2b(v);
      Dhi[i] = hi;
      Dlo[i] = f2b(v - b2f(hi));
    } else {
      const int j = i - totD;
      const int node = j >> 7, k = j & 127;
      const float v = (k < Kp) ? Xp[(size_t)node * Kp + k] : 0.f;
      const unsigned short hi = f2b(v);
      Phi[j] = hi;
      Plo[j] = f2b(v - b2f(hi));
    }
  }
}

// ---------------- split-bf16 MFMA GEMM, both graphs ----------------
// G ≈ Zhi·Whi + Zhi·Wlo + Zlo·Whi. ENC: +bias, no stats. else: BN-stats into stats_sl
// (drug slices 0..31, protein 32..63).
template<bool ENC>
__global__ __launch_bounds__(256, 2)
void k_gemm_both(const unsigned short* __restrict__ Zhi0, const unsigned short* __restrict__ Zlo0,
                 const unsigned short* __restrict__ Whi0, const unsigned short* __restrict__ Wlo0,
                 const float* __restrict__ bias0, float* __restrict__ G0, int nbk0,
                 const unsigned short* __restrict__ Zhi1, const unsigned short* __restrict__ Zlo1,
                 const unsigned short* __restrict__ Whi1, const unsigned short* __restrict__ Wlo1,
                 const float* __restrict__ bias1, float* __restrict__ G1,
                 float* __restrict__ stats_sl) {
  __shared__ unsigned short Bt[128 * 132];
  __shared__ float lstats[256];
  const int bid = blockIdx.x;
  const bool isP = bid >= nbk0;
  const int lb = isP ? bid - nbk0 : bid;
  const unsigned short* Zhi = isP ? Zhi1 : Zhi0;
  const unsigned short* Zlo = isP ? Zlo1 : Zlo0;
  const unsigned short* Wthi = isP ? Whi1 : Whi0;
  const unsigned short* Wtlo = isP ? Wlo1 : Wlo0;
  const float* bias = isP ? bias1 : bias0;
  float* G = isP ? G1 : G0;

  const int tid = threadIdx.x;
  const int w = tid >> 6;
  const int l = tid & 63;
  const int l15 = l & 15;
  const int kb = l >> 4;

  for (int i = tid; i < 128 * 16; i += 256) {
    const int c = i >> 4, k8 = i & 15;
    *(bf16x8*)(&Bt[c * 132 + k8 * 8]) = *(const bf16x8*)(Wthi + (size_t)c * 128 + k8 * 8);
  }
  if constexpr (!ENC) lstats[tid] = 0.f;

  const int rbase = lb * 128 + w * 32 + l15;
  bf16x8 ahi[2][4], alo[2][4];
  #pragma unroll
  for (int rt = 0; rt < 2; ++rt)
    #pragma unroll
    for (int ks = 0; ks < 4; ++ks) {
      ahi[rt][ks] = *(const bf16x8*)(Zhi + (size_t)(rbase + rt * 16) * 128 + ks * 32 + kb * 8);
      alo[rt][ks] = *(const bf16x8*)(Zlo + (size_t)(rbase + rt * 16) * 128 + ks * 32 + kb * 8);
    }

  f32x4v acc[2][8];
  #pragma unroll
  for (int rt = 0; rt < 2; ++rt)
    #pragma unroll
    for (int ct = 0; ct < 8; ++ct)
      acc[rt][ct] = (f32x4v){0.f, 0.f, 0.f, 0.f};

  __syncthreads();
  #pragma unroll
  for (int ks = 0; ks < 4; ++ks) {
    #pragma unroll
    for (int ct = 0; ct < 8; ++ct) {
      const bf16x8 b = *(const bf16x8*)(&Bt[(ct * 16 + l15) * 132 + ks * 32 + kb * 8]);
      acc[0][ct] = __builtin_amdgcn_mfma_f32_16x16x32_bf16(ahi[0][ks], b, acc[0][ct], 0, 0, 0);
      acc[1][ct] = __builtin_amdgcn_mfma_f32_16x16x32_bf16(ahi[1][ks], b, acc[1][ct], 0, 0, 0);
      acc[0][ct] = __builtin_amdgcn_mfma_f32_16x16x32_bf16(alo[0][ks], b, acc[0][ct], 0, 0, 0);
      acc[1][ct] = __builtin_amdgcn_mfma_f32_16x16x32_bf16(alo[1][ks], b, acc[1][ct], 0, 0, 0);
    }
  }
  __syncthreads();

  for (int i = tid; i < 128 * 16; i += 256) {
    const int c = i >> 4, k8 = i & 15;
    *(bf16x8*)(&Bt[c * 132 + k8 * 8]) = *(const bf16x8*)(Wtlo + (size_t)c * 128 + k8 * 8);
  }
  __syncthreads();
  #pragma unroll
  for (int ks = 0; ks < 4; ++ks) {
    #pragma unroll
    for (int ct = 0; ct < 8; ++ct) {
      const bf16x8 b = *(const bf16x8*)(&Bt[(ct * 16 + l15) * 132 + ks * 32 + kb * 8]);
      acc[0][ct] = __builtin_amdgcn_mfma_f32_16x16x32_bf16(ahi[0][ks], b, acc[0][ct], 0, 0, 0);
      acc[1][ct] = __builtin_amdgcn_mfma_f32_16x16x32_bf16(ahi[1][ks], b, acc[1][ct], 0, 0, 0);
    }
  }

  float bb[8];
  if constexpr (ENC) {
    #pragma unroll
    for (int ct = 0; ct < 8; ++ct) bb[ct] = bias[ct * 16 + l15];
  }
  float csum[8], csq[8];
  #pragma unroll
  for (int ct = 0; ct < 8; ++ct) { csum[ct] = 0.f; csq[ct] = 0.f; }
  #pragma unroll
  for (int rt = 0; rt < 2; ++rt) {
    const size_t grow = (size_t)lb * 128 + w * 32 + rt * 16 + (l >> 4) * 4;
    #pragma unroll
    for (int j = 0; j < 4; ++j) {
      float* gr = G + (grow + j) * 128 + l15;
      #pragma unroll
      for (int ct = 0; ct < 8; ++ct) {
        float v = acc[rt][ct][j];
        if constexpr (ENC) v += bb[ct];
        gr[ct * 16] = v;
        if constexpr (!ENC) { csum[ct] += v; csq[ct] += v * v; }
      }
    }
  }
  if constexpr (!ENC) {
    #pragma unroll
    for (int ct = 0; ct < 8; ++ct) {
      csum[ct] += __shfl_xor(csum[ct], 16);
      csum[ct] += __shfl_xor(csum[ct], 32);
      csq[ct] += __shfl_xor(csq[ct], 16);
      csq[ct] += __shfl_xor(csq[ct], 32);
    }
    if (l < 16) {
      #pragma unroll
      for (int ct = 0; ct < 8; ++ct) {
        atomicAdd(&lstats[ct * 16 + l], csum[ct]);
        atomicAdd(&lstats[128 + ct * 16 + l], csq[ct]);
      }
    }
    __syncthreads();
    const int slice = (isP ? 32 : 0) + (lb & 31);
    atomicAdd(&stats_sl[(size_t)slice * 256 + tid], lstats[tid]);
  }
}

// fold stat slices -> scale/shift for both graphs; re-zeros its slices
__global__ __launch_bounds__(128)
void k_bn_scale_both(float* __restrict__ stats_sl,
                     const float* g0, const float* b0, float invN0, float* scsh0,
                     const float* g1, const float* b1, float invN1, float* scsh1) {
  const int seg = blockIdx.x;
  float* base = stats_sl + (size_t)seg * 32 * 256;
  const float* g = seg ? g1 : g0;
  const float* bb = seg ? b1 : b0;
  const float invN = seg ? invN1 : invN0;
  float* scsh = seg ? scsh1 : scsh0;
  const int c = threadIdx.x;
  float s = 0.f, ss = 0.f;
  for (int k = 0; k < 32; ++k) {
    s += base[(size_t)k * 256 + c];
    ss += base[(size_t)k * 256 + 128 + c];
    base[(size_t)k * 256 + c] = 0.f;
    base[(size_t)k * 256 + 128 + c] = 0.f;
  }
  const float m = s * invN;
  const float var = ss * invN - m * m;
  const float sc = g[c] * rsqrtf(var + 1e-5f);
  scsh[c] = sc;
  scsh[HID + c] = bb[c] - m * sc;
}

// fused upass+agg for both graphs: Z_i = nrm_i^2*u(i) + sum_e coef*u(col), u = f(G)+vx[batch]
template<bool HASF>
__global__ __launch_bounds__(256)
void k_agg_both(const int* rE0, const int* cE0, const float* wE0, const float* G0,
                const float* scsh0, const int* bat0, const float* vx0, const float* nrm0,
                unsigned short* Zhi0, unsigned short* Zlo0, int nbk0,
                const int* rE1, const int* cE1, const float* wE1, const float* G1,
                const float* scsh1, const int* bat1, const float* vx1, const float* nrm1,
                unsigned short* Zhi1, unsigned short* Zlo1) {
  const int bid = blockIdx.x;
  const bool isP = bid >= nbk0;
  const int lb = isP ? bid - nbk0 : bid;
  const int* rowp = isP ? rE1 : rE0;
  const int* colp = isP ? cE1 : cE0;
  const float* coefp = isP ? wE1 : wE0;
  const float* G = isP ? G1 : G0;
  const float* scsh = isP ? scsh1 : scsh0;
  const int* batch = isP ? bat1 : bat0;
  const float* vx = isP ? vx1 : vx0;
  const float* nrm = isP ? nrm1 : nrm0;
  unsigned short* Zhi = isP ? Zhi1 : Zhi0;
  unsigned short* Zlo = isP ? Zlo1 : Zlo0;

  const int tid = threadIdx.x;
  const int node = lb * 8 + (tid >> 5);
  const int c4 = tid & 31;
  float4 sc, shv;
  if constexpr (HASF) {
    sc = ((const float4*)scsh)[c4];
    shv = ((const float4*)(scsh + HID))[c4];
  }
  auto loadU = [&](int i) -> float4 {
    float4 v = *(const float4*)(G + (size_t)i * HID + c4 * 4);
    if constexpr (HASF) {
      v.x = fmaxf(v.x * sc.x + shv.x, 0.f);
      v.y = fmaxf(v.y * sc.y + shv.y, 0.f);
      v.z = fmaxf(v.z * sc.z + shv.z, 0.f);
      v.w = fmaxf(v.w * sc.w + shv.w, 0.f);
    }
    const float4 u = *(const float4*)(vx + (size_t)batch[i] * HID + c4 * 4);
    v.x += u.x; v.y += u.y; v.z += u.z; v.w += u.w;
    return v;
  };
  const int lo = rowp[node], hi = rowp[node + 1];
  const float nv = nrm[node];
  const float s2 = nv * nv;
  float4 acc = loadU(node);
  acc.x *= s2; acc.y *= s2; acc.z *= s2; acc.w *= s2;
  int e = lo;
  for (; e + 4 <= hi; e += 4) {
    const float w0 = coefp[e], w1 = coefp[e + 1], w2 = coefp[e + 2], w3 = coefp[e + 3];
    const float4 v0 = loadU(colp[e]);
    const float4 v1 = loadU(colp[e + 1]);
    const float4 v2 = loadU(colp[e + 2]);
    const float4 v3 = loadU(colp[e + 3]);
    acc.x += v0.x * w0 + v1.x * w1 + v2.x * w2 + v3.x * w3;
    acc.y += v0.y * w0 + v1.y * w1 + v2.y * w2 + v3.y * w3;
    acc.z += v0.z * w0 + v1.z * w1 + v2.z * w2 + v3.z * w3;
    acc.w += v0.w * w0 + v1.w * w1 + v2.w * w2 + v3.w * w3;
  }
  for (; e < hi; ++e) {
    const float w = coefp[e];
    const float4 v = loadU(colp[e]);
    acc.x += v.x * w; acc.y += v.y * w; acc.z += v.z * w; acc.w += v.w * w;
  }
  ushort4 h, lo4;
  h.x = f2b(acc.x); lo4.x = f2b(acc.x - b2f(h.x));
  h.y = f2b(acc.y); lo4.y = f2b(acc.y - b2f(h.y));
  h.z = f2b(acc.z); lo4.z = f2b(acc.z - b2f(h.z));
  h.w = f2b(acc.w); lo4.w = f2b(acc.w - b2f(h.w));
  *(ushort4*)(Zhi + (size_t)node * HID + c4 * 4) = h;
  *(ushort4*)(Zlo + (size_t)node * HID + c4 * 4) = lo4;
}

// fused sub-gather + batch pooling for both graphs
__global__ __launch_bounds__(256)
void k_sub_pool_both(const int* rS0, const int* cS0, const float* G0, const float* scsh0,
                     const int* bat0, float* sumS0, int nbk0,
                     const int* rS1, const int* cS1, const float* G1, const float* scsh1,
                     const int* bat1, float* sumS1) {
  __shared__ float sh[8][HID];
  __shared__ int batl[8];
  const int bid = blockIdx.x;
  const bool isP = bid >= nbk0;
  const int lb = isP ? bid - nbk0 : bid;
  const int* rowp = isP ? rS1 : rS0;
  const int* colp = isP ? cS1 : cS0;
  const float* G = isP ? G1 : G0;
  const float* scsh = isP ? scsh1 : scsh0;
  const int* batch = isP ? bat1 : bat0;
  float* sumS = isP ? sumS1 : sumS0;

  const int tid = threadIdx.x;
  const int grp = tid >> 5;
  const int node = lb * 8 + grp;
  const int c4 = tid & 31;
  const float4 sc = ((const float4*)scsh)[c4];
  const float4 shv = ((const float4*)(scsh + HID))[c4];
  const int lo = rowp[node], hi = rowp[node + 1];
  float4 acc = {0.f, 0.f, 0.f, 0.f};
  int e = lo;
  for (; e + 4 <= hi; e += 4) {
    const int i0 = colp[e], i1 = colp[e + 1], i2 = colp[e + 2], i3 = colp[e + 3];
    const float4 v0 = *(const float4*)(G + (size_t)i0 * HID + c4 * 4);
    const float4 v1 = *(const float4*)(G + (size_t)i1 * HID + c4 * 4);
    const float4 v2 = *(const float4*)(G + (size_t)i2 * HID + c4 * 4);
    const float4 v3 = *(const float4*)(G + (size_t)i3 * HID + c4 * 4);
    acc.x += fmaxf(v0.x * sc.x + shv.x, 0.f) + fmaxf(v1.x * sc.x + shv.x, 0.f)
           + fmaxf(v2.x * sc.x + shv.x, 0.f) + fmaxf(v3.x * sc.x + shv.x, 0.f);
    acc.y += fmaxf(v0.y * sc.y + shv.y, 0.f) + fmaxf(v1.y * sc.y + shv.y, 0.f)
           + fmaxf(v2.y * sc.y + shv.y, 0.f) + fmaxf(v3.y * sc.y + shv.y, 0.f);
    acc.z += fmaxf(v0.z * sc.z + shv.z, 0.f) + fmaxf(v1.z * sc.z + shv.z, 0.f)
           + fmaxf(v2.z * sc.z + shv.z, 0.f) + fmaxf(v3.z * sc.z + shv.z, 0.f);
    acc.w += fmaxf(v0.w * sc.w + shv.w, 0.f) + fmaxf(v1.w * sc.w + shv.w, 0.f)
           + fmaxf(v2.w * sc.w + shv.w, 0.f) + fmaxf(v3.w * sc.w + shv.w, 0.f);
  }
  for (; e < hi; ++e) {
    const float4 v = *(const float4*)(G + (size_t)colp[e] * HID + c4 * 4);
    acc.x += fmaxf(v.x * sc.x + shv.x, 0.f);
    acc.y += fmaxf(v.y * sc.y + shv.y, 0.f);
    acc.z += fmaxf(v.z * sc.z + shv.z, 0.f);
    acc.w += fmaxf(v.w * sc.w + shv.w, 0.f);
  }
  const float inv = 1.0f / fmaxf((float)(hi - lo), 1.0f);
  acc.x *= inv; acc.y *= inv; acc.z *= inv; acc.w *= inv;
  ((float4*)&sh[grp][0])[c4] = acc;
  if (tid < 8) batl[tid] = batch[lb * 8 + tid];
  __syncthreads();
  if (tid < HID) {
    int cur = batl[0];
    float a = 0.f;
    #pragma unroll
    for (int g = 0; g < 8; ++g) {
      if (batl[g] != cur) {
        atomicAdd(&sumS[(size_t)cur * HID + tid], a);
        a = 0.f;
        cur = batl[g];
      }
      a += sh[g][tid];
    }
    atomicAdd(&sumS[(size_t)cur * HID + tid], a);
  }
}

// vn update for both graphs (grid 2B)
__global__ __launch_bounds__(128)
void k_vn_update_both(const float* ps0, float* vx0, const float* W0, const float* b0,
                      const float* ps1, float* vx1, const float* W1, const float* b1, int B) {
  const int gb = blockIdx.x;
  const bool isP = gb >= B;
  const int b = isP ? gb - B : gb;
  const float* pooledSum = isP ? ps1 : ps0;
  float* vx = isP ? vx1 : vx0;
  const float* W = isP ? W1 : W0;
  const float* bias = isP ? b1 : b0;
  const int c = threadIdx.x;
  __shared__ float xin[HID];
  xin[c] = pooledSum[(size_t)b * HID + c] + vx[(size_t)b * HID + c];
  __syncthreads();
  float acc = bias[c];
  #pragma unroll 8
  for (int k = 0; k < HID; k += 4) {
    const float4 x = *(const float4*)&xin[k];
    acc += x.x * W[k * HID + c] + x.y * W[(k + 1) * HID + c]
         + x.z * W[(k + 2) * HID + c] + x.w * W[(k + 3) * HID + c];
  }
  vx[(size_t)b * HID + c] += fmaxf(acc, 0.0f);
}

__global__ __launch_bounds__(128)
void k_final_A(const float* __restrict__ sum_Sd, const float* __restrict__ sum_Sp,
               const float* __restrict__ nb_d, const float* __restrict__ nb_p,
               float* __restrict__ A_d, float* __restrict__ A_p) {
  const int b = blockIdx.x, c = threadIdx.x;
  const float nd = nb_d[b], np_ = nb_p[b];
  const float md = sum_Sd[(size_t)b * HID + c] / fmaxf(nd, 1.f);
  const float mp = sum_Sp[(size_t)b * HID + c] / fmaxf(np_, 1.f);
  A_d[(size_t)b * HID + c] = md + (nd > 0.f ? mp : 0.f);
  A_p[(size_t)b * HID + c] = mp + (np_ > 0.f ? md : 0.f);
}

// final MLP for both sides -> fpre[2B][128]
__global__ __launch_bounds__(128)
void k_final_mlp_both(const float* A0, const float* f0, const float* W0, const float* b0,
                      const float* A1, const float* f1, const float* W1, const float* b1,
                      float* __restrict__ fpre, int B) {
  const int gb = blockIdx.x;
  const bool isP = gb >= B;
  const int b = isP ? gb - B : gb;
  const float* A = isP ? A1 : A0;
  const float* feat = isP ? f1 : f0;
  const float* W = isP ? W1 : W0;
  const float* bias = isP ? b1 : b0;
  const int c = threadIdx.x;
  __shared__ float xin[2 * HID];
  xin[c] = A[(size_t)b * HID + c];
  xin[HID + c] = feat[(size_t)b * HID + c];
  __syncthreads();
  float acc = bias[c];
  #pragma unroll 8
  for (int k = 0; k < 2 * HID; k += 4) {
    const float4 x = *(const float4*)&xin[k];
    acc += x.x * W[k * HID + c] + x.y * W[(k + 1) * HID + c]
         + x.z * W[(k + 2) * HID + c] + x.w * W[(k + 3) * HID + c];
  }
  fpre[(size_t)gb * HID + c] = acc;
}

// BN stats over fpre's two halves into statsF[0..255] / statsF[256..511]
__global__ __launch_bounds__(256)
void k_bn_stats_both(const float* __restrict__ fpre, float* __restrict__ statsF, int B) {
  __shared__ float sh[2][256];
  const int seg = blockIdx.x >= 128 ? 1 : 0;
  const int lb = blockIdx.x - seg * 128;
  const float* X = fpre + (size_t)seg * B * HID;
  float* stats = statsF + seg * 256;
  const int tid = threadIdx.x;
  const int c = tid & (HID - 1);
  const int half = tid >> 7;
  float s = 0.f, ss = 0.f;
  for (int r = lb * 2 + half; r < B; r += 256) {
    const float v = X[(size_t)r * HID + c];
    s += v; ss += v * v;
  }
  sh[0][tid] = s; sh[1][tid] = ss;
  __syncthreads();
  if (tid < HID) {
    atomicAdd(&stats[c], sh[0][tid] + sh[0][tid + 128]);
    atomicAdd(&stats[HID + c], sh[1][tid] + sh[1][tid + 128]);
  }
}

// BN apply over both halves: out[2B][128]
__global__ void k_bn_apply_both(const float* __restrict__ fpre, float* __restrict__ out,
                                const float* __restrict__ statsF,
                                const float* g0, const float* b0,
                                const float* g1, const float* b1, int B, float invN) {
  const int stride = gridDim.x * blockDim.x;
  const int n4 = 2 * B * 32;
  for (int i = blockIdx.x * blockDim.x + threadIdx.x; i < n4; i += stride) {
    const int seg = i >= B * 32 ? 1 : 0;
    const int c4 = i & 31;
    const float* stats = statsF + seg * 256;
    const float4 m4 = ((const float4*)stats)[c4];
    const float4 q4 = ((const float4*)stats)[32 + c4];
    const float4 g4 = ((const float4*)(seg ? g1 : g0))[c4];
    const float4 b4 = ((const float4*)(seg ? b1 : b0))[c4];
    float4 v = ((const float4*)fpre)[i];
    float m, va;
    m = m4.x * invN; va = q4.x * invN - m * m; v.x = (v.x - m) * rsqrtf(va + 1e-5f) * g4.x + b4.x;
    m = m4.y * invN; va = q4.y * invN - m * m; v.y = (v.y - m) * rsqrtf(va + 1e-5f) * g4.y + b4.y;
    m = m4.z * invN; va = q4.z * invN - m * m; v.z = (v.z - m) * rsqrtf(va + 1e-5f) * g4.z + b4.z;
    m = m4.w * invN; va = q4.w * invN - m * m; v.w = (v.w - m) * rsqrtf(va + 1e-5f) * g4.w + b4.w;
    ((float4*)out)[i] = v;
  }
}

// ---------------- host launch ----------------
extern "C" void kernel_launch(void* const* d_in, const int* in_sizes, int n_in,
                              void* d_out, int out_size, void* d_ws, size_t ws_size,
                              hipStream_t stream) {
  const float* drug_x   = (const float*)d_in[0];
  const float* prot_x   = (const float*)d_in[1];
  const float* d_feat   = (const float*)d_in[2];
  const float* p_feat   = (const float*)d_in[3];
  const int*   d_ei     = (const int*)d_in[4];
  const int*   d_batch  = (const int*)d_in[5];
  const int*   d_sn     = (const int*)d_in[6];
  const int*   d_si     = (const int*)d_in[7];
  const int*   p_ei     = (const int*)d_in[8];
  const int*   p_batch  = (const int*)d_in[9];
  const int*   p_sn     = (const int*)d_in[10];
  const int*   p_si     = (const int*)d_in[11];
  const float* enc_Wd   = (const float*)d_in[12];
  const float* enc_bd   = (const float*)d_in[13];
  const float* enc_Wp   = (const float*)d_in[14];
  const float* enc_bp   = (const float*)d_in[15];
  const float* convW_d  = (const float*)d_in[16];
  const float* convW_p  = (const float*)d_in[18];
  const float* bng_d    = (const float*)d_in[20];
  const float* bnb_d    = (const float*)d_in[21];
  const float* bng_p    = (const float*)d_in[22];
  const float* bnb_p    = (const float*)d_in[23];
  const float* vn_emb_d = (const float*)d_in[24];
  const float* vn_emb_p = (const float*)d_in[25];
  const float* vnW_d    = (const float*)d_in[26];
  const float* vnb_d    = (const float*)d_in[27];
  const float* vnW_p    = (const float*)d_in[28];
  const float* vnb_p    = (const float*)d_in[29];
  const float* mlpd1_W  = (const float*)d_in[30];
  const float* mlpd1_b  = (const float*)d_in[31];
  const float* mlpd1_g  = (const float*)d_in[32];
  const float* mlpd1_be = (const float*)d_in[33];
  const float* mlpp1_W  = (const float*)d_in[34];
  const float* mlpp1_b  = (const float*)d_in[35];
  const float* mlpp1_g  = (const float*)d_in[36];
  const float* mlpp1_be = (const float*)d_in[37];

  const int ND = in_sizes[5];
  const int ED = in_sizes[4] / 2;
  const int SD = in_sizes[6];
  const int NP = in_sizes[9];
  const int EP = in_sizes[8] / 2;
  const int SP = in_sizes[10];
  const int B  = in_sizes[2] / HID;
  (void)n_in; (void)out_size; (void)ws_size;

  char* wsb = (char*)d_ws;
  size_t off = 0;
  auto alloc = [&](size_t bytes) -> void* {
    void* p = (void*)(wsb + off);
    off = (off + bytes + 255) & ~(size_t)255;
    return p;
  };
  // node buffers
  float* Gp = (float*)alloc((size_t)NP * HID * 4);
  unsigned short* Zhi_p = (unsigned short*)alloc((size_t)NP * HID * 2);
  unsigned short* Zlo_p = (unsigned short*)alloc((size_t)NP * HID * 2);
  float* Gd = (float*)alloc((size_t)ND * HID * 4);
  unsigned short* Zhi_d = (unsigned short*)alloc((size_t)ND * HID * 2);
  unsigned short* Zlo_d = (unsigned short*)alloc((size_t)ND * HID * 2);
  unsigned short* WhiAll = (unsigned short*)alloc((size_t)8 * HID * HID * 2);
  unsigned short* WloAll = (unsigned short*)alloc((size_t)8 * HID * HID * 2);
  // CSR
  float* nrm_p = (float*)alloc((size_t)NP * 4);
  float* nrm_d = (float*)alloc((size_t)ND * 4);
  int* rowE_p = (int*)alloc((size_t)(NP + 1) * 4);
  int* rowE_d = (int*)alloc((size_t)(ND + 1) * 4);
  int* rowS_p = (int*)alloc((size_t)(NP + 1) * 4);
  int* rowS_d = (int*)alloc((size_t)(ND + 1) * 4);
  int* colE_p = (int*)alloc((size_t)EP * 4);
  float* cofE_p = (float*)alloc((size_t)EP * 4);
  int* colE_d = (int*)alloc((size_t)ED * 4);
  float* cofE_d = (float*)alloc((size_t)ED * 4);
  int* colS_p = (int*)alloc((size_t)SP * 4);
  int* colS_d = (int*)alloc((size_t)SD * 4);
  int* aux    = (int*)alloc(4 * 256 * 4);
  float* vx_d  = (float*)alloc((size_t)B * HID * 4);
  float* vx_p  = (float*)alloc((size_t)B * HID * 4);
  float* sum_Sd = (float*)alloc((size_t)B * HID * 4);   // adjacent with sum_Sp
  float* sum_Sp = (float*)alloc((size_t)B * HID * 4);
  float* A_d   = (float*)alloc((size_t)B * HID * 4);
  float* A_p   = (float*)alloc((size_t)B * HID * 4);
  float* nb_d  = (float*)alloc((size_t)B * 4);
  float* nb_p  = (float*)alloc((size_t)B * 4);
  float* scsh_d = (float*)alloc(2 * HID * 4);
  float* scsh_p = (float*)alloc(2 * HID * 4);
  float* fpre  = (float*)alloc((size_t)2 * B * HID * 4);
  float* statsF = (float*)alloc(2 * 256 * 4);
  // zero region: deg/scnt/cur x4 + stats_sl (64 slices)
  const size_t zstart = off;
  int* deg_p  = (int*)alloc((size_t)NP * 4);
  int* deg_d  = (int*)alloc((size_t)ND * 4);
  int* scnt_p = (int*)alloc((size_t)NP * 4);
  int* scnt_d = (int*)alloc((size_t)ND * 4);
  int* curE_p = (int*)alloc((size_t)NP * 4);
  int* curE_d = (int*)alloc((size_t)ND * 4);
  int* curS_p = (int*)alloc((size_t)NP * 4);
  int* curS_d = (int*)alloc((size_t)ND * 4);
  float* stats_sl = (float*)alloc((size_t)64 * 256 * 4);
  const size_t zend = off;

  const int* d_src = d_ei;  const int* d_dst = d_ei + ED;
  const int* p_src = p_ei;  const int* p_dst = p_ei + EP;

  // ---- 1 memset + CSR build (7 launches) ----
  hipMemsetAsync(wsb + zstart, 0, zend - zstart, stream);
  k_hist_all<<<4096, 256, 0, stream>>>(p_dst, EP, deg_p, d_dst, ED, deg_d,
                                       p_si, SP, scnt_p, d_si, SD, scnt_d);
  k_nrm_nb<<<1024, 256, 0, stream>>>(deg_d, nrm_d, ND, deg_p, nrm_p, NP,
                                     d_batch, nb_d, p_batch, nb_p, B);
  const int nbP = (NP + 1023) / 1024, nbD = (ND + 1023) / 1024;
  k_scan1_all<<<2 * nbP + 2 * nbD, 256, 0, stream>>>(
      deg_p, rowE_p, NP, nbP, deg_d, rowE_d, ND, nbD,
      scnt_p, rowS_p, NP, nbP, scnt_d, rowS_d, ND, nbD, aux);
  k_scan2_all<<<4, 256, 0, stream>>>(aux, nbP, nbD, nbP, nbD);
  k_scan3_all<<<2 * nbP + 2 * nbD, 256, 0, stream>>>(
      rowE_p, NP, nbP, EP, rowE_d, ND, nbD, ED,
      rowS_p, NP, nbP, SP, rowS_d, ND, nbD, SD, aux);
  k_fill_all<<<4096, 256, 0, stream>>>(
      p_src, p_dst, rowE_p, curE_p, colE_p, cofE_p, nrm_p, EP,
      d_src, d_dst, rowE_d, curE_d, colE_d, cofE_d, nrm_d, ED,
      p_sn, p_si, rowS_p, curS_p, colS_p, SP,
      d_sn, d_si, rowS_d, curS_d, colS_d, SD);

  // ---- weights + encoders + vx (4 launches) ----
  k_wcvt_all<<<256, 256, 0, stream>>>(convW_d, convW_p, enc_Wd, enc_Wp, WhiAll, WloAll);
  k_xcvt_both<<<4096, 256, 0, stream>>>(drug_x, 78, Zhi_d, Zlo_d, ND * HID,
                                        prot_x, 70, Zhi_p, Zlo_p, NP * HID);
  k_gemm_both<true><<<ND / 128 + NP / 128, 256, 0, stream>>>(
      Zhi_d, Zlo_d, WhiAll + (size_t)6 * HID * HID, WloAll + (size_t)6 * HID * HID,
      enc_bd, Gd, ND / 128,
      Zhi_p, Zlo_p, WhiAll + (size_t)7 * HID * HID, WloAll + (size_t)7 * HID * HID,
      enc_bp, Gp, nullptr);
  k_vx_init_both<<<128, 256, 0, stream>>>(vn_emb_d, d_feat, vx_d, vn_emb_p, p_feat, vx_p, B * HID);

  // ---- 3 layers, merged drug+protein (6 launches/layer) ----
  for (int l = 0; l < 3; ++l) {
    if (l == 0)
      k_agg_both<false><<<ND / 8 + NP / 8, 256, 0, stream>>>(
          rowE_d, colE_d, cofE_d, Gd, nullptr, d_batch, vx_d, nrm_d, Zhi_d, Zlo_d, ND / 8,
          rowE_p, colE_p, cofE_p, Gp, nullptr, p_batch, vx_p, nrm_p, Zhi_p, Zlo_p);
    else
      k_agg_both<true><<<ND / 8 + NP / 8, 256, 0, stream>>>(
          rowE_d, colE_d, cofE_d, Gd, scsh_d, d_batch, vx_d, nrm_d, Zhi_d, Zlo_d, ND / 8,
          rowE_p, colE_p, cofE_p, Gp, scsh_p, p_batch, vx_p, nrm_p, Zhi_p, Zlo_p);
    k_gemm_both<false><<<ND / 128 + NP / 128, 256, 0, stream>>>(
        Zhi_d, Zlo_d, WhiAll + (size_t)l * HID * HID, WloAll + (size_t)l * HID * HID,
        nullptr, Gd, ND / 128,
        Zhi_p, Zlo_p, WhiAll + (size_t)(3 + l) * HID * HID, WloAll + (size_t)(3 + l) * HID * HID,
        nullptr, Gp, stats_sl);
    k_bn_scale_both<<<2, 128, 0, stream>>>(stats_sl,
        bng_d + l * HID, bnb_d + l * HID, 1.0f / (float)ND, scsh_d,
        bng_p + l * HID, bnb_p + l * HID, 1.0f / (float)NP, scsh_p);
    hipMemsetAsync(sum_Sd, 0, (size_t)2 * B * HID * 4, stream);
    k_sub_pool_both<<<ND / 8 + NP / 8, 256, 0, stream>>>(
        rowS_d, colS_d, Gd, scsh_d, d_batch, sum_Sd, ND / 8,
        rowS_p, colS_p, Gp, scsh_p, p_batch, sum_Sp);
    if (l < 2)
      k_vn_update_both<<<2 * B, 128, 0, stream>>>(
          sum_Sd, vx_d, vnW_d + (size_t)l * HID * HID, vnb_d + l * HID,
          sum_Sp, vx_p, vnW_p + (size_t)l * HID * HID, vnb_p + l * HID, B);
  }

  // ---- final (5 launches + 1 memset) ----
  k_final_A<<<B, 128, 0, stream>>>(sum_Sd, sum_Sp, nb_d, nb_p, A_d, A_p);
  k_final_mlp_both<<<2 * B, 128, 0, stream>>>(A_d, d_feat, mlpd1_W, mlpd1_b,
                                              A_p, p_feat, mlpp1_W, mlpp1_b, fpre, B);
  hipMemsetAsync(statsF, 0, 2 * 256 * 4, stream);
  k_bn_stats_both<<<256, 256, 0, stream>>>(fpre, statsF, B);
  k_bn_apply_both<<<128, 256, 0, stream>>>(fpre, (float*)d_out, statsF,
                                           mlpd1_g, mlpd1_be, mlpp1_g, mlpp1_be,
                                           B, 1.0f / (float)B);
}